// Round 2
// baseline (21646.614 us; speedup 1.0000x reference)
//
#include <hip/hip_runtime.h>

#define EN 8000
#define AN 800
#define NCQ 49
#define GPQ 98
#define CH 128

__constant__ int c_perm[49] = {
  0,2,6,12,20,30,42,
  1,5,11,19,29,41,
  3,7,13,21,31,43,
  4,10,18,28,40,
  8,14,22,32,44,
  9,17,27,39,
  15,23,33,45,
  16,26,38,
  24,34,46,
  25,37,
  35,47,
  36,
  48
};

__device__ __forceinline__ float siluf(float x) { return x / (1.0f + __expf(-x)); }
__device__ __forceinline__ void fma4(float4& a, float w, const float4& v) {
  a.x += w * v.x; a.y += w * v.y; a.z += w * v.z; a.w += w * v.w;
}

// ---------------------------------------------------------------------------
// Weight-concat builders (run once per call; all gathers, ~7M floats total)
// ---------------------------------------------------------------------------
__global__ __launch_bounds__(256) void k_build_b2(
    const float* __restrict__ sw2r, const float* __restrict__ sw2i,
    const float* __restrict__ tw2r, const float* __restrict__ tw2i,
    float* __restrict__ dst)
{
  long long id = (long long)blockIdx.x * 256 + threadIdx.x;
  if (id >= 5505024LL) return;
  long long base = 0; int m = 1, k = 768;
  for (; m <= 6; ++m) {
    k = (7 - m) * 128;
    long long sz = 2LL * k * 1024;
    if (id < base + sz) break;
    base += sz;
  }
  long long rem = id - base;
  int p = (int)(rem / ((long long)k * 1024));
  int cj = (int)(rem - (long long)p * k * 1024);
  int c = cj >> 10, j = cj & 1023;
  int q = j >> 8, jj = j & 255;
  const float sgn = (q & 1) ? (p ? 1.f : -1.f) : 1.f;
  const float* src = (q < 2) ? (q == 0 ? sw2r : sw2i) : (q == 2 ? tw2r : tw2i);
  dst[id] = sgn * src[(long long)(m - 1) * 196608 + c * 256 + jj];
}

__global__ __launch_bounds__(256) void k_build_bg(
    const float* __restrict__ swd, const float* __restrict__ twd,
    float* __restrict__ dst)
{
  int id = blockIdx.x * 256 + threadIdx.x;
  if (id >= 786432) return;
  int m = id >> 17;
  int rc = id & 131071;
  int r = rc >> 7, c = rc & 127;
  dst[id] = (r < 512) ? swd[m * 65536 + r * 128 + c]
                      : twd[m * 65536 + (r - 512) * 128 + c];
}

__global__ __launch_bounds__(256) void k_build_misc(
    const float* __restrict__ sw2m0, const float* __restrict__ tw2m0,
    const float* __restrict__ swd0, const float* __restrict__ twd0,
    const float* __restrict__ sbd, const float* __restrict__ tbd,
    const float* __restrict__ sb0, const float* __restrict__ tb0,
    float* __restrict__ b20, float* __restrict__ bg0,
    float* __restrict__ bgb, float* __restrict__ bg0b)
{
  int id = blockIdx.x * 256 + threadIdx.x;
  if (id < 458752) {
    int c = id >> 9, j = id & 511;
    b20[id] = (j < 256) ? sw2m0[c * 256 + j] : tw2m0[c * 256 + (j - 256)];
    return;
  }
  id -= 458752;
  if (id < 65536) {
    int r = id >> 7, c = id & 127;
    bg0[id] = (r < 256) ? swd0[r * 128 + c] : twd0[(r - 256) * 128 + c];
    return;
  }
  id -= 65536;
  if (id < 6144) {
    int m = id >> 10, r = id & 1023;
    bgb[id] = (r < 512) ? sbd[m * 512 + r] : tbd[m * 512 + (r - 512)];
    return;
  }
  id -= 6144;
  if (id < 512) bg0b[id] = (id < 256) ? sb0[id] : tb0[id - 256];
}

// ---------------------------------------------------------------------------
// K1: edge embedding
// ---------------------------------------------------------------------------
__global__ __launch_bounds__(128) void k_edge(
    const float* __restrict__ dist, const float* __restrict__ w_dist1,
    const float* __restrict__ b_dist1, const float* __restrict__ src_emb,
    const float* __restrict__ tgt_emb, const float* __restrict__ w_edge1,
    const float* __restrict__ b_edge1, const int* __restrict__ anum,
    const int* __restrict__ eidx, float* __restrict__ x_edge)
{
  const int e = blockIdx.x, t = threadIdx.x;
  __shared__ __align__(16) float basis[512];
  __shared__ __align__(16) float tmp[128];
  const float d = dist[e];
  const float step = 8.0f / 511.0f;
  const float coeff = -2040.0078125f;
  for (int g = t; g < 512; g += 128) {
    float df = d - (float)g * step;
    basis[g] = expf(coeff * df * df);
  }
  __syncthreads();
  float acc = b_dist1[t];
  const float4* w4 = (const float4*)(w_dist1 + (long long)t * 512);
  const float4* b4 = (const float4*)basis;
  #pragma unroll 4
  for (int g = 0; g < 128; ++g) {
    float4 w = w4[g]; float4 b = b4[g];
    acc += w.x*b.x + w.y*b.y + w.z*b.z + w.w*b.w;
  }
  const int a0 = anum[eidx[e]];
  const int a1 = anum[eidx[EN + e]];
  float v = src_emb[a0 * 128 + t] + tgt_emb[a1 * 128 + t] + acc;
  tmp[t] = siluf(v);
  __syncthreads();
  float acc2 = b_edge1[t];
  const float4* we4 = (const float4*)(w_edge1 + (long long)t * 128);
  const float4* t4 = (const float4*)tmp;
  #pragma unroll 4
  for (int k = 0; k < 32; ++k) {
    float4 w = we4[k]; float4 b = t4[k];
    acc2 += w.x*b.x + w.y*b.y + w.z*b.z + w.w*b.w;
  }
  x_edge[(long long)e * 128 + t] = siluf(acc2);
}

// ---------------------------------------------------------------------------
// K2: per-edge Wigner rotation, PERM folded into output row order.
// Operates on a chunk: wig/srcl/tgtl already offset by e0.
// ---------------------------------------------------------------------------
__global__ __launch_bounds__(256) void k_rot(
    const float* __restrict__ wig, const float* __restrict__ x,
    const int* __restrict__ srcl, const int* __restrict__ tgtl,
    float* __restrict__ osrc, float* __restrict__ otgt)
{
  const int e = blockIdx.x, t = threadIdx.x;
  __shared__ __align__(16) float wl[49 * 52];
  __shared__ __align__(16) float xs[NCQ * CH];
  __shared__ __align__(16) float xt[NCQ * CH];
  const float* wge = wig + (long long)e * (NCQ * NCQ);
  for (int l = t; l < NCQ * NCQ; l += 256) {
    int q = l / NCQ, j = l - q * NCQ;
    wl[q * 52 + j] = wge[c_perm[q] * NCQ + j];
  }
  const int asrc = srcl[e], atgt = tgtl[e];
  const float4* xsg = (const float4*)(x + (long long)asrc * (NCQ * CH));
  const float4* xtg = (const float4*)(x + (long long)atgt * (NCQ * CH));
  float4* xs4 = (float4*)xs;
  float4* xt4 = (float4*)xt;
  for (int l = t; l < NCQ * 32; l += 256) { xs4[l] = xsg[l]; xt4[l] = xtg[l]; }
  __syncthreads();
  const int ct = t & 31, rt = t >> 5;
  if (rt >= 7) return;  // no barriers after this point
  float4 accs[7], acct[7];
  #pragma unroll
  for (int u = 0; u < 7; ++u) {
    accs[u] = make_float4(0.f, 0.f, 0.f, 0.f);
    acct[u] = make_float4(0.f, 0.f, 0.f, 0.f);
  }
  for (int j0 = 0; j0 < 48; j0 += 4) {
    float4 v0s = xs4[(j0 + 0) * 32 + ct];
    float4 v1s = xs4[(j0 + 1) * 32 + ct];
    float4 v2s = xs4[(j0 + 2) * 32 + ct];
    float4 v3s = xs4[(j0 + 3) * 32 + ct];
    float4 v0t = xt4[(j0 + 0) * 32 + ct];
    float4 v1t = xt4[(j0 + 1) * 32 + ct];
    float4 v2t = xt4[(j0 + 2) * 32 + ct];
    float4 v3t = xt4[(j0 + 3) * 32 + ct];
    #pragma unroll
    for (int u = 0; u < 7; ++u) {
      const float4 w = *(const float4*)(wl + (rt * 7 + u) * 52 + j0);
      fma4(accs[u], w.x, v0s); fma4(accs[u], w.y, v1s);
      fma4(accs[u], w.z, v2s); fma4(accs[u], w.w, v3s);
      fma4(acct[u], w.x, v0t); fma4(acct[u], w.y, v1t);
      fma4(acct[u], w.z, v2t); fma4(acct[u], w.w, v3t);
    }
  }
  {
    float4 vs = xs4[48 * 32 + ct], vt = xt4[48 * 32 + ct];
    #pragma unroll
    for (int u = 0; u < 7; ++u) {
      float w = wl[(rt * 7 + u) * 52 + 48];
      fma4(accs[u], w, vs); fma4(acct[u], w, vt);
    }
  }
  float4* os = (float4*)(osrc + (long long)e * (NCQ * CH));
  float4* ot = (float4*)(otgt + (long long)e * (NCQ * CH));
  #pragma unroll
  for (int u = 0; u < 7; ++u) {
    int q = rt * 7 + u;
    os[q * 32 + ct] = accs[u];
    ot[q * 32 + ct] = acct[u];
  }
}

// ---------------------------------------------------------------------------
// Small-matrix x channel-block kernel: OUT[b,r,:] = act(sum_s W[r,s]*IN[b,s,:]+bias)
// ---------------------------------------------------------------------------
struct SmallP {
  const float* W; const float* IN; float* OUT; const float* bias;
  int perEdgeW, permW, R, S, act;
  long long in_bstride, out_bstride;
  int out_rstride, out_ofs;
};

template <int NUT>
__global__ __launch_bounds__(256) void k_smallmm(SmallP p) {
  __shared__ __align__(16) float Ws[5200];
  __shared__ __align__(16) float Ins[48 * 128];
  const int b = blockIdx.x, t = threadIdx.x;
  const int S4 = (p.S + 3) & ~3;
  const float* Wg = p.W + (p.perEdgeW ? (long long)b * p.R * p.S : 0);
  for (int l = t; l < p.R * p.S; l += 256) {
    int r = l / p.S, s = l - r * p.S;
    int scol = p.permW ? c_perm[s] : s;
    Ws[r * S4 + s] = Wg[(long long)r * p.S + scol];
  }
  const int ct = t & 31, rt = t >> 5;
  float4 acc[NUT];
  #pragma unroll
  for (int u = 0; u < NUT; ++u) acc[u] = make_float4(0.f, 0.f, 0.f, 0.f);
  const float* INb = p.IN + (long long)b * p.in_bstride;
  float4* In4 = (float4*)Ins;
  for (int s0 = 0; s0 < p.S; s0 += 48) {
    int sc = p.S - s0; if (sc > 48) sc = 48;
    __syncthreads();
    const float4* src = (const float4*)(INb + (long long)s0 * CH);
    for (int l = t; l < sc * 32; l += 256) In4[l] = src[l];
    __syncthreads();
    const int s4e = sc & ~3;
    for (int ss = 0; ss < s4e; ss += 4) {
      float4 v0 = In4[(ss + 0) * 32 + ct];
      float4 v1 = In4[(ss + 1) * 32 + ct];
      float4 v2 = In4[(ss + 2) * 32 + ct];
      float4 v3 = In4[(ss + 3) * 32 + ct];
      #pragma unroll
      for (int u = 0; u < NUT; ++u) {
        int r = rt + (u << 3);
        if (r < p.R) {
          float4 w = *(const float4*)(Ws + r * S4 + s0 + ss);
          fma4(acc[u], w.x, v0); fma4(acc[u], w.y, v1);
          fma4(acc[u], w.z, v2); fma4(acc[u], w.w, v3);
        }
      }
    }
    for (int ss = s4e; ss < sc; ++ss) {
      float4 v0 = In4[ss * 32 + ct];
      #pragma unroll
      for (int u = 0; u < NUT; ++u) {
        int r = rt + (u << 3);
        if (r < p.R) fma4(acc[u], Ws[r * S4 + s0 + ss], v0);
      }
    }
  }
  #pragma unroll
  for (int u = 0; u < NUT; ++u) {
    int r = rt + (u << 3);
    if (r < p.R) {
      float4 o = acc[u];
      if (p.bias) {
        const float4 bb = *(const float4*)(p.bias + (ct << 2));
        o.x += bb.x; o.y += bb.y; o.z += bb.z; o.w += bb.w;
      }
      if (p.act) { o.x = siluf(o.x); o.y = siluf(o.y); o.z = siluf(o.z); o.w = siluf(o.w); }
      *(float4*)(p.OUT + (long long)b * p.out_bstride +
                 (long long)r * p.out_rstride + p.out_ofs + (ct << 2)) = o;
    }
  }
}

// ---------------------------------------------------------------------------
// f32 GEMM: C = epi(A @ B^T). Row r -> (e,i) via pair flag.
// C row ptr = C + e*c_se + i*c_si + c_ofs; optional bias/silu/gate/accum.
// ---------------------------------------------------------------------------
struct GemmP {
  const float* A; const float* B; const float* bias; const float* gate; float* C;
  long long a_se; int a_si; int pair;
  int ldb; int gate_se; int gate_ofs;
  long long c_se; int c_si; int c_ofs;
  int accum; int act;
  int M, N, K;
};

#define GBM 128
#define GBN 128
#define GBK 16

__global__ __launch_bounds__(256) void gemm_bt(GemmP p) {
  __shared__ __align__(16) float As[GBK][GBM];
  __shared__ __align__(16) float Bs[GBK][GBN];
  const int tid = threadIdx.x;
  const int m0 = blockIdx.x * GBM;
  const int n0 = blockIdx.y * GBN;
  float acc[8][8];
  #pragma unroll
  for (int i = 0; i < 8; ++i)
    #pragma unroll
    for (int j = 0; j < 8; ++j) acc[i][j] = 0.f;

  const int lk = (tid & 3) << 2;
  const int lr = tid >> 2;
  const int tm = tid & 15;
  const int tn = tid >> 4;

  for (int k0 = 0; k0 < p.K; k0 += GBK) {
    #pragma unroll
    for (int h = 0; h < 2; ++h) {
      const int mm = lr + (h << 6);
      int r = m0 + mm;
      float4 a = make_float4(0.f, 0.f, 0.f, 0.f);
      if (r < p.M) {
        long long base;
        if (p.pair) base = (long long)(r >> 1) * p.a_se + (long long)(r & 1) * p.a_si;
        else        base = (long long)r * p.a_se;
        a = *(const float4*)(p.A + base + k0 + lk);
      }
      As[lk + 0][mm] = a.x; As[lk + 1][mm] = a.y;
      As[lk + 2][mm] = a.z; As[lk + 3][mm] = a.w;
      int rn = n0 + mm;
      float4 b = make_float4(0.f, 0.f, 0.f, 0.f);
      if (rn < p.N) b = *(const float4*)(p.B + (long long)rn * p.ldb + k0 + lk);
      Bs[lk + 0][mm] = b.x; Bs[lk + 1][mm] = b.y;
      Bs[lk + 2][mm] = b.z; Bs[lk + 3][mm] = b.w;
    }
    __syncthreads();
    #pragma unroll
    for (int kk = 0; kk < GBK; ++kk) {
      float4 a0 = *(const float4*)(&As[kk][tm * 8]);
      float4 a1 = *(const float4*)(&As[kk][tm * 8 + 4]);
      float4 b0 = *(const float4*)(&Bs[kk][tn * 8]);
      float4 b1 = *(const float4*)(&Bs[kk][tn * 8 + 4]);
      float av[8] = {a0.x, a0.y, a0.z, a0.w, a1.x, a1.y, a1.z, a1.w};
      float bv[8] = {b0.x, b0.y, b0.z, b0.w, b1.x, b1.y, b1.z, b1.w};
      #pragma unroll
      for (int i = 0; i < 8; ++i)
        #pragma unroll
        for (int j = 0; j < 8; ++j) acc[i][j] += av[i] * bv[j];
    }
    __syncthreads();
  }

  #pragma unroll
  for (int i = 0; i < 8; ++i) {
    int r = m0 + tm * 8 + i;
    if (r >= p.M) continue;
    long long e; int ii;
    if (p.pair) { e = r >> 1; ii = r & 1; } else { e = r; ii = 0; }
    const float* grow = p.gate ? (p.gate + e * p.gate_se + p.gate_ofs) : nullptr;
    float* crow = p.C + e * p.c_se + (long long)ii * p.c_si + p.c_ofs;
    #pragma unroll
    for (int j = 0; j < 8; ++j) {
      int c = n0 + tn * 8 + j;
      if (c >= p.N) continue;
      float v = acc[i][j];
      if (p.bias) v += p.bias[c];
      if (p.act)  v = siluf(v);
      if (grow)   v *= grow[c];
      if (p.accum) crow[c] += v; else crow[c] = v;
    }
  }
}

// ---------------------------------------------------------------------------
// Deterministic segment-sum over one edge chunk (accumulates across chunks).
// ---------------------------------------------------------------------------
__global__ __launch_bounds__(256) void k_scatter(
    const float* __restrict__ msg3, const int* __restrict__ tgt,
    float* __restrict__ xmsg, int c, int accum)
{
  const int a = blockIdx.x, t = threadIdx.x;
  __shared__ int tl[EN];
  for (int l = t; l < c; l += 256) tl[l] = tgt[l];
  __syncthreads();
  float acc[25];
  #pragma unroll
  for (int u = 0; u < 25; ++u) acc[u] = 0.f;
  for (int e = 0; e < c; ++e) {
    if (tl[e] == a) {
      const float* m = msg3 + (long long)e * 6272;
      #pragma unroll
      for (int u = 0; u < 25; ++u) {
        int idx = t + (u << 8);
        if (idx < 6272) acc[u] += m[idx];
      }
    }
  }
  float* o = xmsg + (long long)a * 6272;
  #pragma unroll
  for (int u = 0; u < 25; ++u) {
    int idx = t + (u << 8);
    if (idx < 6272) {
      if (accum) o[idx] += acc[u]; else o[idx] = acc[u];
    }
  }
}

// ---------------------------------------------------------------------------
// Host orchestration
// ---------------------------------------------------------------------------
extern "C" void kernel_launch(void* const* d_in, const int* in_sizes, int n_in,
                              void* d_out, int out_size, void* d_ws, size_t ws_size,
                              hipStream_t stream) {
  const float* x         = (const float*)d_in[0];
  const float* edist     = (const float*)d_in[1];
  const float* wigner    = (const float*)d_in[2];
  const float* wiginv    = (const float*)d_in[3];
  const float* to_grid   = (const float*)d_in[4];
  const float* from_grid = (const float*)d_in[5];
  const float* w_dist1   = (const float*)d_in[6];
  const float* b_dist1   = (const float*)d_in[7];
  const float* src_emb   = (const float*)d_in[8];
  const float* tgt_emb   = (const float*)d_in[9];
  const float* w_edge1   = (const float*)d_in[10];
  const float* b_edge1   = (const float*)d_in[11];
  const float* ws1       = (const float*)d_in[12];
  const float* bs1       = (const float*)d_in[13];
  const float* ws2       = (const float*)d_in[14];
  const float* bs2       = (const float*)d_in[15];
  const float* ws3       = (const float*)d_in[16];
  const float* bs3       = (const float*)d_in[17];
  const int*   anum      = (const int*)d_in[18];
  const int*   eidx      = (const int*)d_in[19];
  const float* sw[10]; const float* tw[10];
  for (int i = 0; i < 10; ++i) {
    sw[i] = (const float*)d_in[20 + i];
    tw[i] = (const float*)d_in[30 + i];
  }
  float* outp = (float*)d_out;

  // ---- workspace layout (floats) ----
  float* ws = (float*)d_ws;
  long long off = 0;
  auto alloc = [&](long long n) { float* pp = ws + off; off += n; return pp; };
  float* x_edge = alloc(1024000);
  float* b2a    = alloc(5505024);   // per-m, per-parity stage2 weights (k x 1024)
  float* bg     = alloc(786432);    // 6 x 1024 x 128 gate weights
  float* b2_0   = alloc(458752);    // 896 x 512 m0 stage2
  float* bg0    = alloc(65536);     // 512 x 128 m0 gate
  float* bgb    = alloc(6144);      // 6 x 1024 gate bias
  float* bg0b   = alloc(512);       // m0 gate bias
  float* xmsg   = alloc(5017600);
  const long long fixedF = off;     // 12,864,000
  float* arena  = ws + fixedF;

  // adaptive chunk levels
  static const int ces[7] = {8000, 4000, 2000, 1000, 1000, 500, 250};
  static const int cas[7] = {800, 800, 800, 800, 400, 200, 100};
  long long availF = (long long)(ws_size / 4);
  int ce = 250, ca = 100;
  for (int i = 0; i < 7; ++i) {
    long long ne = (long long)ces[i] * 21888;
    long long na = (long long)cas[i] * 43904;
    long long need = fixedF + (ne > na ? ne : na);
    if (need <= availF) { ce = ces[i]; ca = cas[i]; break; }
  }

  // edge-phase arena
  float* xrot_s = arena;
  float* xrot_t = xrot_s + (long long)ce * 6272;
  float* tb     = xrot_t + (long long)ce * 6272;
  float* msgp   = tb + (long long)ce * 2048;
  float* gate   = msgp + (long long)ce * 6272;
  float* ggrid  = arena;            // overlays xrot_s+xrot_t (exactly ce*12544)
  float* msg3   = arena;            // overlays after ggrid consumed
  // atom-phase arena (overlays edge arena)
  float* hb = arena;
  float* g1 = hb + (long long)ca * 6272;
  float* g2 = g1 + (long long)ca * 12544;
  float* g3 = g2 + (long long)ca * 12544;

  // stage2 concat-weight offsets
  long long ofs2[7][2];
  { long long cur = 0;
    for (int m = 1; m <= 6; ++m) {
      int k = (7 - m) * 128;
      ofs2[m][0] = cur; cur += (long long)k * 1024;
      ofs2[m][1] = cur; cur += (long long)k * 1024;
    } }

  auto gemm = [&](const float* A, long long a_se, int a_si, int pair,
                  const float* B, int ldb, const float* bias,
                  const float* gt, int gse, int gofs,
                  float* C, long long c_se, int c_si, int c_ofs,
                  int accum, int act, int M, int N, int K) {
    GemmP p;
    p.A = A; p.B = B; p.bias = bias; p.gate = gt; p.C = C;
    p.a_se = a_se; p.a_si = a_si; p.pair = pair;
    p.ldb = ldb; p.gate_se = gse; p.gate_ofs = gofs;
    p.c_se = c_se; p.c_si = c_si; p.c_ofs = c_ofs;
    p.accum = accum; p.act = act;
    p.M = M; p.N = N; p.K = K;
    dim3 g((M + GBM - 1) / GBM, (N + GBN - 1) / GBN);
    gemm_bt<<<g, dim3(256), 0, stream>>>(p);
  };
  auto small = [&](int nut, const float* W, int perEdge, int permW, int R, int S,
                   const float* IN, long long inb, float* OUT, long long outb,
                   int rstr, int ofs, const float* bias, int act, int nb) {
    SmallP p;
    p.W = W; p.IN = IN; p.OUT = OUT; p.bias = bias;
    p.perEdgeW = perEdge; p.permW = permW; p.R = R; p.S = S; p.act = act;
    p.in_bstride = inb; p.out_bstride = outb;
    p.out_rstride = rstr; p.out_ofs = ofs;
    if (nut == 13) k_smallmm<13><<<nb, dim3(256), 0, stream>>>(p);
    else           k_smallmm<7><<<nb, dim3(256), 0, stream>>>(p);
  };

  // 0) build concatenated weights
  k_build_b2<<<(5505024 + 255) / 256, 256, 0, stream>>>(sw[7], sw[9], tw[7], tw[9], b2a);
  k_build_bg<<<(786432 + 255) / 256, 256, 0, stream>>>(sw[4], tw[4], bg);
  k_build_misc<<<(530944 + 255) / 256, 256, 0, stream>>>(
      sw[3], tw[3], sw[0], tw[0], sw[5], tw[5], sw[1], tw[1], b2_0, bg0, bgb, bg0b);

  // 1) edge features (all edges)
  k_edge<<<EN, dim3(128), 0, stream>>>(edist, w_dist1, b_dist1, src_emb, tgt_emb,
                                       w_edge1, b_edge1, anum, eidx, x_edge);

  static const int offq[7] = {0, 7, 19, 29, 37, 43, 47};

  // 2) edge chunks
  for (int e0 = 0; e0 < EN; e0 += ce) {
    const int c = ce;
    // rotation
    k_rot<<<c, dim3(256), 0, stream>>>(wigner + (long long)e0 * 2401, x,
                                       eidx + e0, eidx + EN + e0, xrot_s, xrot_t);
    // m = 0
    gemm(x_edge + (long long)e0 * 128, 128, 0, 0, bg0, 128, bg0b, nullptr, 0, 0,
         gate, 1024, 0, 0, 0, 1, c, 512, 128);
    gemm(xrot_s, 6272, 0, 0, sw[2], 896, nullptr, gate, 1024, 0,
         tb, 512, 0, 0, 0, 0, c, 256, 896);
    gemm(xrot_t, 6272, 0, 0, tw[2], 896, nullptr, gate, 1024, 256,
         tb, 512, 0, 256, 0, 0, c, 256, 896);
    gemm(tb, 512, 0, 0, b2_0, 512, nullptr, nullptr, 0, 0,
         msgp, 6272, 0, 0, 0, 0, c, 896, 512);
    // m = 1..6
    for (int m = 1; m <= 6; ++m) {
      const int n = 7 - m, k = n * 128, off = offq[m];
      gemm(x_edge + (long long)e0 * 128, 128, 0, 0, bg + (long long)(m - 1) * 131072,
           128, bgb + (m - 1) * 1024, nullptr, 0, 0,
           gate, 1024, 0, 0, 0, 1, c, 1024, 128);
      // stage 1: 4 GEMMs into parity slabs of tb[e, 2, 4, 256]
      gemm(xrot_s + off * 128, 6272, k, 1, sw[6] + (long long)(m - 1) * 196608, 768,
           nullptr, gate, 1024, 0,    tb, 2048,  1024, 0,    0, 0, 2 * c, 256, k);
      gemm(xrot_s + off * 128, 6272, k, 1, sw[8] + (long long)(m - 1) * 196608, 768,
           nullptr, gate, 1024, 256,  tb, 2048, -1024, 1280, 0, 0, 2 * c, 256, k);
      gemm(xrot_t + off * 128, 6272, k, 1, tw[6] + (long long)(m - 1) * 196608, 768,
           nullptr, gate, 1024, 512,  tb, 2048,  1024, 512,  0, 0, 2 * c, 256, k);
      gemm(xrot_t + off * 128, 6272, k, 1, tw[8] + (long long)(m - 1) * 196608, 768,
           nullptr, gate, 1024, 768,  tb, 2048, -1024, 1792, 0, 0, 2 * c, 256, k);
      // stage 2: one GEMM per parity (signs folded into b2a)
      gemm(tb, 2048, 0, 0, b2a + ofs2[m][0], 1024, nullptr, nullptr, 0, 0,
           msgp, 6272, 0, off * 128, 0, 0, c, k, 1024);
      gemm(tb + 1024, 2048, 0, 0, b2a + ofs2[m][1], 1024, nullptr, nullptr, 0, 0,
           msgp, 6272, 0, (off + n) * 128, 0, 0, c, k, 1024);
    }
    // grid activation + inverse rotation
    small(13, to_grid, 0, 1, 98, 49, msgp, 6272, ggrid, 12544, 128, 0, nullptr, 1, c);
    small(7, from_grid, 0, 0, 49, 98, ggrid, 12544, msgp, 6272, 128, 0, nullptr, 0, c);
    small(7, wiginv + (long long)e0 * 2401, 1, 0, 49, 49, msgp, 6272,
          msg3, 6272, 128, 0, nullptr, 0, c);
    // segment-sum into xmsg
    k_scatter<<<AN, dim3(256), 0, stream>>>(msg3, eidx + EN + e0, xmsg, c, e0 > 0);
  }

  // 3) atom phase: out = fg @ (silu(silu(tg@(x@W1a^T + xmsg@W1b^T)+b1)@W2^T+b2)@W3^T+b3)
  for (int a0 = 0; a0 < AN; a0 += ca) {
    gemm(x + (long long)a0 * 6272, 128, 0, 0, ws1, 256, nullptr, nullptr, 0, 0,
         hb, 128, 0, 0, 0, 0, ca * 49, 128, 128);
    gemm(xmsg + (long long)a0 * 6272, 128, 0, 0, ws1 + 128, 256, nullptr, nullptr, 0, 0,
         hb, 128, 0, 0, 1, 0, ca * 49, 128, 128);
    small(13, to_grid, 0, 0, 98, 49, hb, 6272, g1, 12544, 128, 0, bs1, 1, ca);
    gemm(g1, 128, 0, 0, ws2, 128, bs2, nullptr, 0, 0,
         g2, 128, 0, 0, 0, 1, ca * 98, 128, 128);
    gemm(g2, 128, 0, 0, ws3, 128, bs3, nullptr, 0, 0,
         g3, 128, 0, 0, 0, 0, ca * 98, 128, 128);
    small(7, from_grid, 0, 0, 49, 98, g3, 12544, outp + (long long)a0 * 6272,
          6272, 128, 0, nullptr, 0, ca);
  }
}

// Round 3
// 9359.900 us; speedup vs baseline: 2.3127x; 2.3127x over previous
//
#include <hip/hip_runtime.h>

#define EN 8000
#define AN 800
#define NCQ 49
#define GPQ 98
#define CH 128

__constant__ int c_perm[49] = {
  0,2,6,12,20,30,42,
  1,5,11,19,29,41,
  3,7,13,21,31,43,
  4,10,18,28,40,
  8,14,22,32,44,
  9,17,27,39,
  15,23,33,45,
  16,26,38,
  24,34,46,
  25,37,
  35,47,
  36,
  48
};

typedef __attribute__((ext_vector_type(8))) short bf16x8;
typedef __attribute__((ext_vector_type(4))) float f32x4;

__device__ __forceinline__ float siluf(float x) { return x / (1.0f + __expf(-x)); }
__device__ __forceinline__ void fma4(float4& a, float w, const float4& v) {
  a.x += w * v.x; a.y += w * v.y; a.z += w * v.z; a.w += w * v.w;
}
__device__ __forceinline__ short f2bf(float f) {
  unsigned u = __float_as_uint(f);
  u += 0x7fff + ((u >> 16) & 1);
  return (short)(u >> 16);
}

// ---------------------------------------------------------------------------
// Weight-concat builders (once per call)
// ---------------------------------------------------------------------------
__global__ __launch_bounds__(256) void k_build_b2(
    const float* __restrict__ sw2r, const float* __restrict__ sw2i,
    const float* __restrict__ tw2r, const float* __restrict__ tw2i,
    float* __restrict__ dst)
{
  long long id = (long long)blockIdx.x * 256 + threadIdx.x;
  if (id >= 5505024LL) return;
  long long base = 0; int m = 1, k = 768;
  for (; m <= 6; ++m) {
    k = (7 - m) * 128;
    long long sz = 2LL * k * 1024;
    if (id < base + sz) break;
    base += sz;
  }
  long long rem = id - base;
  int p = (int)(rem / ((long long)k * 1024));
  int cj = (int)(rem - (long long)p * k * 1024);
  int c = cj >> 10, j = cj & 1023;
  int q = j >> 8, jj = j & 255;
  const float sgn = (q & 1) ? (p ? 1.f : -1.f) : 1.f;
  const float* src = (q < 2) ? (q == 0 ? sw2r : sw2i) : (q == 2 ? tw2r : tw2i);
  dst[id] = sgn * src[(long long)(m - 1) * 196608 + c * 256 + jj];
}

__global__ __launch_bounds__(256) void k_build_bg(
    const float* __restrict__ swd, const float* __restrict__ twd,
    float* __restrict__ dst)
{
  int id = blockIdx.x * 256 + threadIdx.x;
  if (id >= 786432) return;
  int m = id >> 17;
  int rc = id & 131071;
  int r = rc >> 7, c = rc & 127;
  dst[id] = (r < 512) ? swd[m * 65536 + r * 128 + c]
                      : twd[m * 65536 + (r - 512) * 128 + c];
}

__global__ __launch_bounds__(256) void k_build_misc(
    const float* __restrict__ sw2m0, const float* __restrict__ tw2m0,
    const float* __restrict__ swd0, const float* __restrict__ twd0,
    const float* __restrict__ sbd, const float* __restrict__ tbd,
    const float* __restrict__ sb0, const float* __restrict__ tb0,
    float* __restrict__ b20, float* __restrict__ bg0,
    float* __restrict__ bgb, float* __restrict__ bg0b)
{
  int id = blockIdx.x * 256 + threadIdx.x;
  if (id < 458752) {
    int c = id >> 9, j = id & 511;
    b20[id] = (j < 256) ? sw2m0[c * 256 + j] : tw2m0[c * 256 + (j - 256)];
    return;
  }
  id -= 458752;
  if (id < 65536) {
    int r = id >> 7, c = id & 127;
    bg0[id] = (r < 256) ? swd0[r * 128 + c] : twd0[(r - 256) * 128 + c];
    return;
  }
  id -= 65536;
  if (id < 6144) {
    int m = id >> 10, r = id & 1023;
    bgb[id] = (r < 512) ? sbd[m * 512 + r] : tbd[m * 512 + (r - 512)];
    return;
  }
  id -= 6144;
  if (id < 512) bg0b[id] = (id < 256) ? sb0[id] : tb0[id - 256];
}

// ---------------------------------------------------------------------------
// Edge-feature path: basis expansion + elementwise embed/silu (GEMMs separate)
// ---------------------------------------------------------------------------
__global__ __launch_bounds__(256) void k_basis(
    const float* __restrict__ dist, float* __restrict__ basis)
{
  int id = blockIdx.x * 256 + threadIdx.x;
  if (id >= EN * 512) return;
  int e = id >> 9, g = id & 511;
  const float step = 8.0f / 511.0f;
  const float coeff = -2040.0078125f;
  float df = dist[e] - (float)g * step;
  basis[id] = expf(coeff * df * df);
}

__global__ __launch_bounds__(256) void k_emb(
    const float* __restrict__ src_emb, const float* __restrict__ tgt_emb,
    const int* __restrict__ anum, const int* __restrict__ eidx,
    float* __restrict__ xd)
{
  int id = blockIdx.x * 256 + threadIdx.x;
  if (id >= EN * 128) return;
  int e = id >> 7, c = id & 127;
  int a0 = anum[eidx[e]], a1 = anum[eidx[EN + e]];
  xd[id] = siluf(src_emb[a0 * 128 + c] + tgt_emb[a1 * 128 + c] + xd[id]);
}

// ---------------------------------------------------------------------------
// K2: per-edge Wigner rotation, PERM folded into output row order.
// ---------------------------------------------------------------------------
__global__ __launch_bounds__(256) void k_rot(
    const float* __restrict__ wig, const float* __restrict__ x,
    const int* __restrict__ srcl, const int* __restrict__ tgtl,
    float* __restrict__ osrc, float* __restrict__ otgt)
{
  const int e = blockIdx.x, t = threadIdx.x;
  __shared__ __align__(16) float wl[49 * 52];
  __shared__ __align__(16) float xs[NCQ * CH];
  __shared__ __align__(16) float xt[NCQ * CH];
  const float* wge = wig + (long long)e * (NCQ * NCQ);
  for (int l = t; l < NCQ * NCQ; l += 256) {
    int q = l / NCQ, j = l - q * NCQ;
    wl[q * 52 + j] = wge[c_perm[q] * NCQ + j];
  }
  const int asrc = srcl[e], atgt = tgtl[e];
  const float4* xsg = (const float4*)(x + (long long)asrc * (NCQ * CH));
  const float4* xtg = (const float4*)(x + (long long)atgt * (NCQ * CH));
  float4* xs4 = (float4*)xs;
  float4* xt4 = (float4*)xt;
  for (int l = t; l < NCQ * 32; l += 256) { xs4[l] = xsg[l]; xt4[l] = xtg[l]; }
  __syncthreads();
  const int ct = t & 31, rt = t >> 5;
  if (rt >= 7) return;
  float4 accs[7], acct[7];
  #pragma unroll
  for (int u = 0; u < 7; ++u) {
    accs[u] = make_float4(0.f, 0.f, 0.f, 0.f);
    acct[u] = make_float4(0.f, 0.f, 0.f, 0.f);
  }
  for (int j0 = 0; j0 < 48; j0 += 4) {
    float4 v0s = xs4[(j0 + 0) * 32 + ct];
    float4 v1s = xs4[(j0 + 1) * 32 + ct];
    float4 v2s = xs4[(j0 + 2) * 32 + ct];
    float4 v3s = xs4[(j0 + 3) * 32 + ct];
    float4 v0t = xt4[(j0 + 0) * 32 + ct];
    float4 v1t = xt4[(j0 + 1) * 32 + ct];
    float4 v2t = xt4[(j0 + 2) * 32 + ct];
    float4 v3t = xt4[(j0 + 3) * 32 + ct];
    #pragma unroll
    for (int u = 0; u < 7; ++u) {
      const float4 w = *(const float4*)(wl + (rt * 7 + u) * 52 + j0);
      fma4(accs[u], w.x, v0s); fma4(accs[u], w.y, v1s);
      fma4(accs[u], w.z, v2s); fma4(accs[u], w.w, v3s);
      fma4(acct[u], w.x, v0t); fma4(acct[u], w.y, v1t);
      fma4(acct[u], w.z, v2t); fma4(acct[u], w.w, v3t);
    }
  }
  {
    float4 vs = xs4[48 * 32 + ct], vt = xt4[48 * 32 + ct];
    #pragma unroll
    for (int u = 0; u < 7; ++u) {
      float w = wl[(rt * 7 + u) * 52 + 48];
      fma4(accs[u], w, vs); fma4(acct[u], w, vt);
    }
  }
  float4* os = (float4*)(osrc + (long long)e * (NCQ * CH));
  float4* ot = (float4*)(otgt + (long long)e * (NCQ * CH));
  #pragma unroll
  for (int u = 0; u < 7; ++u) {
    int q = rt * 7 + u;
    os[q * 32 + ct] = accs[u];
    ot[q * 32 + ct] = acct[u];
  }
}

// ---------------------------------------------------------------------------
// Small-matrix x channel-block kernel (f32): OUT[b,r,:]=act(sum W[r,s]IN[b,s,:]+b)
// ---------------------------------------------------------------------------
struct SmallP {
  const float* W; const float* IN; float* OUT; const float* bias;
  int perEdgeW, permW, R, S, act;
  long long in_bstride, out_bstride;
  int out_rstride, out_ofs;
};

template <int NUT>
__global__ __launch_bounds__(256) void k_smallmm(SmallP p) {
  __shared__ __align__(16) float Ws[5200];
  __shared__ __align__(16) float Ins[48 * 128];
  const int b = blockIdx.x, t = threadIdx.x;
  const int S4 = (p.S + 3) & ~3;
  const float* Wg = p.W + (p.perEdgeW ? (long long)b * p.R * p.S : 0);
  for (int l = t; l < p.R * p.S; l += 256) {
    int r = l / p.S, s = l - r * p.S;
    int scol = p.permW ? c_perm[s] : s;
    Ws[r * S4 + s] = Wg[(long long)r * p.S + scol];
  }
  const int ct = t & 31, rt = t >> 5;
  float4 acc[NUT];
  #pragma unroll
  for (int u = 0; u < NUT; ++u) acc[u] = make_float4(0.f, 0.f, 0.f, 0.f);
  const float* INb = p.IN + (long long)b * p.in_bstride;
  float4* In4 = (float4*)Ins;
  for (int s0 = 0; s0 < p.S; s0 += 48) {
    int sc = p.S - s0; if (sc > 48) sc = 48;
    __syncthreads();
    const float4* src = (const float4*)(INb + (long long)s0 * CH);
    for (int l = t; l < sc * 32; l += 256) In4[l] = src[l];
    __syncthreads();
    const int s4e = sc & ~3;
    for (int ss = 0; ss < s4e; ss += 4) {
      float4 v0 = In4[(ss + 0) * 32 + ct];
      float4 v1 = In4[(ss + 1) * 32 + ct];
      float4 v2 = In4[(ss + 2) * 32 + ct];
      float4 v3 = In4[(ss + 3) * 32 + ct];
      #pragma unroll
      for (int u = 0; u < NUT; ++u) {
        int r = rt + (u << 3);
        if (r < p.R) {
          float4 w = *(const float4*)(Ws + r * S4 + s0 + ss);
          fma4(acc[u], w.x, v0); fma4(acc[u], w.y, v1);
          fma4(acc[u], w.z, v2); fma4(acc[u], w.w, v3);
        }
      }
    }
    for (int ss = s4e; ss < sc; ++ss) {
      float4 v0 = In4[ss * 32 + ct];
      #pragma unroll
      for (int u = 0; u < NUT; ++u) {
        int r = rt + (u << 3);
        if (r < p.R) fma4(acc[u], Ws[r * S4 + s0 + ss], v0);
      }
    }
  }
  #pragma unroll
  for (int u = 0; u < NUT; ++u) {
    int r = rt + (u << 3);
    if (r < p.R) {
      float4 o = acc[u];
      if (p.bias) {
        const float4 bb = *(const float4*)(p.bias + (ct << 2));
        o.x += bb.x; o.y += bb.y; o.z += bb.z; o.w += bb.w;
      }
      if (p.act) { o.x = siluf(o.x); o.y = siluf(o.y); o.z = siluf(o.z); o.w = siluf(o.w); }
      *(float4*)(p.OUT + (long long)b * p.out_bstride +
                 (long long)r * p.out_rstride + p.out_ofs + (ct << 2)) = o;
    }
  }
}

// ---------------------------------------------------------------------------
// MFMA bf16 GEMM: C = epi(A @ B^T), f32 in/out, bf16 convert in staging.
// 128x128 tile, 4 waves x (4x4 frags of 16x16x32), f32 accum.
// ---------------------------------------------------------------------------
struct GemmP {
  const float* A; const float* B; const float* bias; const float* gate; float* C;
  long long a_se; int a_si; int pair;
  int ldb; int gate_se; int gate_ofs;
  long long c_se; int c_si; int c_ofs;
  int accum; int act;
  int M, N, K;
};

#define TM 128
#define TN 128
#define LDW 40  // LDS row stride in bf16 (32 + 8 pad)

__global__ __launch_bounds__(256) void gemm_mfma(GemmP p) {
  __shared__ short As[128 * LDW];
  __shared__ short Bs[128 * LDW];
  const int tid = threadIdx.x;
  const int m0 = blockIdx.x * TM;
  const int n0 = blockIdx.y * TN;
  const int lane = tid & 63;
  const int wave = tid >> 6;
  const int wm = (wave >> 1) * 64;
  const int wn = (wave & 1) * 64;

  f32x4 acc[4][4];
  #pragma unroll
  for (int i = 0; i < 4; ++i)
    #pragma unroll
    for (int j = 0; j < 4; ++j) acc[i][j] = (f32x4){0.f, 0.f, 0.f, 0.f};

  const int srow = tid >> 1;          // 0..127
  const int sk = (tid & 1) * 16;      // k sub-offset
  const int fr = lane & 15;
  const int fk = (lane >> 4) * 8;

  for (int k0 = 0; k0 < p.K; k0 += 32) {
    // --- stage A ---
    {
      float4 a0 = make_float4(0.f,0.f,0.f,0.f), a1 = a0, a2 = a0, a3 = a0;
      int r = m0 + srow;
      if (r < p.M) {
        long long base;
        if (p.pair) base = (long long)(r >> 1) * p.a_se + (long long)(r & 1) * p.a_si;
        else        base = (long long)r * p.a_se;
        const float4* src = (const float4*)(p.A + base + k0 + sk);
        a0 = src[0]; a1 = src[1]; a2 = src[2]; a3 = src[3];
      }
      short* d = &As[srow * LDW + sk];
      bf16x8 lo, hi;
      lo[0]=f2bf(a0.x); lo[1]=f2bf(a0.y); lo[2]=f2bf(a0.z); lo[3]=f2bf(a0.w);
      lo[4]=f2bf(a1.x); lo[5]=f2bf(a1.y); lo[6]=f2bf(a1.z); lo[7]=f2bf(a1.w);
      hi[0]=f2bf(a2.x); hi[1]=f2bf(a2.y); hi[2]=f2bf(a2.z); hi[3]=f2bf(a2.w);
      hi[4]=f2bf(a3.x); hi[5]=f2bf(a3.y); hi[6]=f2bf(a3.z); hi[7]=f2bf(a3.w);
      *(bf16x8*)(d) = lo;
      *(bf16x8*)(d + 8) = hi;
    }
    // --- stage B ---
    {
      float4 a0 = make_float4(0.f,0.f,0.f,0.f), a1 = a0, a2 = a0, a3 = a0;
      int r = n0 + srow;
      if (r < p.N) {
        const float4* src = (const float4*)(p.B + (long long)r * p.ldb + k0 + sk);
        a0 = src[0]; a1 = src[1]; a2 = src[2]; a3 = src[3];
      }
      short* d = &Bs[srow * LDW + sk];
      bf16x8 lo, hi;
      lo[0]=f2bf(a0.x); lo[1]=f2bf(a0.y); lo[2]=f2bf(a0.z); lo[3]=f2bf(a0.w);
      lo[4]=f2bf(a1.x); lo[5]=f2bf(a1.y); lo[6]=f2bf(a1.z); lo[7]=f2bf(a1.w);
      hi[0]=f2bf(a2.x); hi[1]=f2bf(a2.y); hi[2]=f2bf(a2.z); hi[3]=f2bf(a2.w);
      hi[4]=f2bf(a3.x); hi[5]=f2bf(a3.y); hi[6]=f2bf(a3.z); hi[7]=f2bf(a3.w);
      *(bf16x8*)(d) = lo;
      *(bf16x8*)(d + 8) = hi;
    }
    __syncthreads();
    bf16x8 af[4], bfv[4];
    #pragma unroll
    for (int i = 0; i < 4; ++i) {
      af[i]  = *(const bf16x8*)(&As[(wm + i * 16 + fr) * LDW + fk]);
      bfv[i] = *(const bf16x8*)(&Bs[(wn + i * 16 + fr) * LDW + fk]);
    }
    #pragma unroll
    for (int i = 0; i < 4; ++i)
      #pragma unroll
      for (int j = 0; j < 4; ++j)
        acc[i][j] = __builtin_amdgcn_mfma_f32_16x16x32_bf16(af[i], bfv[j], acc[i][j], 0, 0, 0);
    __syncthreads();
  }

  const int crl = (lane >> 4) << 2;
  const int ccl = lane & 15;
  #pragma unroll
  for (int mi = 0; mi < 4; ++mi) {
    #pragma unroll
    for (int r = 0; r < 4; ++r) {
      int gr = m0 + wm + mi * 16 + crl + r;
      if (gr >= p.M) continue;
      long long e; int ii;
      if (p.pair) { e = gr >> 1; ii = gr & 1; } else { e = gr; ii = 0; }
      const float* grow = p.gate ? (p.gate + e * p.gate_se + p.gate_ofs) : nullptr;
      float* crow = p.C + e * p.c_se + (long long)ii * p.c_si + p.c_ofs;
      #pragma unroll
      for (int ni = 0; ni < 4; ++ni) {
        int gc = n0 + wn + ni * 16 + ccl;
        if (gc >= p.N) continue;
        float v = acc[mi][ni][r];
        if (p.bias) v += p.bias[gc];
        if (p.act)  v = siluf(v);
        if (grow)   v *= grow[gc];
        if (p.accum) crow[gc] += v; else crow[gc] = v;
      }
    }
  }
}

// ---------------------------------------------------------------------------
// Deterministic segment-sum over one edge chunk (accumulates across chunks).
// ---------------------------------------------------------------------------
__global__ __launch_bounds__(256) void k_scatter(
    const float* __restrict__ msg3, const int* __restrict__ tgt,
    float* __restrict__ xmsg, int c, int accum)
{
  const int a = blockIdx.x, t = threadIdx.x;
  __shared__ int tl[EN];
  for (int l = t; l < c; l += 256) tl[l] = tgt[l];
  __syncthreads();
  float acc[25];
  #pragma unroll
  for (int u = 0; u < 25; ++u) acc[u] = 0.f;
  for (int e = 0; e < c; ++e) {
    if (tl[e] == a) {
      const float* m = msg3 + (long long)e * 6272;
      #pragma unroll
      for (int u = 0; u < 25; ++u) {
        int idx = t + (u << 8);
        if (idx < 6272) acc[u] += m[idx];
      }
    }
  }
  float* o = xmsg + (long long)a * 6272;
  #pragma unroll
  for (int u = 0; u < 25; ++u) {
    int idx = t + (u << 8);
    if (idx < 6272) {
      if (accum) o[idx] += acc[u]; else o[idx] = acc[u];
    }
  }
}

// ---------------------------------------------------------------------------
// Host orchestration
// ---------------------------------------------------------------------------
extern "C" void kernel_launch(void* const* d_in, const int* in_sizes, int n_in,
                              void* d_out, int out_size, void* d_ws, size_t ws_size,
                              hipStream_t stream) {
  const float* x         = (const float*)d_in[0];
  const float* edist     = (const float*)d_in[1];
  const float* wigner    = (const float*)d_in[2];
  const float* wiginv    = (const float*)d_in[3];
  const float* to_grid   = (const float*)d_in[4];
  const float* from_grid = (const float*)d_in[5];
  const float* w_dist1   = (const float*)d_in[6];
  const float* b_dist1   = (const float*)d_in[7];
  const float* src_emb   = (const float*)d_in[8];
  const float* tgt_emb   = (const float*)d_in[9];
  const float* w_edge1   = (const float*)d_in[10];
  const float* b_edge1   = (const float*)d_in[11];
  const float* ws1       = (const float*)d_in[12];
  const float* bs1       = (const float*)d_in[13];
  const float* ws2       = (const float*)d_in[14];
  const float* bs2       = (const float*)d_in[15];
  const float* ws3       = (const float*)d_in[16];
  const float* bs3       = (const float*)d_in[17];
  const int*   anum      = (const int*)d_in[18];
  const int*   eidx      = (const int*)d_in[19];
  const float* sw[10]; const float* tw[10];
  for (int i = 0; i < 10; ++i) {
    sw[i] = (const float*)d_in[20 + i];
    tw[i] = (const float*)d_in[30 + i];
  }
  float* outp = (float*)d_out;

  // ---- workspace layout (floats) ----
  float* ws = (float*)d_ws;
  long long off = 0;
  auto alloc = [&](long long n) { float* pp = ws + off; off += n; return pp; };
  float* x_edge = alloc(1024000);
  float* b2a    = alloc(5505024);
  float* bg     = alloc(786432);
  float* b2_0   = alloc(458752);
  float* bg0    = alloc(65536);
  float* bgb    = alloc(6144);
  float* bg0b   = alloc(512);
  float* xmsg   = alloc(5017600);
  float* basis  = alloc(4096000);   // 8000 x 512
  float* x_dist = alloc(1024000);   // 8000 x 128 (reused in place by k_emb)
  const long long fixedF = off;
  float* arena  = ws + fixedF;

  // adaptive chunk levels
  static const int ces[7] = {8000, 4000, 2000, 1000, 1000, 500, 250};
  static const int cas[7] = {800, 800, 800, 800, 400, 200, 100};
  long long availF = (long long)(ws_size / 4);
  int ce = 250, ca = 100;
  for (int i = 0; i < 7; ++i) {
    long long ne = (long long)ces[i] * 21888;
    long long na = (long long)cas[i] * 43904;
    long long need = fixedF + (ne > na ? ne : na);
    if (need <= availF) { ce = ces[i]; ca = cas[i]; break; }
  }

  // edge-phase arena
  float* xrot_s = arena;
  float* xrot_t = xrot_s + (long long)ce * 6272;
  float* tb     = xrot_t + (long long)ce * 6272;
  float* msgp   = tb + (long long)ce * 2048;
  float* gate   = msgp + (long long)ce * 6272;
  float* ggrid  = arena;
  float* msg3   = arena;
  // atom-phase arena (overlays edge arena)
  float* hb = arena;
  float* g1 = hb + (long long)ca * 6272;
  float* g2 = g1 + (long long)ca * 12544;
  float* g3 = g2 + (long long)ca * 12544;

  long long ofs2[7][2];
  { long long cur = 0;
    for (int m = 1; m <= 6; ++m) {
      int k = (7 - m) * 128;
      ofs2[m][0] = cur; cur += (long long)k * 1024;
      ofs2[m][1] = cur; cur += (long long)k * 1024;
    } }

  auto gemm = [&](const float* A, long long a_se, int a_si, int pair,
                  const float* B, int ldb, const float* bias,
                  const float* gt, int gse, int gofs,
                  float* C, long long c_se, int c_si, int c_ofs,
                  int accum, int act, int M, int N, int K) {
    GemmP p;
    p.A = A; p.B = B; p.bias = bias; p.gate = gt; p.C = C;
    p.a_se = a_se; p.a_si = a_si; p.pair = pair;
    p.ldb = ldb; p.gate_se = gse; p.gate_ofs = gofs;
    p.c_se = c_se; p.c_si = c_si; p.c_ofs = c_ofs;
    p.accum = accum; p.act = act;
    p.M = M; p.N = N; p.K = K;
    dim3 g((M + TM - 1) / TM, (N + TN - 1) / TN);
    gemm_mfma<<<g, dim3(256), 0, stream>>>(p);
  };
  auto small = [&](int nut, const float* W, int perEdge, int permW, int R, int S,
                   const float* IN, long long inb, float* OUT, long long outb,
                   int rstr, int ofs, const float* bias, int act, int nb) {
    SmallP p;
    p.W = W; p.IN = IN; p.OUT = OUT; p.bias = bias;
    p.perEdgeW = perEdge; p.permW = permW; p.R = R; p.S = S; p.act = act;
    p.in_bstride = inb; p.out_bstride = outb;
    p.out_rstride = rstr; p.out_ofs = ofs;
    if (nut == 13) k_smallmm<13><<<nb, dim3(256), 0, stream>>>(p);
    else           k_smallmm<7><<<nb, dim3(256), 0, stream>>>(p);
  };

  // 0) build concatenated weights
  k_build_b2<<<(5505024 + 255) / 256, 256, 0, stream>>>(sw[7], sw[9], tw[7], tw[9], b2a);
  k_build_bg<<<(786432 + 255) / 256, 256, 0, stream>>>(sw[4], tw[4], bg);
  k_build_misc<<<(530944 + 255) / 256, 256, 0, stream>>>(
      sw[3], tw[3], sw[0], tw[0], sw[5], tw[5], sw[1], tw[1], b2_0, bg0, bgb, bg0b);

  // 1) edge features: basis -> GEMM -> embed/silu -> GEMM
  k_basis<<<(EN * 512 + 255) / 256, 256, 0, stream>>>(edist, basis);
  gemm(basis, 512, 0, 0, w_dist1, 512, b_dist1, nullptr, 0, 0,
       x_dist, 128, 0, 0, 0, 0, EN, 128, 512);
  k_emb<<<(EN * 128 + 255) / 256, 256, 0, stream>>>(src_emb, tgt_emb, anum, eidx, x_dist);
  gemm(x_dist, 128, 0, 0, w_edge1, 128, b_edge1, nullptr, 0, 0,
       x_edge, 128, 0, 0, 0, 1, EN, 128, 128);

  static const int offq[7] = {0, 7, 19, 29, 37, 43, 47};

  // 2) edge chunks
  for (int e0 = 0; e0 < EN; e0 += ce) {
    const int c = ce;
    k_rot<<<c, dim3(256), 0, stream>>>(wigner + (long long)e0 * 2401, x,
                                       eidx + e0, eidx + EN + e0, xrot_s, xrot_t);
    // m = 0
    gemm(x_edge + (long long)e0 * 128, 128, 0, 0, bg0, 128, bg0b, nullptr, 0, 0,
         gate, 1024, 0, 0, 0, 1, c, 512, 128);
    gemm(xrot_s, 6272, 0, 0, sw[2], 896, nullptr, gate, 1024, 0,
         tb, 512, 0, 0, 0, 0, c, 256, 896);
    gemm(xrot_t, 6272, 0, 0, tw[2], 896, nullptr, gate, 1024, 256,
         tb, 512, 0, 256, 0, 0, c, 256, 896);
    gemm(tb, 512, 0, 0, b2_0, 512, nullptr, nullptr, 0, 0,
         msgp, 6272, 0, 0, 0, 0, c, 896, 512);
    // m = 1..6
    for (int m = 1; m <= 6; ++m) {
      const int n = 7 - m, k = n * 128, off = offq[m];
      gemm(x_edge + (long long)e0 * 128, 128, 0, 0, bg + (long long)(m - 1) * 131072,
           128, bgb + (m - 1) * 1024, nullptr, 0, 0,
           gate, 1024, 0, 0, 0, 1, c, 1024, 128);
      gemm(xrot_s + off * 128, 6272, k, 1, sw[6] + (long long)(m - 1) * 196608, 768,
           nullptr, gate, 1024, 0,    tb, 2048,  1024, 0,    0, 0, 2 * c, 256, k);
      gemm(xrot_s + off * 128, 6272, k, 1, sw[8] + (long long)(m - 1) * 196608, 768,
           nullptr, gate, 1024, 256,  tb, 2048, -1024, 1280, 0, 0, 2 * c, 256, k);
      gemm(xrot_t + off * 128, 6272, k, 1, tw[6] + (long long)(m - 1) * 196608, 768,
           nullptr, gate, 1024, 512,  tb, 2048,  1024, 512,  0, 0, 2 * c, 256, k);
      gemm(xrot_t + off * 128, 6272, k, 1, tw[8] + (long long)(m - 1) * 196608, 768,
           nullptr, gate, 1024, 768,  tb, 2048, -1024, 1792, 0, 0, 2 * c, 256, k);
      gemm(tb, 2048, 0, 0, b2a + ofs2[m][0], 1024, nullptr, nullptr, 0, 0,
           msgp, 6272, 0, off * 128, 0, 0, c, k, 1024);
      gemm(tb + 1024, 2048, 0, 0, b2a + ofs2[m][1], 1024, nullptr, nullptr, 0, 0,
           msgp, 6272, 0, (off + n) * 128, 0, 0, c, k, 1024);
    }
    // grid activation + inverse rotation
    small(13, to_grid, 0, 1, 98, 49, msgp, 6272, ggrid, 12544, 128, 0, nullptr, 1, c);
    small(7, from_grid, 0, 0, 49, 98, ggrid, 12544, msgp, 6272, 128, 0, nullptr, 0, c);
    small(7, wiginv + (long long)e0 * 2401, 1, 0, 49, 49, msgp, 6272,
          msg3, 6272, 128, 0, nullptr, 0, c);
    k_scatter<<<AN, dim3(256), 0, stream>>>(msg3, eidx + EN + e0, xmsg, c, e0 > 0);
  }

  // 3) atom phase
  for (int a0 = 0; a0 < AN; a0 += ca) {
    gemm(x + (long long)a0 * 6272, 128, 0, 0, ws1, 256, nullptr, nullptr, 0, 0,
         hb, 128, 0, 0, 0, 0, ca * 49, 128, 128);
    gemm(xmsg + (long long)a0 * 6272, 128, 0, 0, ws1 + 128, 256, nullptr, nullptr, 0, 0,
         hb, 128, 0, 0, 1, 0, ca * 49, 128, 128);
    small(13, to_grid, 0, 0, 98, 49, hb, 6272, g1, 12544, 128, 0, bs1, 1, ca);
    gemm(g1, 128, 0, 0, ws2, 128, bs2, nullptr, 0, 0,
         g2, 128, 0, 0, 0, 1, ca * 98, 128, 128);
    gemm(g2, 128, 0, 0, ws3, 128, bs3, nullptr, 0, 0,
         g3, 128, 0, 0, 0, 0, ca * 98, 128, 128);
    small(7, from_grid, 0, 0, 49, 98, g3, 12544, outp + (long long)a0 * 6272,
          6272, 128, 0, nullptr, 0, ca);
  }
}

// Round 4
// 4377.782 us; speedup vs baseline: 4.9447x; 2.1380x over previous
//
#include <hip/hip_runtime.h>
#include <string.h>

#define EN 8000
#define AN 800

typedef __attribute__((ext_vector_type(8))) short bf16x8;
typedef __attribute__((ext_vector_type(4))) float f32x4;
typedef unsigned short ushort_t;
typedef unsigned int uint32;

__constant__ int c_perm[49] = {
  0,2,6,12,20,30,42,
  1,5,11,19,29,41,
  3,7,13,21,31,43,
  4,10,18,28,40,
  8,14,22,32,44,
  9,17,27,39,
  15,23,33,45,
  16,26,38,
  24,34,46,
  25,37,
  35,47,
  36,
  48
};

__device__ __forceinline__ float siluf(float x) { return x / (1.0f + __expf(-x)); }
__device__ __forceinline__ void fma4(float4& a, float w, const float4& v) {
  a.x += w * v.x; a.y += w * v.y; a.z += w * v.z; a.w += w * v.w;
}
__device__ __forceinline__ ushort_t f2bf(float f) {
  uint32 u = __float_as_uint(f);
  u += 0x7fff + ((u >> 16) & 1);
  return (ushort_t)(u >> 16);
}
__device__ __forceinline__ float bf2f(ushort_t h) {
  return __uint_as_float(((uint32)h) << 16);
}
__device__ __forceinline__ uint32 pk2(float a, float b) {
  return (uint32)f2bf(a) | ((uint32)f2bf(b) << 16);
}

// ---------------------------------------------------------------------------
// Weight-concat builders
// ---------------------------------------------------------------------------
__global__ __launch_bounds__(256) void k_build_b2(
    const float* __restrict__ sw2r, const float* __restrict__ sw2i,
    const float* __restrict__ tw2r, const float* __restrict__ tw2i,
    float* __restrict__ dst)
{
  long long id = (long long)blockIdx.x * 256 + threadIdx.x;
  if (id >= 5505024LL) return;
  long long base = 0; int m = 1, k = 768;
  for (; m <= 6; ++m) {
    k = (7 - m) * 128;
    long long sz = 2LL * k * 1024;
    if (id < base + sz) break;
    base += sz;
  }
  long long rem = id - base;
  int p = (int)(rem / ((long long)k * 1024));
  int cj = (int)(rem - (long long)p * k * 1024);
  int c = cj >> 10, j = cj & 1023;
  int q = j >> 8, jj = j & 255;
  const float sgn = (q & 1) ? (p ? 1.f : -1.f) : 1.f;
  const float* src = (q < 2) ? (q == 0 ? sw2r : sw2i) : (q == 2 ? tw2r : tw2i);
  dst[id] = sgn * src[(long long)(m - 1) * 196608 + c * 256 + jj];
}

__global__ __launch_bounds__(256) void k_build_bgcat(
    const float* __restrict__ sw0, const float* __restrict__ tw0,
    const float* __restrict__ sw4, const float* __restrict__ tw4,
    const float* __restrict__ sb0, const float* __restrict__ tb0b,
    const float* __restrict__ sbd, const float* __restrict__ tbd,
    float* __restrict__ w, float* __restrict__ b)
{
  int id = blockIdx.x * 256 + threadIdx.x;
  if (id < 851968) {
    int r = id >> 7, c = id & 127;
    float v;
    if (r < 256) v = sw0[r * 128 + c];
    else if (r < 512) v = tw0[(r - 256) * 128 + c];
    else {
      int rr = r - 512, m = rr >> 10, q = rr & 1023;
      v = (q < 512) ? sw4[m * 65536 + q * 128 + c] : tw4[m * 65536 + (q - 512) * 128 + c];
    }
    w[id] = v;
    return;
  }
  id -= 851968;
  if (id < 6656) {
    float v;
    if (id < 256) v = sb0[id];
    else if (id < 512) v = tb0b[id - 256];
    else {
      int rr = id - 512, m = rr >> 10, q = rr & 1023;
      v = (q < 512) ? sbd[m * 512 + q] : tbd[m * 512 + (q - 512)];
    }
    b[id] = v;
  }
}

__global__ __launch_bounds__(256) void k_build_b20(
    const float* __restrict__ sw3, const float* __restrict__ tw3,
    float* __restrict__ b20)
{
  int id = blockIdx.x * 256 + threadIdx.x;
  if (id >= 458752) return;
  int cc = id >> 9, j = id & 511;
  b20[id] = (j < 256) ? sw3[cc * 256 + j] : tw3[cc * 256 + (j - 256)];
}

// ---------------------------------------------------------------------------
// Edge features
// ---------------------------------------------------------------------------
__global__ __launch_bounds__(256) void k_basis(
    const float* __restrict__ dist, float* __restrict__ basis)
{
  int id = blockIdx.x * 256 + threadIdx.x;
  if (id >= EN * 512) return;
  int e = id >> 9, g = id & 511;
  const float step = 8.0f / 511.0f;
  const float coeff = -2040.0078125f;
  float df = dist[e] - (float)g * step;
  basis[id] = expf(coeff * df * df);
}

__global__ __launch_bounds__(256) void k_emb(
    const float* __restrict__ src_emb, const float* __restrict__ tgt_emb,
    const int* __restrict__ anum, const int* __restrict__ eidx,
    float* __restrict__ xd)
{
  int id = blockIdx.x * 256 + threadIdx.x;
  if (id >= EN * 128) return;
  int e = id >> 7, c = id & 127;
  int a0 = anum[eidx[e]], a1 = anum[eidx[EN + e]];
  xd[id] = siluf(src_emb[a0 * 128 + c] + tgt_emb[a1 * 128 + c] + xd[id]);
}

// ---------------------------------------------------------------------------
// Wigner rotation (PERM-folded rows), bf16 output
// ---------------------------------------------------------------------------
__global__ __launch_bounds__(256) void k_rot(
    const float* __restrict__ wig, const float* __restrict__ x,
    const int* __restrict__ srcl, const int* __restrict__ tgtl,
    ushort_t* __restrict__ osrc, ushort_t* __restrict__ otgt)
{
  const int e = blockIdx.x, t = threadIdx.x;
  __shared__ __align__(16) float wl[49 * 52];
  __shared__ __align__(16) float xs[49 * 128];
  __shared__ __align__(16) float xt[49 * 128];
  const float* wge = wig + (long long)e * 2401;
  for (int l = t; l < 2401; l += 256) {
    int q = l / 49, j = l - q * 49;
    wl[q * 52 + j] = wge[c_perm[q] * 49 + j];
  }
  const int asrc = srcl[e], atgt = tgtl[e];
  const float4* xsg = (const float4*)(x + (long long)asrc * 6272);
  const float4* xtg = (const float4*)(x + (long long)atgt * 6272);
  float4* xs4 = (float4*)xs;
  float4* xt4 = (float4*)xt;
  for (int l = t; l < 49 * 32; l += 256) { xs4[l] = xsg[l]; xt4[l] = xtg[l]; }
  __syncthreads();
  const int ct = t & 31, rt = t >> 5;
  if (rt >= 7) return;
  float4 accs[7], acct[7];
  #pragma unroll
  for (int u = 0; u < 7; ++u) {
    accs[u] = make_float4(0.f, 0.f, 0.f, 0.f);
    acct[u] = make_float4(0.f, 0.f, 0.f, 0.f);
  }
  for (int j0 = 0; j0 < 48; j0 += 4) {
    float4 v0s = xs4[(j0 + 0) * 32 + ct];
    float4 v1s = xs4[(j0 + 1) * 32 + ct];
    float4 v2s = xs4[(j0 + 2) * 32 + ct];
    float4 v3s = xs4[(j0 + 3) * 32 + ct];
    float4 v0t = xt4[(j0 + 0) * 32 + ct];
    float4 v1t = xt4[(j0 + 1) * 32 + ct];
    float4 v2t = xt4[(j0 + 2) * 32 + ct];
    float4 v3t = xt4[(j0 + 3) * 32 + ct];
    #pragma unroll
    for (int u = 0; u < 7; ++u) {
      const float4 w = *(const float4*)(wl + (rt * 7 + u) * 52 + j0);
      fma4(accs[u], w.x, v0s); fma4(accs[u], w.y, v1s);
      fma4(accs[u], w.z, v2s); fma4(accs[u], w.w, v3s);
      fma4(acct[u], w.x, v0t); fma4(acct[u], w.y, v1t);
      fma4(acct[u], w.z, v2t); fma4(acct[u], w.w, v3t);
    }
  }
  {
    float4 vs = xs4[48 * 32 + ct], vt = xt4[48 * 32 + ct];
    #pragma unroll
    for (int u = 0; u < 7; ++u) {
      float w = wl[(rt * 7 + u) * 52 + 48];
      fma4(accs[u], w, vs); fma4(acct[u], w, vt);
    }
  }
  #pragma unroll
  for (int u = 0; u < 7; ++u) {
    int q = rt * 7 + u;
    ushort_t* os = osrc + (long long)e * 6272 + q * 128 + ct * 4;
    ushort_t* ot = otgt + (long long)e * 6272 + q * 128 + ct * 4;
    uint2 ps, pt;
    ps.x = pk2(accs[u].x, accs[u].y); ps.y = pk2(accs[u].z, accs[u].w);
    pt.x = pk2(acct[u].x, acct[u].y); pt.y = pk2(acct[u].z, acct[u].w);
    *(uint2*)os = ps;
    *(uint2*)ot = pt;
  }
}

// ---------------------------------------------------------------------------
// Grouped MFMA GEMM: C = epi(A @ B^T)
// A: bf16 or f32, optional row-pair addressing, optional K-split (A2).
// B: f32 weights, optional row-split (B2). Epilogue: bias, silu, bf16-gate,
// parity-flip (ihalf) for fused r|i stage-1, bf16 or f32 C.
// ---------------------------------------------------------------------------
struct GemmP {
  const void* A; const void* A2; const float* B; const float* B2;
  const float* bias; const ushort_t* gate; void* C;
  int a_se, a_si, pair, asplit, a_bf16;
  int ldb, bsplit;
  int gate_ofs;
  int c_se, c_si, c_ofs;
  int ihalf, act, c_bf16;
  int M, N, K;
  int ngx, wg_base;
};
struct Grouped { GemmP d[14]; int nd; };

#define LDW 40

__global__ __launch_bounds__(256) void gemm_g(Grouped G) {
  __shared__ short As[128 * LDW];
  __shared__ short Bs[128 * LDW];
  const int bid = blockIdx.x;
  int di = G.nd - 1;
  for (int i = 1; i < G.nd; ++i) if (bid < G.d[i].wg_base) { di = i - 1; break; }
  const GemmP p = G.d[di];
  const int local = bid - p.wg_base;
  const int bx = local % p.ngx, by = local / p.ngx;
  const int m0 = bx << 7, n0 = by << 7;

  const int tid = threadIdx.x;
  const int srow = tid >> 1, sk = (tid & 1) << 4;
  const int lane = tid & 63, wave = tid >> 6;
  const int wm = (wave >> 1) << 6, wn = (wave & 1) << 6;
  const int fr = lane & 15, fk = (lane >> 4) << 3;

  f32x4 acc[4][4];
  #pragma unroll
  for (int i = 0; i < 4; ++i)
    #pragma unroll
    for (int j = 0; j < 4; ++j) acc[i][j] = (f32x4){0.f, 0.f, 0.f, 0.f};

  for (int k0 = 0; k0 < p.K; k0 += 32) {
    // stage A
    {
      bf16x8 lo = (bf16x8)0, hi = (bf16x8)0;
      int r = m0 + srow;
      if (r < p.M) {
        long long base;
        if (p.pair) base = (long long)(r >> 1) * p.a_se + (long long)(r & 1) * p.a_si;
        else        base = (long long)r * p.a_se;
        int kk = k0 + sk;
        const void* Ap = p.A;
        if (p.A2 && kk >= p.asplit) { Ap = p.A2; kk -= p.asplit; }
        if (p.a_bf16) {
          const ushort_t* ap = (const ushort_t*)Ap + base + kk;
          lo = *(const bf16x8*)ap;
          hi = *(const bf16x8*)(ap + 8);
        } else {
          const float4* ap = (const float4*)((const float*)Ap + base + kk);
          float4 a0 = ap[0], a1 = ap[1], a2 = ap[2], a3 = ap[3];
          lo[0]=(short)f2bf(a0.x); lo[1]=(short)f2bf(a0.y); lo[2]=(short)f2bf(a0.z); lo[3]=(short)f2bf(a0.w);
          lo[4]=(short)f2bf(a1.x); lo[5]=(short)f2bf(a1.y); lo[6]=(short)f2bf(a1.z); lo[7]=(short)f2bf(a1.w);
          hi[0]=(short)f2bf(a2.x); hi[1]=(short)f2bf(a2.y); hi[2]=(short)f2bf(a2.z); hi[3]=(short)f2bf(a2.w);
          hi[4]=(short)f2bf(a3.x); hi[5]=(short)f2bf(a3.y); hi[6]=(short)f2bf(a3.z); hi[7]=(short)f2bf(a3.w);
        }
      }
      *(bf16x8*)&As[srow * LDW + sk] = lo;
      *(bf16x8*)&As[srow * LDW + sk + 8] = hi;
    }
    // stage B
    {
      bf16x8 lo = (bf16x8)0, hi = (bf16x8)0;
      int rn = n0 + srow;
      if (rn < p.N) {
        const float* bp = (p.B2 && rn >= p.bsplit)
            ? p.B2 + (long long)(rn - p.bsplit) * p.ldb
            : p.B + (long long)rn * p.ldb;
        const float4* ap = (const float4*)(bp + k0 + sk);
        float4 a0 = ap[0], a1 = ap[1], a2 = ap[2], a3 = ap[3];
        lo[0]=(short)f2bf(a0.x); lo[1]=(short)f2bf(a0.y); lo[2]=(short)f2bf(a0.z); lo[3]=(short)f2bf(a0.w);
        lo[4]=(short)f2bf(a1.x); lo[5]=(short)f2bf(a1.y); lo[6]=(short)f2bf(a1.z); lo[7]=(short)f2bf(a1.w);
        hi[0]=(short)f2bf(a2.x); hi[1]=(short)f2bf(a2.y); hi[2]=(short)f2bf(a2.z); hi[3]=(short)f2bf(a2.w);
        hi[4]=(short)f2bf(a3.x); hi[5]=(short)f2bf(a3.y); hi[6]=(short)f2bf(a3.z); hi[7]=(short)f2bf(a3.w);
      }
      *(bf16x8*)&Bs[srow * LDW + sk] = lo;
      *(bf16x8*)&Bs[srow * LDW + sk + 8] = hi;
    }
    __syncthreads();
    bf16x8 af[4], bfv[4];
    #pragma unroll
    for (int i = 0; i < 4; ++i) {
      af[i]  = *(const bf16x8*)(&As[(wm + i * 16 + fr) * LDW + fk]);
      bfv[i] = *(const bf16x8*)(&Bs[(wn + i * 16 + fr) * LDW + fk]);
    }
    #pragma unroll
    for (int i = 0; i < 4; ++i)
      #pragma unroll
      for (int j = 0; j < 4; ++j)
        acc[i][j] = __builtin_amdgcn_mfma_f32_16x16x32_bf16(af[i], bfv[j], acc[i][j], 0, 0, 0);
    __syncthreads();
  }

  const int crl = (lane >> 4) << 2, ccl = lane & 15;
  #pragma unroll
  for (int mi = 0; mi < 4; ++mi) {
    #pragma unroll
    for (int r = 0; r < 4; ++r) {
      int gr = m0 + wm + mi * 16 + crl + r;
      if (gr >= p.M) continue;
      long long e; int ii;
      if (p.pair) { e = gr >> 1; ii = gr & 1; } else { e = gr; ii = 0; }
      const ushort_t* grow = p.gate ? p.gate + e * 6656 + p.gate_ofs : nullptr;
      #pragma unroll
      for (int ni = 0; ni < 4; ++ni) {
        int gc = n0 + wn + ni * 16 + ccl;
        if (gc >= p.N) continue;
        float v = acc[mi][ni][r];
        if (p.bias) v += p.bias[gc];
        if (p.act)  v = siluf(v);
        if (grow)   v *= bf2f(grow[gc]);
        int par = (p.ihalf && gc >= 256) ? (1 - ii) : ii;
        long long co = e * (long long)p.c_se + (long long)par * p.c_si + p.c_ofs + gc;
        if (p.c_bf16) ((ushort_t*)p.C)[co] = f2bf(v);
        else          ((float*)p.C)[co] = v;
      }
    }
  }
}

// ---------------------------------------------------------------------------
// gridmm: C[b, gr, c] = epi( sum_k A[gr, k] * IN[b, k, c] ), MFMA.
// A: small f32 (M<=128, K<=128), optional col-perm. IN/C: bf16 (or f32 C).
// One block per item b (TN=128 channels).
// ---------------------------------------------------------------------------
struct GridP {
  const float* A; const ushort_t* B; void* C; const float* bias;
  int b_ib, c_ib;
  int M, K, permA, act, c_bf16;
};

__global__ __launch_bounds__(256) void gridmm(GridP p) {
  __shared__ short As[128 * LDW];
  __shared__ short Bs[128 * LDW];
  const int e = blockIdx.x;
  const int tid = threadIdx.x;
  const int srow = tid >> 1, sk = (tid & 1) << 4;
  const int lane = tid & 63, wave = tid >> 6;
  const int wm = (wave >> 1) << 6, wn = (wave & 1) << 6;
  const int fr = lane & 15, fk = (lane >> 4) << 3;

  f32x4 acc[4][4];
  #pragma unroll
  for (int i = 0; i < 4; ++i)
    #pragma unroll
    for (int j = 0; j < 4; ++j) acc[i][j] = (f32x4){0.f, 0.f, 0.f, 0.f};

  const ushort_t* bp0 = p.B + (long long)e * p.b_ib;

  for (int k0 = 0; k0 < p.K; k0 += 32) {
    // stage A (small f32, optional perm cols)
    {
      bf16x8 lo = (bf16x8)0, hi = (bf16x8)0;
      if (srow < p.M) {
        const float* ar = p.A + srow * p.K;
        #pragma unroll
        for (int j = 0; j < 8; ++j) {
          int col = k0 + sk + j;
          float v = 0.f;
          if (col < p.K) v = ar[p.permA ? c_perm[col] : col];
          lo[j] = (short)f2bf(v);
        }
        #pragma unroll
        for (int j = 0; j < 8; ++j) {
          int col = k0 + sk + 8 + j;
          float v = 0.f;
          if (col < p.K) v = ar[p.permA ? c_perm[col] : col];
          hi[j] = (short)f2bf(v);
        }
      }
      *(bf16x8*)&As[srow * LDW + sk] = lo;
      *(bf16x8*)&As[srow * LDW + sk + 8] = hi;
    }
    // stage B: transposed strided bf16 reads -> Bs[c][k]
    {
      const int c = tid & 127, kq = tid >> 7;
      #pragma unroll
      for (int i = 0; i < 8; ++i) {
        int kk = kq * 16 + i * 2;
        int k1 = k0 + kk, k2 = k1 + 1;
        uint32 v0 = (k1 < p.K) ? (uint32)bp0[(long long)k1 * 128 + c] : 0u;
        uint32 v1 = (k2 < p.K) ? (uint32)bp0[(long long)k2 * 128 + c] : 0u;
        *(uint32*)&Bs[c * LDW + kk] = v0 | (v1 << 16);
      }
    }
    __syncthreads();
    bf16x8 af[4], bfv[4];
    #pragma unroll
    for (int i = 0; i < 4; ++i) {
      af[i]  = *(const bf16x8*)(&As[(wm + i * 16 + fr) * LDW + fk]);
      bfv[i] = *(const bf16x8*)(&Bs[(wn + i * 16 + fr) * LDW + fk]);
    }
    #pragma unroll
    for (int i = 0; i < 4; ++i)
      #pragma unroll
      for (int j = 0; j < 4; ++j)
        acc[i][j] = __builtin_amdgcn_mfma_f32_16x16x32_bf16(af[i], bfv[j], acc[i][j], 0, 0, 0);
    __syncthreads();
  }

  const int crl = (lane >> 4) << 2, ccl = lane & 15;
  #pragma unroll
  for (int mi = 0; mi < 4; ++mi) {
    #pragma unroll
    for (int r = 0; r < 4; ++r) {
      int gr = wm + mi * 16 + crl + r;
      if (gr >= p.M) continue;
      #pragma unroll
      for (int ni = 0; ni < 4; ++ni) {
        int c = wn + ni * 16 + ccl;
        float v = acc[mi][ni][r];
        if (p.bias) v += p.bias[c];
        if (p.act)  v = siluf(v);
        long long co = (long long)e * p.c_ib + gr * 128 + c;
        if (p.c_bf16) ((ushort_t*)p.C)[co] = f2bf(v);
        else          ((float*)p.C)[co] = v;
      }
    }
  }
}

// ---------------------------------------------------------------------------
// wigner_inv per-edge small matmul: bf16 in/out, f32 compute
// ---------------------------------------------------------------------------
__global__ __launch_bounds__(256) void k_wiginv(
    const float* __restrict__ wig, const ushort_t* __restrict__ in,
    ushort_t* __restrict__ out)
{
  __shared__ __align__(16) float Ws[49 * 52];
  __shared__ __align__(16) float In[49 * 128];
  const int e = blockIdx.x, t = threadIdx.x;
  const float* wge = wig + (long long)e * 2401;
  for (int l = t; l < 2401; l += 256) {
    int r = l / 49, s = l - r * 49;
    Ws[r * 52 + s] = wge[l];
  }
  const ushort_t* ie = in + (long long)e * 6272;
  for (int l = t; l < 6272; l += 256) In[l] = bf2f(ie[l]);
  __syncthreads();
  const int ct = t & 31, rt = t >> 5;
  float4 acc[7];
  #pragma unroll
  for (int u = 0; u < 7; ++u) acc[u] = make_float4(0.f, 0.f, 0.f, 0.f);
  const float4* In4 = (const float4*)In;
  for (int s = 0; s < 48; s += 4) {
    float4 v0 = In4[(s + 0) * 32 + ct];
    float4 v1 = In4[(s + 1) * 32 + ct];
    float4 v2 = In4[(s + 2) * 32 + ct];
    float4 v3 = In4[(s + 3) * 32 + ct];
    #pragma unroll
    for (int u = 0; u < 7; ++u) {
      int r = rt + (u << 3);
      if (r < 49) {
        const float4 w = *(const float4*)(Ws + r * 52 + s);
        fma4(acc[u], w.x, v0); fma4(acc[u], w.y, v1);
        fma4(acc[u], w.z, v2); fma4(acc[u], w.w, v3);
      }
    }
  }
  {
    float4 v = In4[48 * 32 + ct];
    #pragma unroll
    for (int u = 0; u < 7; ++u) {
      int r = rt + (u << 3);
      if (r < 49) fma4(acc[u], Ws[r * 52 + 48], v);
    }
  }
  #pragma unroll
  for (int u = 0; u < 7; ++u) {
    int r = rt + (u << 3);
    if (r < 49) {
      ushort_t* oe = out + (long long)e * 6272 + r * 128 + ct * 4;
      uint2 pw;
      pw.x = pk2(acc[u].x, acc[u].y);
      pw.y = pk2(acc[u].z, acc[u].w);
      *(uint2*)oe = pw;
    }
  }
}

// ---------------------------------------------------------------------------
// Segment-sum: grid (AN, 8); bf16 msg3 -> f32 xmsg
// ---------------------------------------------------------------------------
__global__ __launch_bounds__(256) void k_scatter2(
    const ushort_t* __restrict__ msg3, const int* __restrict__ tgt,
    float* __restrict__ xmsg, int c, int accum)
{
  const int a = blockIdx.x, part = blockIdx.y, t = threadIdx.x;
  __shared__ int tl[EN];
  for (int l = t; l < c; l += 256) tl[l] = tgt[l];
  __syncthreads();
  float acc[4] = {0.f, 0.f, 0.f, 0.f};
  const int base = part * 784;
  for (int e = 0; e < c; ++e) {
    if (tl[e] == a) {
      const ushort_t* m = msg3 + (long long)e * 6272 + base;
      #pragma unroll
      for (int u = 0; u < 4; ++u) {
        int idx = t + (u << 8);
        if (idx < 784) acc[u] += bf2f(m[idx]);
      }
    }
  }
  float* o = xmsg + (long long)a * 6272 + base;
  #pragma unroll
  for (int u = 0; u < 4; ++u) {
    int idx = t + (u << 8);
    if (idx < 784) {
      if (accum) o[idx] += acc[u]; else o[idx] = acc[u];
    }
  }
}

// ---------------------------------------------------------------------------
// Host orchestration
// ---------------------------------------------------------------------------
extern "C" void kernel_launch(void* const* d_in, const int* in_sizes, int n_in,
                              void* d_out, int out_size, void* d_ws, size_t ws_size,
                              hipStream_t stream) {
  const float* x         = (const float*)d_in[0];
  const float* edist     = (const float*)d_in[1];
  const float* wigner    = (const float*)d_in[2];
  const float* wiginv    = (const float*)d_in[3];
  const float* to_grid   = (const float*)d_in[4];
  const float* from_grid = (const float*)d_in[5];
  const float* w_dist1   = (const float*)d_in[6];
  const float* b_dist1   = (const float*)d_in[7];
  const float* src_emb   = (const float*)d_in[8];
  const float* tgt_emb   = (const float*)d_in[9];
  const float* w_edge1   = (const float*)d_in[10];
  const float* b_edge1   = (const float*)d_in[11];
  const float* ws1       = (const float*)d_in[12];
  const float* bs1       = (const float*)d_in[13];
  const float* ws2       = (const float*)d_in[14];
  const float* bs2       = (const float*)d_in[15];
  const float* ws3       = (const float*)d_in[16];
  const float* bs3       = (const float*)d_in[17];
  const int*   anum      = (const int*)d_in[18];
  const int*   eidx      = (const int*)d_in[19];
  const float* sw[10]; const float* tw[10];
  for (int i = 0; i < 10; ++i) {
    sw[i] = (const float*)d_in[20 + i];
    tw[i] = (const float*)d_in[30 + i];
  }
  float* outp = (float*)d_out;

  // ---- workspace (f32 units; bf16 buffers cast) ----
  float* ws = (float*)d_ws;
  long long off = 0;
  auto alloc = [&](long long n) { float* pp = ws + off; off += n; return pp; };
  ushort_t* x_edge = (ushort_t*)alloc(512000);   // 8000x128 bf16
  float* b2a     = alloc(5505024);
  float* bgcat_w = alloc(851968);                // 6656 x 128
  float* bgcat_b = alloc(6656);
  float* b2_0    = alloc(458752);
  float* xmsg    = alloc(5017600);               // f32
  float* basis   = alloc(4096000);
  float* x_dist  = alloc(1024000);
  const long long fixedF = off;                  // 17,472,000
  float* arena = ws + fixedF;

  // chunk levels
  static const int ces[6] = {8000, 4000, 2000, 1000, 500, 250};
  static const int cas[6] = {800, 800, 800, 400, 200, 100};
  long long availF = (long long)(ws_size / 4);
  int ce = 250, ca = 100;
  for (int i = 0; i < 6; ++i) {
    long long ne = (long long)ces[i] * 19136;
    long long na = (long long)cas[i] * 21952;
    long long need = fixedF + (ne > na ? ne : na);
    if (need <= availF) { ce = ces[i]; ca = cas[i]; break; }
  }

  // edge-phase arena (bf16 unless noted)
  ushort_t* xrot_s = (ushort_t*)(arena);
  ushort_t* xrot_t = (ushort_t*)(arena + (long long)ce * 3136);
  ushort_t* tb0    = (ushort_t*)(arena + (long long)ce * 6272);
  ushort_t* tbm    = (ushort_t*)(arena + (long long)ce * 6528);
  ushort_t* msgp   = (ushort_t*)(arena + (long long)ce * 12672);
  ushort_t* gate   = (ushort_t*)(arena + (long long)ce * 15808);
  ushort_t* ggrid  = (ushort_t*)(arena);   // overlays xrot (ce*12544 bf16)
  ushort_t* msg3   = (ushort_t*)(arena);   // overlays ggrid
  // atom-phase arena
  ushort_t* hb = (ushort_t*)(arena);
  ushort_t* g1 = (ushort_t*)(arena + (long long)ca * 3136);
  ushort_t* g2 = (ushort_t*)(arena + (long long)ca * 9408);
  ushort_t* g3 = (ushort_t*)(arena + (long long)ca * 15680);

  long long ofs2[7][2];
  { long long cur = 0;
    for (int m = 1; m <= 6; ++m) {
      int k = (7 - m) * 128;
      ofs2[m][0] = cur; cur += (long long)k * 1024;
      ofs2[m][1] = cur; cur += (long long)k * 1024;
    } }

  auto D0 = []() { GemmP p; memset(&p, 0, sizeof(p)); p.asplit = 1 << 30; p.bsplit = 1 << 30; return p; };
  auto finalize = [&](Grouped& G) {
    int base = 0;
    for (int i = 0; i < G.nd; ++i) {
      GemmP& p = G.d[i];
      p.ngx = (p.M + 127) >> 7;
      int ngy = (p.N + 127) >> 7;
      p.wg_base = base;
      base += p.ngx * ngy;
    }
    gemm_g<<<base, 256, 0, stream>>>(G);
  };
  auto run1 = [&](GemmP p) { Grouped G; G.d[0] = p; G.nd = 1; finalize(G); };
  auto rungrid = [&](const float* A, int M, int K, int permA,
                     const ushort_t* B, int b_ib, void* C, int c_ib,
                     const float* bias, int act, int c_bf16, int nb) {
    GridP p;
    p.A = A; p.B = B; p.C = C; p.bias = bias;
    p.b_ib = b_ib; p.c_ib = c_ib;
    p.M = M; p.K = K; p.permA = permA; p.act = act; p.c_bf16 = c_bf16;
    gridmm<<<nb, 256, 0, stream>>>(p);
  };

  // 0) builds
  k_build_b2<<<(5505024 + 255) / 256, 256, 0, stream>>>(sw[7], sw[9], tw[7], tw[9], b2a);
  k_build_bgcat<<<(858624 + 255) / 256, 256, 0, stream>>>(
      sw[0], tw[0], sw[4], tw[4], sw[1], tw[1], sw[5], tw[5], bgcat_w, bgcat_b);
  k_build_b20<<<(458752 + 255) / 256, 256, 0, stream>>>(sw[3], tw[3], b2_0);

  // 1) edge features
  k_basis<<<(EN * 512 + 255) / 256, 256, 0, stream>>>(edist, basis);
  { GemmP p = D0();
    p.A = basis; p.a_se = 512; p.B = w_dist1; p.ldb = 512; p.bias = b_dist1;
    p.C = x_dist; p.c_se = 128; p.M = EN; p.N = 128; p.K = 512;
    run1(p); }
  k_emb<<<(EN * 128 + 255) / 256, 256, 0, stream>>>(src_emb, tgt_emb, anum, eidx, x_dist);
  { GemmP p = D0();
    p.A = x_dist; p.a_se = 128; p.B = w_edge1; p.ldb = 128; p.bias = b_edge1;
    p.act = 1; p.C = x_edge; p.c_se = 128; p.c_bf16 = 1; p.M = EN; p.N = 128; p.K = 128;
    run1(p); }

  static const int offq[7] = {0, 7, 19, 29, 37, 43, 47};

  // 2) edge chunks
  for (int e0 = 0; e0 < EN; e0 += ce) {
    const int c = ce;
    k_rot<<<c, 256, 0, stream>>>(wigner + (long long)e0 * 2401, x,
                                 eidx + e0, eidx + EN + e0, xrot_s, xrot_t);
    // gates: one GEMM, N=6656
    { GemmP p = D0();
      p.A = x_edge + (long long)e0 * 128; p.a_se = 128; p.a_bf16 = 1;
      p.B = bgcat_w; p.ldb = 128; p.bias = bgcat_b; p.act = 1;
      p.C = gate; p.c_se = 6656; p.c_bf16 = 1;
      p.M = c; p.N = 6656; p.K = 128;
      run1(p); }
    // stage 1: grouped (m0 s,t + 12 fused r|i)
    { Grouped G; G.nd = 14;
      for (int s = 0; s < 2; ++s) {
        GemmP p = D0();
        p.A = s ? xrot_t : xrot_s; p.a_se = 6272; p.a_bf16 = 1;
        p.B = s ? tw[2] : sw[2]; p.ldb = 896;
        p.gate = gate; p.gate_ofs = s * 256;
        p.C = tb0; p.c_se = 512; p.c_ofs = s * 256; p.c_bf16 = 1;
        p.M = c; p.N = 256; p.K = 896;
        G.d[s] = p;
      }
      int di = 2;
      for (int m = 1; m <= 6; ++m) {
        const int n = 7 - m, k = n * 128, off = offq[m];
        for (int s = 0; s < 2; ++s) {
          GemmP p = D0();
          p.A = (s ? xrot_t : xrot_s) + off * 128;
          p.a_se = 6272; p.a_si = k; p.pair = 1; p.a_bf16 = 1;
          p.B  = (s ? tw[6] : sw[6]) + (long long)(m - 1) * 196608; p.ldb = 768;
          p.B2 = (s ? tw[8] : sw[8]) + (long long)(m - 1) * 196608; p.bsplit = 256;
          p.gate = gate; p.gate_ofs = 512 + (m - 1) * 1024 + s * 512;
          p.C = tbm; p.c_se = 12288; p.c_si = 1024;
          p.c_ofs = (m - 1) * 2048 + s * 512;
          p.ihalf = 1; p.c_bf16 = 1;
          p.M = 2 * c; p.N = 512; p.K = k;
          G.d[di++] = p;
        }
      }
      finalize(G); }
    // stage 2: grouped (m0 + 12 parity)
    { Grouped G; G.nd = 13;
      { GemmP p = D0();
        p.A = tb0; p.a_se = 512; p.a_bf16 = 1;
        p.B = b2_0; p.ldb = 512;
        p.C = msgp; p.c_se = 6272; p.c_bf16 = 1;
        p.M = c; p.N = 896; p.K = 512;
        G.d[0] = p; }
      int di = 1;
      for (int m = 1; m <= 6; ++m) {
        const int n = 7 - m, k = n * 128, off = offq[m];
        for (int pp = 0; pp < 2; ++pp) {
          GemmP p = D0();
          p.A = tbm + (m - 1) * 2048 + pp * 1024; p.a_se = 12288; p.a_bf16 = 1;
          p.B = b2a + ofs2[m][pp]; p.ldb = 1024;
          p.C = msgp; p.c_se = 6272; p.c_ofs = (off + (pp ? n : 0)) * 128; p.c_bf16 = 1;
          p.M = c; p.N = k; p.K = 1024;
          G.d[di++] = p;
        }
      }
      finalize(G); }
    // grid activation + inverse rotation
    rungrid(to_grid, 98, 49, 1, msgp, 6272, ggrid, 12544, nullptr, 1, 1, c);
    rungrid(from_grid, 49, 98, 0, ggrid, 12544, msgp, 6272, nullptr, 0, 1, c);
    k_wiginv<<<c, 256, 0, stream>>>(wiginv + (long long)e0 * 2401, msgp, msg3);
    k_scatter2<<<dim3(AN, 8), 256, 0, stream>>>(msg3, eidx + EN + e0, xmsg, c, e0 > 0);
  }

  // 3) atom phase
  for (int a0 = 0; a0 < AN; a0 += ca) {
    { GemmP p = D0();
      p.A = x + (long long)a0 * 6272; p.A2 = xmsg + (long long)a0 * 6272;
      p.a_se = 128; p.asplit = 128;
      p.B = ws1; p.ldb = 256;
      p.C = hb; p.c_se = 128; p.c_bf16 = 1;
      p.M = ca * 49; p.N = 128; p.K = 256;
      run1(p); }
    rungrid(to_grid, 98, 49, 0, hb, 6272, g1, 12544, bs1, 1, 1, ca);
    { GemmP p = D0();
      p.A = g1; p.a_se = 128; p.a_bf16 = 1;
      p.B = ws2; p.ldb = 128; p.bias = bs2; p.act = 1;
      p.C = g2; p.c_se = 128; p.c_bf16 = 1;
      p.M = ca * 98; p.N = 128; p.K = 128;
      run1(p); }
    { GemmP p = D0();
      p.A = g2; p.a_se = 128; p.a_bf16 = 1;
      p.B = ws3; p.ldb = 128; p.bias = bs3;
      p.C = g3; p.c_se = 128; p.c_bf16 = 1;
      p.M = ca * 98; p.N = 128; p.K = 128;
      run1(p); }
    rungrid(from_grid, 49, 98, 0, g3, 12544, outp + (long long)a0 * 6272, 6272,
            nullptr, 0, 0, ca);
  }
}

// Round 5
// 1982.067 us; speedup vs baseline: 10.9212x; 2.2087x over previous
//
#include <hip/hip_runtime.h>
#include <string.h>

#define EN 8000
#define AN 800

typedef __attribute__((ext_vector_type(8))) short bf16x8;
typedef __attribute__((ext_vector_type(4))) float f32x4;
typedef unsigned short ushort_t;
typedef unsigned int uint32;

__constant__ int c_perm[49] = {
  0,2,6,12,20,30,42,
  1,5,11,19,29,41,
  3,7,13,21,31,43,
  4,10,18,28,40,
  8,14,22,32,44,
  9,17,27,39,
  15,23,33,45,
  16,26,38,
  24,34,46,
  25,37,
  35,47,
  36,
  48
};

__device__ __forceinline__ float siluf(float x) { return x / (1.0f + __expf(-x)); }
__device__ __forceinline__ void fma4(float4& a, float w, const float4& v) {
  a.x += w * v.x; a.y += w * v.y; a.z += w * v.z; a.w += w * v.w;
}
__device__ __forceinline__ ushort_t f2bf(float f) {
  uint32 u = __float_as_uint(f);
  u += 0x7fff + ((u >> 16) & 1);
  return (ushort_t)(u >> 16);
}
__device__ __forceinline__ float bf2f(ushort_t h) {
  return __uint_as_float(((uint32)h) << 16);
}
__device__ __forceinline__ uint32 pk2(float a, float b) {
  return (uint32)f2bf(a) | ((uint32)f2bf(b) << 16);
}
// XOR swizzle of 8-short (16B) groups within a row: low-3-bit XOR with row
#define SWZ8(cg, r) (((cg) ^ ((r) & 7)) & 7)
#define SWZ16(cg, r) (((cg) & 8) | (((cg) ^ (r)) & 7))

// ---------------------------------------------------------------------------
// Weight builders (bf16 outputs)
// ---------------------------------------------------------------------------
__global__ __launch_bounds__(256) void k_build_b2b(
    const float* __restrict__ sw2r, const float* __restrict__ sw2i,
    const float* __restrict__ tw2r, const float* __restrict__ tw2i,
    ushort_t* __restrict__ dst)
{
  long long id = (long long)blockIdx.x * 256 + threadIdx.x;
  if (id >= 5505024LL) return;
  long long base = 0; int m = 1, k = 768;
  for (; m <= 6; ++m) {
    k = (7 - m) * 128;
    long long sz = 2LL * k * 1024;
    if (id < base + sz) break;
    base += sz;
  }
  long long rem = id - base;
  int p = (int)(rem / ((long long)k * 1024));
  int cj = (int)(rem - (long long)p * k * 1024);
  int c = cj >> 10, j = cj & 1023;
  int q = j >> 8, jj = j & 255;
  const float sgn = (q & 1) ? (p ? 1.f : -1.f) : 1.f;
  const float* src = (q < 2) ? (q == 0 ? sw2r : sw2i) : (q == 2 ? tw2r : tw2i);
  dst[id] = f2bf(sgn * src[(long long)(m - 1) * 196608 + c * 256 + jj]);
}

__global__ __launch_bounds__(256) void k_build_bgcat(
    const float* __restrict__ sw0, const float* __restrict__ tw0,
    const float* __restrict__ sw4, const float* __restrict__ tw4,
    const float* __restrict__ sb0, const float* __restrict__ tb0b,
    const float* __restrict__ sbd, const float* __restrict__ tbd,
    ushort_t* __restrict__ w, float* __restrict__ b)
{
  int id = blockIdx.x * 256 + threadIdx.x;
  if (id < 851968) {
    int r = id >> 7, c = id & 127;
    float v;
    if (r < 256) v = sw0[r * 128 + c];
    else if (r < 512) v = tw0[(r - 256) * 128 + c];
    else {
      int rr = r - 512, m = rr >> 10, q = rr & 1023;
      v = (q < 512) ? sw4[m * 65536 + q * 128 + c] : tw4[m * 65536 + (q - 512) * 128 + c];
    }
    w[id] = f2bf(v);
    return;
  }
  id -= 851968;
  if (id < 6656) {
    float v;
    if (id < 256) v = sb0[id];
    else if (id < 512) v = tb0b[id - 256];
    else {
      int rr = id - 512, m = rr >> 10, q = rr & 1023;
      v = (q < 512) ? sbd[m * 512 + q] : tbd[m * 512 + (q - 512)];
    }
    b[id] = v;
  }
}

__global__ __launch_bounds__(256) void k_build_b20b(
    const float* __restrict__ sw3, const float* __restrict__ tw3,
    ushort_t* __restrict__ b20)
{
  int id = blockIdx.x * 256 + threadIdx.x;
  if (id >= 458752) return;
  int cc = id >> 9, j = id & 511;
  b20[id] = f2bf((j < 256) ? sw3[cc * 256 + j] : tw3[cc * 256 + (j - 256)]);
}

// pack stage-1 weights: per (m, s): [512][k]; rows 0..255 = w1r, 256..511 = w1i
__global__ __launch_bounds__(256) void k_build_s1m(
    const float* __restrict__ sw6, const float* __restrict__ sw8,
    const float* __restrict__ tw6, const float* __restrict__ tw8,
    ushort_t* __restrict__ dst)
{
  long long id = (long long)blockIdx.x * 256 + threadIdx.x;
  if (id >= 2752512LL) return;
  long long base = 0; int m = 1, k = 768;
  for (; m <= 6; ++m) {
    k = (7 - m) * 128;
    long long sz = 1024LL * k;
    if (id < base + sz) break;
    base += sz;
  }
  long long rem = id - base;
  int s = (int)(rem / (512LL * k));
  int rr = (int)(rem - (long long)s * 512 * k);
  int r = rr / k, c = rr - r * k;
  const float* src = (r < 256) ? (s ? tw6 : sw6) : (s ? tw8 : sw8);
  int r0 = (r < 256) ? r : r - 256;
  dst[id] = f2bf(src[(long long)(m - 1) * 196608 + r0 * 768 + c]);
}

__global__ __launch_bounds__(256) void k_cvt(
    const float* __restrict__ src, ushort_t* __restrict__ dst, int n)
{
  int id = blockIdx.x * 256 + threadIdx.x;
  if (id < n) dst[id] = f2bf(src[id]);
}

__global__ __launch_bounds__(256) void k_build_tg(
    const float* __restrict__ tg, ushort_t* __restrict__ dst)
{
  int id = blockIdx.x * 256 + threadIdx.x;
  if (id >= 98 * 49) return;
  int r = id / 49, s = id - r * 49;
  dst[id] = f2bf(tg[r * 49 + c_perm[s]]);
}

// ---------------------------------------------------------------------------
// Edge features
// ---------------------------------------------------------------------------
__global__ __launch_bounds__(256) void k_basis(
    const float* __restrict__ dist, float* __restrict__ basis)
{
  int id = blockIdx.x * 256 + threadIdx.x;
  if (id >= EN * 512) return;
  int e = id >> 9, g = id & 511;
  const float step = 8.0f / 511.0f;
  const float coeff = -2040.0078125f;
  float df = dist[e] - (float)g * step;
  basis[id] = expf(coeff * df * df);
}

__global__ __launch_bounds__(256) void k_emb(
    const float* __restrict__ src_emb, const float* __restrict__ tgt_emb,
    const int* __restrict__ anum, const int* __restrict__ eidx,
    float* __restrict__ xd)
{
  int id = blockIdx.x * 256 + threadIdx.x;
  if (id >= EN * 128) return;
  int e = id >> 7, c = id & 127;
  int a0 = anum[eidx[e]], a1 = anum[eidx[EN + e]];
  xd[id] = siluf(src_emb[a0 * 128 + c] + tgt_emb[a1 * 128 + c] + xd[id]);
}

// ---------------------------------------------------------------------------
// Wigner rotation (PERM-folded rows), bf16 out
// ---------------------------------------------------------------------------
__global__ __launch_bounds__(256) void k_rot(
    const float* __restrict__ wig, const float* __restrict__ x,
    const int* __restrict__ srcl, const int* __restrict__ tgtl,
    ushort_t* __restrict__ osrc, ushort_t* __restrict__ otgt)
{
  const int e = blockIdx.x, t = threadIdx.x;
  __shared__ __align__(16) float wl[49 * 52];
  __shared__ __align__(16) float xs[49 * 128];
  __shared__ __align__(16) float xt[49 * 128];
  const float* wge = wig + (long long)e * 2401;
  for (int l = t; l < 2401; l += 256) {
    int q = l / 49, j = l - q * 49;
    wl[q * 52 + j] = wge[c_perm[q] * 49 + j];
  }
  const int asrc = srcl[e], atgt = tgtl[e];
  const float4* xsg = (const float4*)(x + (long long)asrc * 6272);
  const float4* xtg = (const float4*)(x + (long long)atgt * 6272);
  float4* xs4 = (float4*)xs;
  float4* xt4 = (float4*)xt;
  for (int l = t; l < 49 * 32; l += 256) { xs4[l] = xsg[l]; xt4[l] = xtg[l]; }
  __syncthreads();
  const int ct = t & 31, rt = t >> 5;
  if (rt >= 7) return;
  float4 accs[7], acct[7];
  #pragma unroll
  for (int u = 0; u < 7; ++u) {
    accs[u] = make_float4(0.f, 0.f, 0.f, 0.f);
    acct[u] = make_float4(0.f, 0.f, 0.f, 0.f);
  }
  for (int j0 = 0; j0 < 48; j0 += 4) {
    float4 v0s = xs4[(j0 + 0) * 32 + ct];
    float4 v1s = xs4[(j0 + 1) * 32 + ct];
    float4 v2s = xs4[(j0 + 2) * 32 + ct];
    float4 v3s = xs4[(j0 + 3) * 32 + ct];
    float4 v0t = xt4[(j0 + 0) * 32 + ct];
    float4 v1t = xt4[(j0 + 1) * 32 + ct];
    float4 v2t = xt4[(j0 + 2) * 32 + ct];
    float4 v3t = xt4[(j0 + 3) * 32 + ct];
    #pragma unroll
    for (int u = 0; u < 7; ++u) {
      const float4 w = *(const float4*)(wl + (rt * 7 + u) * 52 + j0);
      fma4(accs[u], w.x, v0s); fma4(accs[u], w.y, v1s);
      fma4(accs[u], w.z, v2s); fma4(accs[u], w.w, v3s);
      fma4(acct[u], w.x, v0t); fma4(acct[u], w.y, v1t);
      fma4(acct[u], w.z, v2t); fma4(acct[u], w.w, v3t);
    }
  }
  {
    float4 vs = xs4[48 * 32 + ct], vt = xt4[48 * 32 + ct];
    #pragma unroll
    for (int u = 0; u < 7; ++u) {
      float w = wl[(rt * 7 + u) * 52 + 48];
      fma4(accs[u], w, vs); fma4(acct[u], w, vt);
    }
  }
  #pragma unroll
  for (int u = 0; u < 7; ++u) {
    int q = rt * 7 + u;
    ushort_t* os = osrc + (long long)e * 6272 + q * 128 + ct * 4;
    ushort_t* ot = otgt + (long long)e * 6272 + q * 128 + ct * 4;
    uint2 ps, pt;
    ps.x = pk2(accs[u].x, accs[u].y); ps.y = pk2(accs[u].z, accs[u].w);
    pt.x = pk2(acct[u].x, acct[u].y); pt.y = pk2(acct[u].z, acct[u].w);
    *(uint2*)os = ps;
    *(uint2*)ot = pt;
  }
}

// ---------------------------------------------------------------------------
// Grouped MFMA GEMM: C = epi(A @ B^T); B is bf16 [N][ldb]
// ---------------------------------------------------------------------------
struct GemmP {
  const void* A; const void* A2; const ushort_t* B;
  const float* bias; const ushort_t* gate; void* C;
  int a_se, a_si, pair, asplit, a_bf16;
  int ldb;
  int gate_ofs;
  int c_se, c_si, c_ofs;
  int ihalf, act, c_bf16;
  int M, N, K;
  int ngx, wg_base;
};
struct Grouped { GemmP d[14]; int nd; };

#define LDW 40

__global__ __launch_bounds__(256) void gemm_g(Grouped G) {
  __shared__ short As[128 * LDW];
  __shared__ short Bs[128 * LDW];
  const int bid = blockIdx.x;
  int di = G.nd - 1;
  for (int i = 1; i < G.nd; ++i) if (bid < G.d[i].wg_base) { di = i - 1; break; }
  const GemmP p = G.d[di];
  const int local = bid - p.wg_base;
  const int bx = local % p.ngx, by = local / p.ngx;
  const int m0 = bx << 7, n0 = by << 7;

  const int tid = threadIdx.x;
  const int srow = tid >> 1, sk = (tid & 1) << 4;
  const int lane = tid & 63, wave = tid >> 6;
  const int wm = (wave >> 1) << 6, wn = (wave & 1) << 6;
  const int fr = lane & 15, fk = (lane >> 4) << 3;

  f32x4 acc[4][4];
  #pragma unroll
  for (int i = 0; i < 4; ++i)
    #pragma unroll
    for (int j = 0; j < 4; ++j) acc[i][j] = (f32x4){0.f, 0.f, 0.f, 0.f};

  for (int k0 = 0; k0 < p.K; k0 += 32) {
    // stage A
    {
      bf16x8 lo = (bf16x8)0, hi = (bf16x8)0;
      int r = m0 + srow;
      if (r < p.M) {
        long long base;
        if (p.pair) base = (long long)(r >> 1) * p.a_se + (long long)(r & 1) * p.a_si;
        else        base = (long long)r * p.a_se;
        int kk = k0 + sk;
        const void* Ap = p.A;
        if (p.A2 && kk >= p.asplit) { Ap = p.A2; kk -= p.asplit; }
        if (p.a_bf16) {
          const ushort_t* ap = (const ushort_t*)Ap + base + kk;
          lo = *(const bf16x8*)ap;
          hi = *(const bf16x8*)(ap + 8);
        } else {
          const float4* ap = (const float4*)((const float*)Ap + base + kk);
          float4 a0 = ap[0], a1 = ap[1], a2 = ap[2], a3 = ap[3];
          lo[0]=(short)f2bf(a0.x); lo[1]=(short)f2bf(a0.y); lo[2]=(short)f2bf(a0.z); lo[3]=(short)f2bf(a0.w);
          lo[4]=(short)f2bf(a1.x); lo[5]=(short)f2bf(a1.y); lo[6]=(short)f2bf(a1.z); lo[7]=(short)f2bf(a1.w);
          hi[0]=(short)f2bf(a2.x); hi[1]=(short)f2bf(a2.y); hi[2]=(short)f2bf(a2.z); hi[3]=(short)f2bf(a2.w);
          hi[4]=(short)f2bf(a3.x); hi[5]=(short)f2bf(a3.y); hi[6]=(short)f2bf(a3.z); hi[7]=(short)f2bf(a3.w);
        }
      }
      *(bf16x8*)&As[srow * LDW + sk] = lo;
      *(bf16x8*)&As[srow * LDW + sk + 8] = hi;
    }
    // stage B (bf16 direct)
    {
      bf16x8 lo = (bf16x8)0, hi = (bf16x8)0;
      int rn = n0 + srow;
      if (rn < p.N) {
        const ushort_t* bp = p.B + (long long)rn * p.ldb + k0 + sk;
        lo = *(const bf16x8*)bp;
        hi = *(const bf16x8*)(bp + 8);
      }
      *(bf16x8*)&Bs[srow * LDW + sk] = lo;
      *(bf16x8*)&Bs[srow * LDW + sk + 8] = hi;
    }
    __syncthreads();
    bf16x8 af[4], bfv[4];
    #pragma unroll
    for (int i = 0; i < 4; ++i) {
      af[i]  = *(const bf16x8*)(&As[(wm + i * 16 + fr) * LDW + fk]);
      bfv[i] = *(const bf16x8*)(&Bs[(wn + i * 16 + fr) * LDW + fk]);
    }
    #pragma unroll
    for (int i = 0; i < 4; ++i)
      #pragma unroll
      for (int j = 0; j < 4; ++j)
        acc[i][j] = __builtin_amdgcn_mfma_f32_16x16x32_bf16(af[i], bfv[j], acc[i][j], 0, 0, 0);
    __syncthreads();
  }

  const int crl = (lane >> 4) << 2, ccl = lane & 15;
  #pragma unroll
  for (int mi = 0; mi < 4; ++mi) {
    #pragma unroll
    for (int r = 0; r < 4; ++r) {
      int gr = m0 + wm + mi * 16 + crl + r;
      if (gr >= p.M) continue;
      long long e; int ii;
      if (p.pair) { e = gr >> 1; ii = gr & 1; } else { e = gr; ii = 0; }
      const ushort_t* grow = p.gate ? p.gate + e * 6656 + p.gate_ofs : nullptr;
      #pragma unroll
      for (int ni = 0; ni < 4; ++ni) {
        int gc = n0 + wn + ni * 16 + ccl;
        if (gc >= p.N) continue;
        float v = acc[mi][ni][r];
        if (p.bias) v += p.bias[gc];
        if (p.act)  v = siluf(v);
        if (grow)   v *= bf2f(grow[gc]);
        int par = (p.ihalf && gc >= 256) ? (1 - ii) : ii;
        long long co = e * (long long)p.c_se + (long long)par * p.c_si + p.c_ofs + gc;
        if (p.c_bf16) ((ushort_t*)p.C)[co] = f2bf(v);
        else          ((float*)p.C)[co] = v;
      }
    }
  }
}

// ---------------------------------------------------------------------------
// gridmm (atom phase): C[b,gr,c] = epi(sum_k A[gr,k]*IN[b,k,c]) MFMA
// ---------------------------------------------------------------------------
struct GridP {
  const float* A; const ushort_t* B; void* C; const float* bias;
  int b_ib, c_ib;
  int M, K, permA, act, c_bf16;
};

__global__ __launch_bounds__(256) void gridmm(GridP p) {
  __shared__ short As[128 * LDW];
  __shared__ short Bs[128 * LDW];
  const int e = blockIdx.x;
  const int tid = threadIdx.x;
  const int srow = tid >> 1, sk = (tid & 1) << 4;
  const int lane = tid & 63, wave = tid >> 6;
  const int wm = (wave >> 1) << 6, wn = (wave & 1) << 6;
  const int fr = lane & 15, fk = (lane >> 4) << 3;

  f32x4 acc[4][4];
  #pragma unroll
  for (int i = 0; i < 4; ++i)
    #pragma unroll
    for (int j = 0; j < 4; ++j) acc[i][j] = (f32x4){0.f, 0.f, 0.f, 0.f};

  const ushort_t* bp0 = p.B + (long long)e * p.b_ib;

  for (int k0 = 0; k0 < p.K; k0 += 32) {
    {
      bf16x8 lo = (bf16x8)0, hi = (bf16x8)0;
      if (srow < p.M) {
        const float* ar = p.A + srow * p.K;
        #pragma unroll
        for (int j = 0; j < 8; ++j) {
          int col = k0 + sk + j;
          float v = 0.f;
          if (col < p.K) v = ar[p.permA ? c_perm[col] : col];
          lo[j] = (short)f2bf(v);
        }
        #pragma unroll
        for (int j = 0; j < 8; ++j) {
          int col = k0 + sk + 8 + j;
          float v = 0.f;
          if (col < p.K) v = ar[p.permA ? c_perm[col] : col];
          hi[j] = (short)f2bf(v);
        }
      }
      *(bf16x8*)&As[srow * LDW + sk] = lo;
      *(bf16x8*)&As[srow * LDW + sk + 8] = hi;
    }
    {
      const int c = tid & 127, kq = tid >> 7;
      #pragma unroll
      for (int i = 0; i < 8; ++i) {
        int kk = kq * 16 + i * 2;
        int k1 = k0 + kk, k2 = k1 + 1;
        uint32 v0 = (k1 < p.K) ? (uint32)bp0[(long long)k1 * 128 + c] : 0u;
        uint32 v1 = (k2 < p.K) ? (uint32)bp0[(long long)k2 * 128 + c] : 0u;
        *(uint32*)&Bs[c * LDW + kk] = v0 | (v1 << 16);
      }
    }
    __syncthreads();
    bf16x8 af[4], bfv[4];
    #pragma unroll
    for (int i = 0; i < 4; ++i) {
      af[i]  = *(const bf16x8*)(&As[(wm + i * 16 + fr) * LDW + fk]);
      bfv[i] = *(const bf16x8*)(&Bs[(wn + i * 16 + fr) * LDW + fk]);
    }
    #pragma unroll
    for (int i = 0; i < 4; ++i)
      #pragma unroll
      for (int j = 0; j < 4; ++j)
        acc[i][j] = __builtin_amdgcn_mfma_f32_16x16x32_bf16(af[i], bfv[j], acc[i][j], 0, 0, 0);
    __syncthreads();
  }

  const int crl = (lane >> 4) << 2, ccl = lane & 15;
  #pragma unroll
  for (int mi = 0; mi < 4; ++mi) {
    #pragma unroll
    for (int r = 0; r < 4; ++r) {
      int gr = wm + mi * 16 + crl + r;
      if (gr >= p.M) continue;
      #pragma unroll
      for (int ni = 0; ni < 4; ++ni) {
        int c = wn + ni * 16 + ccl;
        float v = acc[mi][ni][r];
        if (p.bias) v += p.bias[c];
        if (p.act)  v = siluf(v);
        long long co = (long long)e * p.c_ib + gr * 128 + c;
        if (p.c_bf16) ((ushort_t*)p.C)[co] = f2bf(v);
        else          ((float*)p.C)[co] = v;
      }
    }
  }
}

// ---------------------------------------------------------------------------
// Fused grid pipeline per edge: msg3 = WI @ (FG @ silu(TGp @ msgp))
// 3 MFMA phases, XOR-swizzled LDS. 64KB LDS -> 2 blocks/CU.
// ---------------------------------------------------------------------------
__global__ __launch_bounds__(256, 2) void k_grid(
    const ushort_t* __restrict__ tgb, const ushort_t* __restrict__ fgb,
    const float* __restrict__ wigv, const ushort_t* __restrict__ msgp,
    ushort_t* __restrict__ msg3)
{
  __shared__ short Abuf[8192];   // ph1: [112][64]; ph2: [64][128]; ph3: [64][64]
  __shared__ short Bsh[8192];    // ph1: M^T [128][64]; ph3: Q^T [128][64]
  __shared__ short Ps[16384];    // P^T [128 c][128 g]
  const int e = blockIdx.x, tid = threadIdx.x;
  const int lane = tid & 63, wv = tid >> 6;
  const int fr = lane & 15, fk = (lane >> 4) << 3;
  const int crl = (lane >> 4) << 2, ccl = lane & 15;
  const ushort_t* me = msgp + (long long)e * 6272;

  // stage TG [112][64] swz
  for (int gid = tid; gid < 896; gid += 256) {
    int r = gid >> 3, cg = gid & 7;
    bf16x8 v = (bf16x8)0;
    if (r < 98) {
      #pragma unroll
      for (int j = 0; j < 8; ++j) {
        int col = (cg << 3) + j;
        if (col < 49) v[j] = (short)tgb[r * 49 + col];
      }
    }
    *(bf16x8*)&Abuf[(r << 6) + (SWZ8(cg, r) << 3)] = v;
  }
  // stage M^T [128][64] swz
  for (int gid = tid; gid < 1024; gid += 256) {
    int kg = gid >> 7, c = gid & 127;
    bf16x8 v = (bf16x8)0;
    #pragma unroll
    for (int j = 0; j < 8; ++j) {
      int k = (kg << 3) + j;
      if (k < 49) v[j] = (short)me[k * 128 + c];
    }
    *(bf16x8*)&Bsh[(c << 6) + (SWZ8(kg, c) << 3)] = v;
  }
  // zero Ps pad cols (g = 112..127)
  {
    int c = tid >> 1, gg = 14 + (tid & 1);
    *(bf16x8*)&Ps[(c << 7) + (SWZ16(gg, c) << 3)] = (bf16x8)0;
  }
  __syncthreads();

  // phase 1: P = silu(TG @ M)  (M-tiles 7, N = 128, K = 64)
  {
    f32x4 acc[7][2];
    #pragma unroll
    for (int i = 0; i < 7; ++i) { acc[i][0] = (f32x4){0,0,0,0}; acc[i][1] = (f32x4){0,0,0,0}; }
    #pragma unroll
    for (int k0 = 0; k0 < 64; k0 += 32) {
      int cg = (k0 + fk) >> 3;
      int br0 = ((2 * wv) << 4) + fr, br1 = ((2 * wv + 1) << 4) + fr;
      bf16x8 bf0 = *(const bf16x8*)&Bsh[(br0 << 6) + (SWZ8(cg, br0) << 3)];
      bf16x8 bf1 = *(const bf16x8*)&Bsh[(br1 << 6) + (SWZ8(cg, br1) << 3)];
      #pragma unroll
      for (int rt = 0; rt < 7; ++rt) {
        int ar = (rt << 4) + fr;
        bf16x8 af = *(const bf16x8*)&Abuf[(ar << 6) + (SWZ8(cg, ar) << 3)];
        acc[rt][0] = __builtin_amdgcn_mfma_f32_16x16x32_bf16(af, bf0, acc[rt][0], 0, 0, 0);
        acc[rt][1] = __builtin_amdgcn_mfma_f32_16x16x32_bf16(af, bf1, acc[rt][1], 0, 0, 0);
      }
    }
    // write P^T (silu) into Ps[c][g]
    #pragma unroll
    for (int rt = 0; rt < 7; ++rt)
      #pragma unroll
      for (int cj = 0; cj < 2; ++cj) {
        int c = ((2 * wv + cj) << 4) + ccl;
        #pragma unroll
        for (int r = 0; r < 4; ++r) {
          int g = (rt << 4) + crl + r;
          Ps[(c << 7) + (SWZ16(g >> 3, c) << 3) + (g & 7)] =
              (short)f2bf(siluf(acc[rt][cj][r]));
        }
      }
  }
  __syncthreads();
  // stage FG [64][128] swz
  for (int gid = tid; gid < 1024; gid += 256) {
    int r = gid >> 4, cg = gid & 15;
    bf16x8 v = (bf16x8)0;
    if (r < 49) {
      #pragma unroll
      for (int j = 0; j < 8; ++j) {
        int col = (cg << 3) + j;
        if (col < 98) v[j] = (short)fgb[r * 98 + col];
      }
    }
    *(bf16x8*)&Abuf[(r << 7) + (SWZ16(cg, r) << 3)] = v;
  }
  __syncthreads();

  // phase 2: Q = FG @ P   (M-tiles 4, N = 128, K = 128)
  {
    f32x4 acc[4][2];
    #pragma unroll
    for (int i = 0; i < 4; ++i) { acc[i][0] = (f32x4){0,0,0,0}; acc[i][1] = (f32x4){0,0,0,0}; }
    #pragma unroll
    for (int k0 = 0; k0 < 128; k0 += 32) {
      int cg = (k0 + fk) >> 3;
      int br0 = ((2 * wv) << 4) + fr, br1 = ((2 * wv + 1) << 4) + fr;
      bf16x8 bf0 = *(const bf16x8*)&Ps[(br0 << 7) + (SWZ16(cg, br0) << 3)];
      bf16x8 bf1 = *(const bf16x8*)&Ps[(br1 << 7) + (SWZ16(cg, br1) << 3)];
      #pragma unroll
      for (int rt = 0; rt < 4; ++rt) {
        int ar = (rt << 4) + fr;
        bf16x8 af = *(const bf16x8*)&Abuf[(ar << 7) + (SWZ16(cg, ar) << 3)];
        acc[rt][0] = __builtin_amdgcn_mfma_f32_16x16x32_bf16(af, bf0, acc[rt][0], 0, 0, 0);
        acc[rt][1] = __builtin_amdgcn_mfma_f32_16x16x32_bf16(af, bf1, acc[rt][1], 0, 0, 0);
      }
    }
    // write Q^T into Bsh[c][q]
    #pragma unroll
    for (int rt = 0; rt < 4; ++rt)
      #pragma unroll
      for (int cj = 0; cj < 2; ++cj) {
        int c = ((2 * wv + cj) << 4) + ccl;
        #pragma unroll
        for (int r = 0; r < 4; ++r) {
          int q = (rt << 4) + crl + r;
          Bsh[(c << 6) + (SWZ8(q >> 3, c) << 3) + (q & 7)] = (short)f2bf(acc[rt][cj][r]);
        }
      }
  }
  __syncthreads();
  // stage WI [64][64] swz (f32 -> bf16)
  {
    const float* we = wigv + (long long)e * 2401;
    for (int gid = tid; gid < 512; gid += 256) {
      int r = gid >> 3, cg = gid & 7;
      bf16x8 v = (bf16x8)0;
      if (r < 49) {
        #pragma unroll
        for (int j = 0; j < 8; ++j) {
          int col = (cg << 3) + j;
          if (col < 49) v[j] = (short)f2bf(we[r * 49 + col]);
        }
      }
      *(bf16x8*)&Abuf[(r << 6) + (SWZ8(cg, r) << 3)] = v;
    }
  }
  __syncthreads();

  // phase 3: O = WI @ Q   (M-tiles 4, N = 128, K = 64)
  {
    f32x4 acc[4][2];
    #pragma unroll
    for (int i = 0; i < 4; ++i) { acc[i][0] = (f32x4){0,0,0,0}; acc[i][1] = (f32x4){0,0,0,0}; }
    #pragma unroll
    for (int k0 = 0; k0 < 64; k0 += 32) {
      int cg = (k0 + fk) >> 3;
      int br0 = ((2 * wv) << 4) + fr, br1 = ((2 * wv + 1) << 4) + fr;
      bf16x8 bf0 = *(const bf16x8*)&Bsh[(br0 << 6) + (SWZ8(cg, br0) << 3)];
      bf16x8 bf1 = *(const bf16x8*)&Bsh[(br1 << 6) + (SWZ8(cg, br1) << 3)];
      #pragma unroll
      for (int rt = 0; rt < 4; ++rt) {
        int ar = (rt << 4) + fr;
        bf16x8 af = *(const bf16x8*)&Abuf[(ar << 6) + (SWZ8(cg, ar) << 3)];
        acc[rt][0] = __builtin_amdgcn_mfma_f32_16x16x32_bf16(af, bf0, acc[rt][0], 0, 0, 0);
        acc[rt][1] = __builtin_amdgcn_mfma_f32_16x16x32_bf16(af, bf1, acc[rt][1], 0, 0, 0);
      }
    }
    ushort_t* oe = msg3 + (long long)e * 6272;
    #pragma unroll
    for (int rt = 0; rt < 4; ++rt)
      #pragma unroll
      for (int r = 0; r < 4; ++r) {
        int gi = (rt << 4) + crl + r;
        if (gi < 49) {
          #pragma unroll
          for (int cj = 0; cj < 2; ++cj) {
            int c = ((2 * wv + cj) << 4) + ccl;
            oe[gi * 128 + c] = f2bf(acc[rt][cj][r]);
          }
        }
      }
  }
}

// ---------------------------------------------------------------------------
// Segment-sum via prebuilt per-atom edge lists (deterministic)
// ---------------------------------------------------------------------------
__global__ __launch_bounds__(256) void k_zeroi(int* __restrict__ p, int n) {
  int id = blockIdx.x * 256 + threadIdx.x;
  if (id < n) p[id] = 0;
}

__global__ __launch_bounds__(256) void k_deg(
    const int* __restrict__ tgt, int* __restrict__ deg) {
  int e = blockIdx.x * 256 + threadIdx.x;
  if (e < EN) atomicAdd(&deg[tgt[e]], 1);
}

__global__ __launch_bounds__(1024) void k_prefix(
    const int* __restrict__ deg, int* __restrict__ base) {
  __shared__ int s[1024];
  int t = threadIdx.x;
  s[t] = (t < AN) ? deg[t] : 0;
  __syncthreads();
  for (int ofs = 1; ofs < 1024; ofs <<= 1) {
    int u = (t >= ofs) ? s[t - ofs] : 0;
    __syncthreads();
    s[t] += u;
    __syncthreads();
  }
  if (t < AN) base[t + 1] = s[t];
  if (t == 0) base[0] = 0;
}

__global__ __launch_bounds__(256) void k_fill(
    const int* __restrict__ tgt, const int* __restrict__ base,
    int* __restrict__ list) {
  const int a = blockIdx.x, t = threadIdx.x;
  const int lane = t & 63, w = t >> 6;
  __shared__ int wtot[4];
  __shared__ int runbase;
  if (t == 0) runbase = base[a];
  __syncthreads();
  for (int i0 = 0; i0 < EN; i0 += 256) {
    int e = i0 + t;
    bool m = (e < EN) && (tgt[e] == a);
    unsigned long long bal = __ballot(m);
    if (lane == 0) wtot[w] = __popcll(bal);
    __syncthreads();
    int wbase = 0;
    for (int j = 0; j < w; ++j) wbase += wtot[j];
    int tot = wtot[0] + wtot[1] + wtot[2] + wtot[3];
    if (m) {
      int off = __popcll(bal & ((1ull << lane) - 1ull));
      list[runbase + wbase + off] = e;
    }
    __syncthreads();
    if (t == 0) runbase += tot;
    __syncthreads();
  }
}

__global__ __launch_bounds__(256) void k_gather(
    const ushort_t* __restrict__ msg3, const int* __restrict__ base,
    const int* __restrict__ list, float* __restrict__ xmsg,
    int e0, int ce, int accum)
{
  const int a = blockIdx.x, part = blockIdx.y, t = threadIdx.x;
  const int b0 = base[a], b1 = base[a + 1];
  const int ofs = part * 784;
  float acc[4] = {0.f, 0.f, 0.f, 0.f};
  for (int i = b0; i < b1; ++i) {
    int e = list[i];
    if (e < e0 || e >= e0 + ce) continue;
    const ushort_t* m = msg3 + (long long)(e - e0) * 6272 + ofs;
    #pragma unroll
    for (int u = 0; u < 4; ++u) {
      int idx = t + (u << 8);
      if (idx < 784) acc[u] += bf2f(m[idx]);
    }
  }
  float* o = xmsg + (long long)a * 6272 + ofs;
  #pragma unroll
  for (int u = 0; u < 4; ++u) {
    int idx = t + (u << 8);
    if (idx < 784) {
      if (accum) o[idx] += acc[u]; else o[idx] = acc[u];
    }
  }
}

// ---------------------------------------------------------------------------
// Host orchestration
// ---------------------------------------------------------------------------
extern "C" void kernel_launch(void* const* d_in, const int* in_sizes, int n_in,
                              void* d_out, int out_size, void* d_ws, size_t ws_size,
                              hipStream_t stream) {
  const float* x         = (const float*)d_in[0];
  const float* edist     = (const float*)d_in[1];
  const float* wigner    = (const float*)d_in[2];
  const float* wiginv    = (const float*)d_in[3];
  const float* to_grid   = (const float*)d_in[4];
  const float* from_grid = (const float*)d_in[5];
  const float* w_dist1   = (const float*)d_in[6];
  const float* b_dist1   = (const float*)d_in[7];
  const float* src_emb   = (const float*)d_in[8];
  const float* tgt_emb   = (const float*)d_in[9];
  const float* w_edge1   = (const float*)d_in[10];
  const float* b_edge1   = (const float*)d_in[11];
  const float* ws1       = (const float*)d_in[12];
  const float* bs1       = (const float*)d_in[13];
  const float* ws2       = (const float*)d_in[14];
  const float* bs2       = (const float*)d_in[15];
  const float* ws3       = (const float*)d_in[16];
  const float* bs3       = (const float*)d_in[17];
  const int*   anum      = (const int*)d_in[18];
  const int*   eidx      = (const int*)d_in[19];
  const float* sw[10]; const float* tw[10];
  for (int i = 0; i < 10; ++i) {
    sw[i] = (const float*)d_in[20 + i];
    tw[i] = (const float*)d_in[30 + i];
  }
  float* outp = (float*)d_out;

  // ---- workspace (byte-based) ----
  char* wsb = (char*)d_ws;
  size_t off = 0;
  auto alloc = [&](long long nbytes) {
    char* p = wsb + off; off += (size_t)((nbytes + 63) & ~63LL); return p;
  };
  ushort_t* x_edge = (ushort_t*)alloc(8000LL * 128 * 2);
  ushort_t* b2ab   = (ushort_t*)alloc(5505024LL * 2);
  ushort_t* bgcw   = (ushort_t*)alloc(851968LL * 2);
  float*    bgcb   = (float*)alloc(6656 * 4);
  ushort_t* b20b   = (ushort_t*)alloc(458752LL * 2);
  ushort_t* s1m0b  = (ushort_t*)alloc(458752LL * 2);
  ushort_t* s1mb   = (ushort_t*)alloc(2752512LL * 2);
  ushort_t* wd1b   = (ushort_t*)alloc(65536 * 2);
  ushort_t* we1b   = (ushort_t*)alloc(16384 * 2);
  ushort_t* ws1b   = (ushort_t*)alloc(32768 * 2);
  ushort_t* ws2b   = (ushort_t*)alloc(16384 * 2);
  ushort_t* ws3b   = (ushort_t*)alloc(16384 * 2);
  ushort_t* tgb    = (ushort_t*)alloc(4802 * 2);
  ushort_t* fgb    = (ushort_t*)alloc(4802 * 2);
  float*    xmsg   = (float*)alloc(5017600LL * 4);
  float*    basis  = (float*)alloc(4096000LL * 4);
  float*    x_dist = (float*)alloc(1024000LL * 4);
  int*      deg    = (int*)alloc(800 * 4);
  int*      sbase  = (int*)alloc(801 * 4);
  int*      elist  = (int*)alloc(8000 * 4);
  const size_t fixedB = off;
  char* arena = wsb + off;

  static const int ces[6] = {8000, 4000, 2000, 1000, 500, 250};
  static const int cas[6] = {800, 800, 800, 400, 200, 100};
  int ce = 250, ca = 100;
  for (int i = 0; i < 6; ++i) {
    long long ne = (long long)ces[i] * 76544;
    long long na = (long long)cas[i] * 87808;
    long long need = (long long)fixedB + (ne > na ? ne : na);
    if (need <= (long long)ws_size) { ce = ces[i]; ca = cas[i]; break; }
  }

  // edge-phase arena (bytes)
  ushort_t* xrot_s = (ushort_t*)(arena);
  ushort_t* xrot_t = (ushort_t*)(arena + (long long)ce * 12544);
  ushort_t* tb0    = (ushort_t*)(arena + (long long)ce * 25088);
  ushort_t* tbm    = (ushort_t*)(arena + (long long)ce * 26112);
  ushort_t* msgp   = (ushort_t*)(arena + (long long)ce * 50688);
  ushort_t* gate   = (ushort_t*)(arena + (long long)ce * 63232);
  ushort_t* msg3   = (ushort_t*)(arena);   // overlays xrot after stage1
  // atom-phase arena
  ushort_t* hb = (ushort_t*)(arena);
  ushort_t* g1 = (ushort_t*)(arena + (long long)ca * 12544);
  ushort_t* g2 = (ushort_t*)(arena + (long long)ca * 37632);
  ushort_t* g3 = (ushort_t*)(arena + (long long)ca * 62720);

  long long ofs2[7][2], s1ofs[7][2];
  { long long cur = 0, cur1 = 0;
    for (int m = 1; m <= 6; ++m) {
      int k = (7 - m) * 128;
      ofs2[m][0] = cur; cur += (long long)k * 1024;
      ofs2[m][1] = cur; cur += (long long)k * 1024;
      s1ofs[m][0] = cur1; cur1 += 512LL * k;
      s1ofs[m][1] = cur1; cur1 += 512LL * k;
    } }

  auto D0 = []() { GemmP p; memset(&p, 0, sizeof(p)); p.asplit = 1 << 30; return p; };
  auto finalize = [&](Grouped& G) {
    int base = 0;
    for (int i = 0; i < G.nd; ++i) {
      GemmP& p = G.d[i];
      p.ngx = (p.M + 127) >> 7;
      int ngy = (p.N + 127) >> 7;
      p.wg_base = base;
      base += p.ngx * ngy;
    }
    gemm_g<<<base, 256, 0, stream>>>(G);
  };
  auto run1 = [&](GemmP p) { Grouped G; G.d[0] = p; G.nd = 1; finalize(G); };
  auto rungrid = [&](const float* A, int M, int K, int permA,
                     const ushort_t* B, int b_ib, void* C, int c_ib,
                     const float* bias, int act, int c_bf16, int nb) {
    GridP p;
    p.A = A; p.B = B; p.C = C; p.bias = bias;
    p.b_ib = b_ib; p.c_ib = c_ib;
    p.M = M; p.K = K; p.permA = permA; p.act = act; p.c_bf16 = c_bf16;
    gridmm<<<nb, 256, 0, stream>>>(p);
  };
  auto cvt = [&](const float* s, ushort_t* d, int n) {
    k_cvt<<<(n + 255) / 256, 256, 0, stream>>>(s, d, n);
  };

  // 0) weight builds (bf16)
  k_build_b2b<<<(5505024 + 255) / 256, 256, 0, stream>>>(sw[7], sw[9], tw[7], tw[9], b2ab);
  k_build_bgcat<<<(858624 + 255) / 256, 256, 0, stream>>>(
      sw[0], tw[0], sw[4], tw[4], sw[1], tw[1], sw[5], tw[5], bgcw, bgcb);
  k_build_b20b<<<(458752 + 255) / 256, 256, 0, stream>>>(sw[3], tw[3], b20b);
  k_build_s1m<<<(2752512 + 255) / 256, 256, 0, stream>>>(sw[6], sw[8], tw[6], tw[8], s1mb);
  cvt(sw[2], s1m0b, 229376);
  cvt(tw[2], s1m0b + 229376, 229376);
  cvt(w_dist1, wd1b, 65536);
  cvt(w_edge1, we1b, 16384);
  cvt(ws1, ws1b, 32768);
  cvt(ws2, ws2b, 16384);
  cvt(ws3, ws3b, 16384);
  cvt(from_grid, fgb, 4802);
  k_build_tg<<<(4802 + 255) / 256, 256, 0, stream>>>(to_grid, tgb);

  // scatter lists
  k_zeroi<<<4, 256, 0, stream>>>(deg, 800);
  k_deg<<<(EN + 255) / 256, 256, 0, stream>>>(eidx + EN, deg);
  k_prefix<<<1, 1024, 0, stream>>>(deg, sbase);
  k_fill<<<AN, 256, 0, stream>>>(eidx + EN, sbase, elist);

  // 1) edge features
  k_basis<<<(EN * 512 + 255) / 256, 256, 0, stream>>>(edist, basis);
  { GemmP p = D0();
    p.A = basis; p.a_se = 512; p.B = wd1b; p.ldb = 512; p.bias = b_dist1;
    p.C = x_dist; p.c_se = 128; p.M = EN; p.N = 128; p.K = 512;
    run1(p); }
  k_emb<<<(EN * 128 + 255) / 256, 256, 0, stream>>>(src_emb, tgt_emb, anum, eidx, x_dist);
  { GemmP p = D0();
    p.A = x_dist; p.a_se = 128; p.B = we1b; p.ldb = 128; p.bias = b_edge1;
    p.act = 1; p.C = x_edge; p.c_se = 128; p.c_bf16 = 1;
    p.M = EN; p.N = 128; p.K = 128;
    run1(p); }

  static const int offq[7] = {0, 7, 19, 29, 37, 43, 47};

  // 2) edge chunks
  for (int e0 = 0; e0 < EN; e0 += ce) {
    const int c = ce;
    k_rot<<<c, 256, 0, stream>>>(wigner + (long long)e0 * 2401, x,
                                 eidx + e0, eidx + EN + e0, xrot_s, xrot_t);
    // gates
    { GemmP p = D0();
      p.A = x_edge + (long long)e0 * 128; p.a_se = 128; p.a_bf16 = 1;
      p.B = bgcw; p.ldb = 128; p.bias = bgcb; p.act = 1;
      p.C = gate; p.c_se = 6656; p.c_bf16 = 1;
      p.M = c; p.N = 6656; p.K = 128;
      run1(p); }
    // stage 1 grouped
    { Grouped G; G.nd = 14;
      for (int s = 0; s < 2; ++s) {
        GemmP p = D0();
        p.A = s ? xrot_t : xrot_s; p.a_se = 6272; p.a_bf16 = 1;
        p.B = s1m0b + (long long)s * 229376; p.ldb = 896;
        p.gate = gate; p.gate_ofs = s * 256;
        p.C = tb0; p.c_se = 512; p.c_ofs = s * 256; p.c_bf16 = 1;
        p.M = c; p.N = 256; p.K = 896;
        G.d[s] = p;
      }
      int di = 2;
      for (int m = 1; m <= 6; ++m) {
        const int k = (7 - m) * 128, off2 = offq[m];
        for (int s = 0; s < 2; ++s) {
          GemmP p = D0();
          p.A = (s ? xrot_t : xrot_s) + off2 * 128;
          p.a_se = 6272; p.a_si = k; p.pair = 1; p.a_bf16 = 1;
          p.B = s1mb + s1ofs[m][s]; p.ldb = k;
          p.gate = gate; p.gate_ofs = 512 + (m - 1) * 1024 + s * 512;
          p.C = tbm; p.c_se = 12288; p.c_si = 1024;
          p.c_ofs = (m - 1) * 2048 + s * 512;
          p.ihalf = 1; p.c_bf16 = 1;
          p.M = 2 * c; p.N = 512; p.K = k;
          G.d[di++] = p;
        }
      }
      finalize(G); }
    // stage 2 grouped
    { Grouped G; G.nd = 13;
      { GemmP p = D0();
        p.A = tb0; p.a_se = 512; p.a_bf16 = 1;
        p.B = b20b; p.ldb = 512;
        p.C = msgp; p.c_se = 6272; p.c_bf16 = 1;
        p.M = c; p.N = 896; p.K = 512;
        G.d[0] = p; }
      int di = 1;
      for (int m = 1; m <= 6; ++m) {
        const int n = 7 - m, k = n * 128, off2 = offq[m];
        for (int pp = 0; pp < 2; ++pp) {
          GemmP p = D0();
          p.A = tbm + (m - 1) * 2048 + pp * 1024; p.a_se = 12288; p.a_bf16 = 1;
          p.B = b2ab + ofs2[m][pp]; p.ldb = 1024;
          p.C = msgp; p.c_se = 6272; p.c_ofs = (off2 + (pp ? n : 0)) * 128; p.c_bf16 = 1;
          p.M = c; p.N = k; p.K = 1024;
          G.d[di++] = p;
        }
      }
      finalize(G); }
    // fused grid pipeline + gather
    k_grid<<<c, 256, 0, stream>>>(tgb, fgb, wiginv + (long long)e0 * 2401, msgp, msg3);
    k_gather<<<dim3(AN, 8), 256, 0, stream>>>(msg3, sbase, elist, xmsg, e0, c, e0 > 0);
  }

  // 3) atom phase
  for (int a0 = 0; a0 < AN; a0 += ca) {
    { GemmP p = D0();
      p.A = x + (long long)a0 * 6272; p.A2 = xmsg + (long long)a0 * 6272;
      p.a_se = 128; p.asplit = 128;
      p.B = ws1b; p.ldb = 256;
      p.C = hb; p.c_se = 128; p.c_bf16 = 1;
      p.M = ca * 49; p.N = 128; p.K = 256;
      run1(p); }
    rungrid(to_grid, 98, 49, 0, hb, 6272, g1, 12544, bs1, 1, 1, ca);
    { GemmP p = D0();
      p.A = g1; p.a_se = 128; p.a_bf16 = 1;
      p.B = ws2b; p.ldb = 128; p.bias = bs2; p.act = 1;
      p.C = g2; p.c_se = 128; p.c_bf16 = 1;
      p.M = ca * 98; p.N = 128; p.K = 128;
      run1(p); }
    { GemmP p = D0();
      p.A = g2; p.a_se = 128; p.a_bf16 = 1;
      p.B = ws3b; p.ldb = 128; p.bias = bs3;
      p.C = g3; p.c_se = 128; p.c_bf16 = 1;
      p.M = ca * 98; p.N = 128; p.K = 128;
      run1(p); }
    rungrid(from_grid, 49, 98, 0, g3, 12544, outp + (long long)a0 * 6272, 6272,
            nullptr, 0, 0, ca);
  }
}

// Round 6
// 1804.478 us; speedup vs baseline: 11.9961x; 1.0984x over previous
//
#include <hip/hip_runtime.h>
#include <string.h>

#define EN 8000
#define AN 800

typedef __attribute__((ext_vector_type(8))) short bf16x8;
typedef __attribute__((ext_vector_type(4))) float f32x4;
typedef unsigned short ushort_t;
typedef unsigned int uint32;

__constant__ int c_perm[49] = {
  0,2,6,12,20,30,42,
  1,5,11,19,29,41,
  3,7,13,21,31,43,
  4,10,18,28,40,
  8,14,22,32,44,
  9,17,27,39,
  15,23,33,45,
  16,26,38,
  24,34,46,
  25,37,
  35,47,
  36,
  48
};

__device__ __forceinline__ float siluf(float x) { return x / (1.0f + __expf(-x)); }
__device__ __forceinline__ ushort_t f2bf(float f) {
  uint32 u = __float_as_uint(f);
  u += 0x7fff + ((u >> 16) & 1);
  return (ushort_t)(u >> 16);
}
__device__ __forceinline__ float bf2f(ushort_t h) {
  return __uint_as_float(((uint32)h) << 16);
}
__device__ __forceinline__ void gld16(const void* g, void* l) {
  __builtin_amdgcn_global_load_lds(
      (const __attribute__((address_space(1))) void*)g,
      (__attribute__((address_space(3))) void*)l, 16, 0, 0);
}

// ---------------------------------------------------------------------------
// Weight builders (bf16 outputs)
// ---------------------------------------------------------------------------
__global__ __launch_bounds__(256) void k_build_b2b(
    const float* __restrict__ sw2r, const float* __restrict__ sw2i,
    const float* __restrict__ tw2r, const float* __restrict__ tw2i,
    ushort_t* __restrict__ dst)
{
  long long id = (long long)blockIdx.x * 256 + threadIdx.x;
  if (id >= 5505024LL) return;
  long long base = 0; int m = 1, k = 768;
  for (; m <= 6; ++m) {
    k = (7 - m) * 128;
    long long sz = 2LL * k * 1024;
    if (id < base + sz) break;
    base += sz;
  }
  long long rem = id - base;
  int p = (int)(rem / ((long long)k * 1024));
  int cj = (int)(rem - (long long)p * k * 1024);
  int c = cj >> 10, j = cj & 1023;
  int q = j >> 8, jj = j & 255;
  const float sgn = (q & 1) ? (p ? 1.f : -1.f) : 1.f;
  const float* src = (q < 2) ? (q == 0 ? sw2r : sw2i) : (q == 2 ? tw2r : tw2i);
  dst[id] = f2bf(sgn * src[(long long)(m - 1) * 196608 + c * 256 + jj]);
}

__global__ __launch_bounds__(256) void k_build_bgcat(
    const float* __restrict__ sw0, const float* __restrict__ tw0,
    const float* __restrict__ sw4, const float* __restrict__ tw4,
    const float* __restrict__ sb0, const float* __restrict__ tb0b,
    const float* __restrict__ sbd, const float* __restrict__ tbd,
    ushort_t* __restrict__ w, float* __restrict__ b)
{
  int id = blockIdx.x * 256 + threadIdx.x;
  if (id < 851968) {
    int r = id >> 7, c = id & 127;
    float v;
    if (r < 256) v = sw0[r * 128 + c];
    else if (r < 512) v = tw0[(r - 256) * 128 + c];
    else {
      int rr = r - 512, m = rr >> 10, q = rr & 1023;
      v = (q < 512) ? sw4[m * 65536 + q * 128 + c] : tw4[m * 65536 + (q - 512) * 128 + c];
    }
    w[id] = f2bf(v);
    return;
  }
  id -= 851968;
  if (id < 6656) {
    float v;
    if (id < 256) v = sb0[id];
    else if (id < 512) v = tb0b[id - 256];
    else {
      int rr = id - 512, m = rr >> 10, q = rr & 1023;
      v = (q < 512) ? sbd[m * 512 + q] : tbd[m * 512 + (q - 512)];
    }
    b[id] = v;
  }
}

__global__ __launch_bounds__(256) void k_build_b20b(
    const float* __restrict__ sw3, const float* __restrict__ tw3,
    ushort_t* __restrict__ b20)
{
  int id = blockIdx.x * 256 + threadIdx.x;
  if (id >= 458752) return;
  int cc = id >> 9, j = id & 511;
  b20[id] = f2bf((j < 256) ? sw3[cc * 256 + j] : tw3[cc * 256 + (j - 256)]);
}

__global__ __launch_bounds__(256) void k_build_s1m(
    const float* __restrict__ sw6, const float* __restrict__ sw8,
    const float* __restrict__ tw6, const float* __restrict__ tw8,
    ushort_t* __restrict__ dst)
{
  long long id = (long long)blockIdx.x * 256 + threadIdx.x;
  if (id >= 2752512LL) return;
  long long base = 0; int m = 1, k = 768;
  for (; m <= 6; ++m) {
    k = (7 - m) * 128;
    long long sz = 1024LL * k;
    if (id < base + sz) break;
    base += sz;
  }
  long long rem = id - base;
  int s = (int)(rem / (512LL * k));
  int rr = (int)(rem - (long long)s * 512 * k);
  int r = rr / k, c = rr - r * k;
  const float* src = (r < 256) ? (s ? tw6 : sw6) : (s ? tw8 : sw8);
  int r0 = (r < 256) ? r : r - 256;
  dst[id] = f2bf(src[(long long)(m - 1) * 196608 + r0 * 768 + c]);
}

__global__ __launch_bounds__(256) void k_cvt(
    const float* __restrict__ src, ushort_t* __restrict__ dst, int n)
{
  int id = blockIdx.x * 256 + threadIdx.x;
  if (id < n) dst[id] = f2bf(src[id]);
}

__global__ __launch_bounds__(256) void k_build_tg(
    const float* __restrict__ tg, ushort_t* __restrict__ dst)
{
  int id = blockIdx.x * 256 + threadIdx.x;
  if (id >= 98 * 49) return;
  int r = id / 49, s = id - r * 49;
  dst[id] = f2bf(tg[r * 49 + c_perm[s]]);
}

// transpose x (f32 [49][128]) -> xbT (bf16 [128][64], j-padded)
__global__ __launch_bounds__(256) void k_xT(
    const float* __restrict__ x, ushort_t* __restrict__ xbT)
{
  __shared__ __align__(16) float xs[49 * 128];
  const int a = blockIdx.x, t = threadIdx.x;
  const float4* src = (const float4*)(x + (long long)a * 6272);
  float4* d = (float4*)xs;
  for (int i = t; i < 1568; i += 256) d[i] = src[i];
  __syncthreads();
  ushort_t* o = xbT + (long long)a * 8192;
  int c = t >> 1;
  int jg = (t & 1) << 2;
  #pragma unroll
  for (int u = 0; u < 4; ++u) {
    int g = jg + u;
    bf16x8 v = (bf16x8)0;
    #pragma unroll
    for (int j = 0; j < 8; ++j) {
      int jj = (g << 3) + j;
      if (jj < 49) v[j] = (short)f2bf(xs[jj * 128 + c]);
    }
    *(bf16x8*)&o[(c << 6) + (g << 3)] = v;
  }
}

// ---------------------------------------------------------------------------
// Edge features
// ---------------------------------------------------------------------------
__global__ __launch_bounds__(256) void k_basis(
    const float* __restrict__ dist, ushort_t* __restrict__ basis)
{
  int id = blockIdx.x * 256 + threadIdx.x;
  if (id >= EN * 512) return;
  int e = id >> 9, g = id & 511;
  const float step = 8.0f / 511.0f;
  const float coeff = -2040.0078125f;
  float df = dist[e] - (float)g * step;
  basis[id] = f2bf(expf(coeff * df * df));
}

__global__ __launch_bounds__(256) void k_emb(
    const float* __restrict__ src_emb, const float* __restrict__ tgt_emb,
    const int* __restrict__ anum, const int* __restrict__ eidx,
    const float* __restrict__ xd, ushort_t* __restrict__ out)
{
  int id = blockIdx.x * 256 + threadIdx.x;
  if (id >= EN * 128) return;
  int e = id >> 7, c = id & 127;
  int a0 = anum[eidx[e]], a1 = anum[eidx[EN + e]];
  out[id] = f2bf(siluf(src_emb[a0 * 128 + c] + tgt_emb[a1 * 128 + c] + xd[id]));
}

// ---------------------------------------------------------------------------
// MFMA Wigner rotation: out[q][c] = sum_j W[perm[q]][j] * x[j][c] (s and t)
// ---------------------------------------------------------------------------
__global__ __launch_bounds__(256) void k_rot2(
    const float* __restrict__ wig, const ushort_t* __restrict__ xbT,
    const int* __restrict__ srcl, const int* __restrict__ tgtl,
    ushort_t* __restrict__ osrc, ushort_t* __restrict__ otgt)
{
  __shared__ short Ws[4096];   // [64][64] bf16, 8-slot swz
  __shared__ short Xs[8192];   // [128][64]
  __shared__ short Xt[8192];
  const int e = blockIdx.x, tid = threadIdx.x;
  const int lane = tid & 63, wave = tid >> 6;
  const float* wge = wig + (long long)e * 2401;
  #pragma unroll
  for (int t = 0; t < 2; ++t) {
    int ci = (t << 8) + tid;
    int row = ci >> 3, g = ci & 7;
    bf16x8 v = (bf16x8)0;
    if (row < 49) {
      const float* wr = wge + c_perm[row] * 49;
      #pragma unroll
      for (int j = 0; j < 8; ++j) {
        int col = (g << 3) + j;
        if (col < 49) v[j] = (short)f2bf(wr[col]);
      }
    }
    *(bf16x8*)&Ws[(row << 6) + ((g ^ (row & 7)) << 3)] = v;
  }
  const int as = srcl[e], at = tgtl[e];
  const ushort_t* xsg = xbT + (long long)as * 8192;
  const ushort_t* xtg = xbT + (long long)at * 8192;
  #pragma unroll
  for (int t = 0; t < 4; ++t) {
    int ci = (t << 8) + tid;
    int row = ci >> 3, g = ci & 7;
    int ofs = (row << 6) + ((g ^ (row & 7)) << 3);
    *(bf16x8*)&Xs[ofs] = *(const bf16x8*)&xsg[ci << 3];
    *(bf16x8*)&Xt[ofs] = *(const bf16x8*)&xtg[ci << 3];
  }
  __syncthreads();
  const short* Xb = (wave >> 1) ? Xt : Xs;
  ushort_t* ob = ((wave >> 1) ? otgt : osrc) + (long long)e * 6272;
  const int ch = (wave & 1) << 6;
  const int fr = lane & 15, g = lane >> 4;
  f32x4 acc[4][4];
  #pragma unroll
  for (int i = 0; i < 4; ++i)
    #pragma unroll
    for (int j = 0; j < 4; ++j) acc[i][j] = (f32x4){0.f, 0.f, 0.f, 0.f};
  #pragma unroll
  for (int ks = 0; ks < 2; ++ks) {
    bf16x8 af[4], bfv[4];
    int lc = (ks << 2) + g;
    #pragma unroll
    for (int i = 0; i < 4; ++i) {
      int ra = (i << 4) + fr;
      af[i] = *(const bf16x8*)&Ws[(ra << 6) + ((lc ^ (ra & 7)) << 3)];
      int rb = ch + (i << 4) + fr;
      bfv[i] = *(const bf16x8*)&Xb[(rb << 6) + ((lc ^ (rb & 7)) << 3)];
    }
    #pragma unroll
    for (int i = 0; i < 4; ++i)
      #pragma unroll
      for (int j = 0; j < 4; ++j)
        acc[i][j] = __builtin_amdgcn_mfma_f32_16x16x32_bf16(af[i], bfv[j], acc[i][j], 0, 0, 0);
  }
  const int crl = (lane >> 4) << 2, ccl = lane & 15;
  #pragma unroll
  for (int i = 0; i < 4; ++i)
    #pragma unroll
    for (int r = 0; r < 4; ++r) {
      int q = (i << 4) + crl + r;
      if (q < 49) {
        #pragma unroll
        for (int j = 0; j < 4; ++j) {
          int col = ch + (j << 4) + ccl;
          ob[q * 128 + col] = f2bf(acc[i][j][r]);
        }
      }
    }
}

// ---------------------------------------------------------------------------
// Grouped MFMA GEMM, all-bf16 operands, global_load_lds staging + XOR swizzle
// ---------------------------------------------------------------------------
struct GemmP {
  const ushort_t* A; const ushort_t* A2; const ushort_t* B;
  const float* bias; const ushort_t* gate; void* C;
  int a_se, a_si, pair, asplit;
  int ldb;
  int gate_ofs;
  int c_se, c_si, c_ofs;
  int ihalf, act, c_bf16;
  int M, N, K;
  int ngx, wg_base;
};
struct Grouped { GemmP d[14]; int nd; };

__global__ __launch_bounds__(256) void gemm_g(Grouped G) {
  __shared__ short As[4096];   // [128 rows][32 k] 4-slot swz
  __shared__ short Bs[4096];
  const int bid = blockIdx.x;
  int di = G.nd - 1;
  for (int i = 1; i < G.nd; ++i) if (bid < G.d[i].wg_base) { di = i - 1; break; }
  const GemmP p = G.d[di];
  const int local = bid - p.wg_base;
  const int bx = local % p.ngx, by = local / p.ngx;
  const int m0 = bx << 7, n0 = by << 7;

  const int tid = threadIdx.x;
  const int lane = tid & 63, wave = tid >> 6;
  const int gl = ((lane & 3) ^ ((lane >> 3) & 3)) << 3;  // pre-swizzled k-offset
  const int grow = (wave << 4) + (lane >> 2);
  const int fr = lane & 15, fkg = lane >> 4;
  const int sxor = (fr >> 1) & 3;
  const int wm = (wave >> 1) << 6, wn = (wave & 1) << 6;

  f32x4 acc[4][4];
  #pragma unroll
  for (int i = 0; i < 4; ++i)
    #pragma unroll
    for (int j = 0; j < 4; ++j) acc[i][j] = (f32x4){0.f, 0.f, 0.f, 0.f};

  for (int k0 = 0; k0 < p.K; k0 += 32) {
    const ushort_t* Ap = p.A;
    int kk = k0;
    if (p.A2 && k0 >= p.asplit) { Ap = p.A2; kk = k0 - p.asplit; }
    #pragma unroll
    for (int t = 0; t < 2; ++t) {
      int r = m0 + (t << 6) + grow;
      long long base = p.pair
          ? (long long)(r >> 1) * p.a_se + (long long)(r & 1) * p.a_si
          : (long long)r * p.a_se;
      gld16(Ap + base + kk + gl, &As[(t << 11) + (wave << 9)]);
      int rn = n0 + (t << 6) + grow;
      gld16(p.B + (long long)rn * p.ldb + k0 + gl, &Bs[(t << 11) + (wave << 9)]);
    }
    __syncthreads();
    bf16x8 af[4], bfv[4];
    #pragma unroll
    for (int i = 0; i < 4; ++i) {
      int ra = wm + (i << 4) + fr;
      int rb = wn + (i << 4) + fr;
      af[i]  = *(const bf16x8*)&As[(ra << 5) + ((fkg ^ sxor) << 3)];
      bfv[i] = *(const bf16x8*)&Bs[(rb << 5) + ((fkg ^ sxor) << 3)];
    }
    #pragma unroll
    for (int i = 0; i < 4; ++i)
      #pragma unroll
      for (int j = 0; j < 4; ++j)
        acc[i][j] = __builtin_amdgcn_mfma_f32_16x16x32_bf16(af[i], bfv[j], acc[i][j], 0, 0, 0);
    __syncthreads();
  }

  const int crl = (lane >> 4) << 2, ccl = lane & 15;
  #pragma unroll
  for (int mi = 0; mi < 4; ++mi) {
    #pragma unroll
    for (int r = 0; r < 4; ++r) {
      int gr = m0 + wm + mi * 16 + crl + r;
      if (gr >= p.M) continue;
      long long e; int ii;
      if (p.pair) { e = gr >> 1; ii = gr & 1; } else { e = gr; ii = 0; }
      const ushort_t* grw = p.gate ? p.gate + e * 6656 + p.gate_ofs : nullptr;
      #pragma unroll
      for (int ni = 0; ni < 4; ++ni) {
        int gc = n0 + wn + ni * 16 + ccl;
        if (gc >= p.N) continue;
        float v = acc[mi][ni][r];
        if (p.bias) v += p.bias[gc];
        if (p.act)  v = siluf(v);
        if (grw)    v *= bf2f(grw[gc]);
        int par = (p.ihalf && gc >= 256) ? (1 - ii) : ii;
        long long co = e * (long long)p.c_se + (long long)par * p.c_si + p.c_ofs + gc;
        if (p.c_bf16) ((ushort_t*)p.C)[co] = f2bf(v);
        else          ((float*)p.C)[co] = v;
      }
    }
  }
}

// ---------------------------------------------------------------------------
// gridmm (atom phase)
// ---------------------------------------------------------------------------
struct GridP {
  const float* A; const ushort_t* B; void* C; const float* bias;
  int b_ib, c_ib;
  int M, K, permA, act, c_bf16;
};

#define LDW 40

__global__ __launch_bounds__(256) void gridmm(GridP p) {
  __shared__ short As[128 * LDW];
  __shared__ short Bs[128 * LDW];
  const int e = blockIdx.x;
  const int tid = threadIdx.x;
  const int srow = tid >> 1, sk = (tid & 1) << 4;
  const int lane = tid & 63, wave = tid >> 6;
  const int wm = (wave >> 1) << 6, wn = (wave & 1) << 6;
  const int fr = lane & 15, fk = (lane >> 4) << 3;

  f32x4 acc[4][4];
  #pragma unroll
  for (int i = 0; i < 4; ++i)
    #pragma unroll
    for (int j = 0; j < 4; ++j) acc[i][j] = (f32x4){0.f, 0.f, 0.f, 0.f};

  const ushort_t* bp0 = p.B + (long long)e * p.b_ib;

  for (int k0 = 0; k0 < p.K; k0 += 32) {
    {
      bf16x8 lo = (bf16x8)0, hi = (bf16x8)0;
      if (srow < p.M) {
        const float* ar = p.A + srow * p.K;
        #pragma unroll
        for (int j = 0; j < 8; ++j) {
          int col = k0 + sk + j;
          float v = 0.f;
          if (col < p.K) v = ar[p.permA ? c_perm[col] : col];
          lo[j] = (short)f2bf(v);
        }
        #pragma unroll
        for (int j = 0; j < 8; ++j) {
          int col = k0 + sk + 8 + j;
          float v = 0.f;
          if (col < p.K) v = ar[p.permA ? c_perm[col] : col];
          hi[j] = (short)f2bf(v);
        }
      }
      *(bf16x8*)&As[srow * LDW + sk] = lo;
      *(bf16x8*)&As[srow * LDW + sk + 8] = hi;
    }
    {
      const int c = tid & 127, kq = tid >> 7;
      #pragma unroll
      for (int i = 0; i < 8; ++i) {
        int kk = kq * 16 + i * 2;
        int k1 = k0 + kk, k2 = k1 + 1;
        uint32 v0 = (k1 < p.K) ? (uint32)bp0[(long long)k1 * 128 + c] : 0u;
        uint32 v1 = (k2 < p.K) ? (uint32)bp0[(long long)k2 * 128 + c] : 0u;
        *(uint32*)&Bs[c * LDW + kk] = v0 | (v1 << 16);
      }
    }
    __syncthreads();
    bf16x8 af[4], bfv[4];
    #pragma unroll
    for (int i = 0; i < 4; ++i) {
      af[i]  = *(const bf16x8*)(&As[(wm + i * 16 + fr) * LDW + fk]);
      bfv[i] = *(const bf16x8*)(&Bs[(wn + i * 16 + fr) * LDW + fk]);
    }
    #pragma unroll
    for (int i = 0; i < 4; ++i)
      #pragma unroll
      for (int j = 0; j < 4; ++j)
        acc[i][j] = __builtin_amdgcn_mfma_f32_16x16x32_bf16(af[i], bfv[j], acc[i][j], 0, 0, 0);
    __syncthreads();
  }

  const int crl = (lane >> 4) << 2, ccl = lane & 15;
  #pragma unroll
  for (int mi = 0; mi < 4; ++mi) {
    #pragma unroll
    for (int r = 0; r < 4; ++r) {
      int gr = wm + mi * 16 + crl + r;
      if (gr >= p.M) continue;
      #pragma unroll
      for (int ni = 0; ni < 4; ++ni) {
        int c = wn + ni * 16 + ccl;
        float v = acc[mi][ni][r];
        if (p.bias) v += p.bias[c];
        if (p.act)  v = siluf(v);
        long long co = (long long)e * p.c_ib + gr * 128 + c;
        if (p.c_bf16) ((ushort_t*)p.C)[co] = f2bf(v);
        else          ((float*)p.C)[co] = v;
      }
    }
  }
}

// ---------------------------------------------------------------------------
// Fused grid pipeline per edge: msg3 = WI @ (FG @ silu(TGp @ msgp))
// ---------------------------------------------------------------------------
#define SWZ8(cg, r) (((cg) ^ ((r) & 7)) & 7)
#define SWZ16(cg, r) (((cg) & 8) | (((cg) ^ (r)) & 7))

__global__ __launch_bounds__(256, 2) void k_grid(
    const ushort_t* __restrict__ tgb, const ushort_t* __restrict__ fgb,
    const float* __restrict__ wigv, const ushort_t* __restrict__ msgp,
    ushort_t* __restrict__ msg3)
{
  __shared__ short Abuf[8192];
  __shared__ short Bsh[8192];
  __shared__ short Ps[16384];
  const int e = blockIdx.x, tid = threadIdx.x;
  const int lane = tid & 63, wv = tid >> 6;
  const int fr = lane & 15, fk = (lane >> 4) << 3;
  const int crl = (lane >> 4) << 2, ccl = lane & 15;
  const ushort_t* me = msgp + (long long)e * 6272;

  for (int gid = tid; gid < 896; gid += 256) {
    int r = gid >> 3, cg = gid & 7;
    bf16x8 v = (bf16x8)0;
    if (r < 98) {
      #pragma unroll
      for (int j = 0; j < 8; ++j) {
        int col = (cg << 3) + j;
        if (col < 49) v[j] = (short)tgb[r * 49 + col];
      }
    }
    *(bf16x8*)&Abuf[(r << 6) + (SWZ8(cg, r) << 3)] = v;
  }
  for (int gid = tid; gid < 1024; gid += 256) {
    int kg = gid >> 7, c = gid & 127;
    bf16x8 v = (bf16x8)0;
    #pragma unroll
    for (int j = 0; j < 8; ++j) {
      int k = (kg << 3) + j;
      if (k < 49) v[j] = (short)me[k * 128 + c];
    }
    *(bf16x8*)&Bsh[(c << 6) + (SWZ8(kg, c) << 3)] = v;
  }
  {
    int c = tid >> 1, gg = 14 + (tid & 1);
    *(bf16x8*)&Ps[(c << 7) + (SWZ16(gg, c) << 3)] = (bf16x8)0;
  }
  __syncthreads();

  {
    f32x4 acc[7][2];
    #pragma unroll
    for (int i = 0; i < 7; ++i) { acc[i][0] = (f32x4){0,0,0,0}; acc[i][1] = (f32x4){0,0,0,0}; }
    #pragma unroll
    for (int k0 = 0; k0 < 64; k0 += 32) {
      int cg = (k0 + fk) >> 3;
      int br0 = ((2 * wv) << 4) + fr, br1 = ((2 * wv + 1) << 4) + fr;
      bf16x8 bf0 = *(const bf16x8*)&Bsh[(br0 << 6) + (SWZ8(cg, br0) << 3)];
      bf16x8 bf1 = *(const bf16x8*)&Bsh[(br1 << 6) + (SWZ8(cg, br1) << 3)];
      #pragma unroll
      for (int rt = 0; rt < 7; ++rt) {
        int ar = (rt << 4) + fr;
        bf16x8 af = *(const bf16x8*)&Abuf[(ar << 6) + (SWZ8(cg, ar) << 3)];
        acc[rt][0] = __builtin_amdgcn_mfma_f32_16x16x32_bf16(af, bf0, acc[rt][0], 0, 0, 0);
        acc[rt][1] = __builtin_amdgcn_mfma_f32_16x16x32_bf16(af, bf1, acc[rt][1], 0, 0, 0);
      }
    }
    #pragma unroll
    for (int rt = 0; rt < 7; ++rt)
      #pragma unroll
      for (int cj = 0; cj < 2; ++cj) {
        int c = ((2 * wv + cj) << 4) + ccl;
        #pragma unroll
        for (int r = 0; r < 4; ++r) {
          int g = (rt << 4) + crl + r;
          Ps[(c << 7) + (SWZ16(g >> 3, c) << 3) + (g & 7)] =
              (short)f2bf(siluf(acc[rt][cj][r]));
        }
      }
  }
  __syncthreads();
  for (int gid = tid; gid < 1024; gid += 256) {
    int r = gid >> 4, cg = gid & 15;
    bf16x8 v = (bf16x8)0;
    if (r < 49) {
      #pragma unroll
      for (int j = 0; j < 8; ++j) {
        int col = (cg << 3) + j;
        if (col < 98) v[j] = (short)fgb[r * 98 + col];
      }
    }
    *(bf16x8*)&Abuf[(r << 7) + (SWZ16(cg, r) << 3)] = v;
  }
  __syncthreads();

  {
    f32x4 acc[4][2];
    #pragma unroll
    for (int i = 0; i < 4; ++i) { acc[i][0] = (f32x4){0,0,0,0}; acc[i][1] = (f32x4){0,0,0,0}; }
    #pragma unroll
    for (int k0 = 0; k0 < 128; k0 += 32) {
      int cg = (k0 + fk) >> 3;
      int br0 = ((2 * wv) << 4) + fr, br1 = ((2 * wv + 1) << 4) + fr;
      bf16x8 bf0 = *(const bf16x8*)&Ps[(br0 << 7) + (SWZ16(cg, br0) << 3)];
      bf16x8 bf1 = *(const bf16x8*)&Ps[(br1 << 7) + (SWZ16(cg, br1) << 3)];
      #pragma unroll
      for (int rt = 0; rt < 4; ++rt) {
        int ar = (rt << 4) + fr;
        bf16x8 af = *(const bf16x8*)&Abuf[(ar << 7) + (SWZ16(cg, ar) << 3)];
        acc[rt][0] = __builtin_amdgcn_mfma_f32_16x16x32_bf16(af, bf0, acc[rt][0], 0, 0, 0);
        acc[rt][1] = __builtin_amdgcn_mfma_f32_16x16x32_bf16(af, bf1, acc[rt][1], 0, 0, 0);
      }
    }
    #pragma unroll
    for (int rt = 0; rt < 4; ++rt)
      #pragma unroll
      for (int cj = 0; cj < 2; ++cj) {
        int c = ((2 * wv + cj) << 4) + ccl;
        #pragma unroll
        for (int r = 0; r < 4; ++r) {
          int q = (rt << 4) + crl + r;
          Bsh[(c << 6) + (SWZ8(q >> 3, c) << 3) + (q & 7)] = (short)f2bf(acc[rt][cj][r]);
        }
      }
  }
  __syncthreads();
  {
    const float* we = wigv + (long long)e * 2401;
    for (int gid = tid; gid < 512; gid += 256) {
      int r = gid >> 3, cg = gid & 7;
      bf16x8 v = (bf16x8)0;
      if (r < 49) {
        #pragma unroll
        for (int j = 0; j < 8; ++j) {
          int col = (cg << 3) + j;
          if (col < 49) v[j] = (short)f2bf(we[r * 49 + col]);
        }
      }
      *(bf16x8*)&Abuf[(r << 6) + (SWZ8(cg, r) << 3)] = v;
    }
  }
  __syncthreads();

  {
    f32x4 acc[4][2];
    #pragma unroll
    for (int i = 0; i < 4; ++i) { acc[i][0] = (f32x4){0,0,0,0}; acc[i][1] = (f32x4){0,0,0,0}; }
    #pragma unroll
    for (int k0 = 0; k0 < 64; k0 += 32) {
      int cg = (k0 + fk) >> 3;
      int br0 = ((2 * wv) << 4) + fr, br1 = ((2 * wv + 1) << 4) + fr;
      bf16x8 bf0 = *(const bf16x8*)&Bsh[(br0 << 6) + (SWZ8(cg, br0) << 3)];
      bf16x8 bf1 = *(const bf16x8*)&Bsh[(br1 << 6) + (SWZ8(cg, br1) << 3)];
      #pragma unroll
      for (int rt = 0; rt < 4; ++rt) {
        int ar = (rt << 4) + fr;
        bf16x8 af = *(const bf16x8*)&Abuf[(ar << 6) + (SWZ8(cg, ar) << 3)];
        acc[rt][0] = __builtin_amdgcn_mfma_f32_16x16x32_bf16(af, bf0, acc[rt][0], 0, 0, 0);
        acc[rt][1] = __builtin_amdgcn_mfma_f32_16x16x32_bf16(af, bf1, acc[rt][1], 0, 0, 0);
      }
    }
    ushort_t* oe = msg3 + (long long)e * 6272;
    #pragma unroll
    for (int rt = 0; rt < 4; ++rt)
      #pragma unroll
      for (int r = 0; r < 4; ++r) {
        int gi = (rt << 4) + crl + r;
        if (gi < 49) {
          #pragma unroll
          for (int cj = 0; cj < 2; ++cj) {
            int c = ((2 * wv + cj) << 4) + ccl;
            oe[gi * 128 + c] = f2bf(acc[rt][cj][r]);
          }
        }
      }
  }
}

// ---------------------------------------------------------------------------
// Segment-sum via per-atom edge lists
// ---------------------------------------------------------------------------
__global__ __launch_bounds__(256) void k_zeroi(int* __restrict__ p, int n) {
  int id = blockIdx.x * 256 + threadIdx.x;
  if (id < n) p[id] = 0;
}

__global__ __launch_bounds__(256) void k_deg(
    const int* __restrict__ tgt, int* __restrict__ deg) {
  int e = blockIdx.x * 256 + threadIdx.x;
  if (e < EN) atomicAdd(&deg[tgt[e]], 1);
}

__global__ __launch_bounds__(1024) void k_prefix(
    const int* __restrict__ deg, int* __restrict__ base) {
  __shared__ int s[1024];
  int t = threadIdx.x;
  s[t] = (t < AN) ? deg[t] : 0;
  __syncthreads();
  for (int ofs = 1; ofs < 1024; ofs <<= 1) {
    int u = (t >= ofs) ? s[t - ofs] : 0;
    __syncthreads();
    s[t] += u;
    __syncthreads();
  }
  if (t < AN) base[t + 1] = s[t];
  if (t == 0) base[0] = 0;
}

__global__ __launch_bounds__(256) void k_fill(
    const int* __restrict__ tgt, const int* __restrict__ base,
    int* __restrict__ list) {
  const int a = blockIdx.x, t = threadIdx.x;
  const int lane = t & 63, w = t >> 6;
  __shared__ int wtot[4];
  __shared__ int runbase;
  if (t == 0) runbase = base[a];
  __syncthreads();
  for (int i0 = 0; i0 < EN; i0 += 256) {
    int e = i0 + t;
    bool m = (e < EN) && (tgt[e] == a);
    unsigned long long bal = __ballot(m);
    if (lane == 0) wtot[w] = __popcll(bal);
    __syncthreads();
    int wbase = 0;
    for (int j = 0; j < w; ++j) wbase += wtot[j];
    int tot = wtot[0] + wtot[1] + wtot[2] + wtot[3];
    if (m) {
      int off = __popcll(bal & ((1ull << lane) - 1ull));
      list[runbase + wbase + off] = e;
    }
    __syncthreads();
    if (t == 0) runbase += tot;
    __syncthreads();
  }
}

__global__ __launch_bounds__(256) void k_gather(
    const ushort_t* __restrict__ msg3, const int* __restrict__ base,
    const int* __restrict__ list, float* __restrict__ xmsg,
    int e0, int ce, int accum)
{
  const int a = blockIdx.x, part = blockIdx.y, t = threadIdx.x;
  const int b0 = base[a], b1 = base[a + 1];
  const int ofs = part * 784;
  float acc[4] = {0.f, 0.f, 0.f, 0.f};
  for (int i = b0; i < b1; ++i) {
    int e = list[i];
    if (e < e0 || e >= e0 + ce) continue;
    const ushort_t* m = msg3 + (long long)(e - e0) * 6272 + ofs;
    #pragma unroll
    for (int u = 0; u < 4; ++u) {
      int idx = t + (u << 8);
      if (idx < 784) acc[u] += bf2f(m[idx]);
    }
  }
  float* o = xmsg + (long long)a * 6272 + ofs;
  #pragma unroll
  for (int u = 0; u < 4; ++u) {
    int idx = t + (u << 8);
    if (idx < 784) {
      if (accum) o[idx] += acc[u]; else o[idx] = acc[u];
    }
  }
}

// ---------------------------------------------------------------------------
// Host orchestration
// ---------------------------------------------------------------------------
extern "C" void kernel_launch(void* const* d_in, const int* in_sizes, int n_in,
                              void* d_out, int out_size, void* d_ws, size_t ws_size,
                              hipStream_t stream) {
  const float* x         = (const float*)d_in[0];
  const float* edist     = (const float*)d_in[1];
  const float* wigner    = (const float*)d_in[2];
  const float* wiginv    = (const float*)d_in[3];
  const float* to_grid   = (const float*)d_in[4];
  const float* from_grid = (const float*)d_in[5];
  const float* w_dist1   = (const float*)d_in[6];
  const float* b_dist1   = (const float*)d_in[7];
  const float* src_emb   = (const float*)d_in[8];
  const float* tgt_emb   = (const float*)d_in[9];
  const float* w_edge1   = (const float*)d_in[10];
  const float* b_edge1   = (const float*)d_in[11];
  const float* ws1       = (const float*)d_in[12];
  const float* bs1       = (const float*)d_in[13];
  const float* ws2       = (const float*)d_in[14];
  const float* bs2       = (const float*)d_in[15];
  const float* ws3       = (const float*)d_in[16];
  const float* bs3       = (const float*)d_in[17];
  const int*   anum      = (const int*)d_in[18];
  const int*   eidx      = (const int*)d_in[19];
  const float* sw[10]; const float* tw[10];
  for (int i = 0; i < 10; ++i) {
    sw[i] = (const float*)d_in[20 + i];
    tw[i] = (const float*)d_in[30 + i];
  }
  float* outp = (float*)d_out;

  // ---- workspace ----
  char* wsb = (char*)d_ws;
  size_t off = 0;
  auto alloc = [&](long long nbytes) {
    char* p = wsb + off; off += (size_t)((nbytes + 63) & ~63LL); return p;
  };
  ushort_t* x_edge  = (ushort_t*)alloc((8000LL + 128) * 128 * 2);
  ushort_t* b2ab    = (ushort_t*)alloc(5505024LL * 2);
  ushort_t* bgcw    = (ushort_t*)alloc(851968LL * 2);
  float*    bgcb    = (float*)alloc(6656 * 4);
  ushort_t* b20b    = (ushort_t*)alloc(458752LL * 2);
  ushort_t* s1m0b   = (ushort_t*)alloc(458752LL * 2);
  ushort_t* s1mb    = (ushort_t*)alloc(2752512LL * 2);
  ushort_t* wd1b    = (ushort_t*)alloc(65536 * 2);
  ushort_t* we1b    = (ushort_t*)alloc(16384 * 2);
  ushort_t* ws1b    = (ushort_t*)alloc(32768 * 2);
  ushort_t* ws2b    = (ushort_t*)alloc(16384 * 2);
  ushort_t* ws3b    = (ushort_t*)alloc(16384 * 2);
  ushort_t* tgb     = (ushort_t*)alloc(4802 * 2);
  ushort_t* fgb     = (ushort_t*)alloc(4802 * 2);
  float*    xmsg    = (float*)alloc(5017600LL * 4);
  ushort_t* xmsgb   = (ushort_t*)alloc((5017600LL + 16384) * 2);
  ushort_t* xb      = (ushort_t*)alloc((5017600LL + 16384) * 2);
  ushort_t* xbT     = (ushort_t*)alloc(6553600LL * 2);
  ushort_t* basis   = (ushort_t*)alloc((8000LL + 128) * 512 * 2);
  float*    x_dist  = (float*)alloc(1024000LL * 4);
  ushort_t* x_distb = (ushort_t*)alloc((8000LL + 128) * 128 * 2);
  int*      deg     = (int*)alloc(800 * 4);
  int*      sbase   = (int*)alloc(801 * 4);
  int*      elist   = (int*)alloc(8000 * 4);
  const size_t fixedB = off;
  char* arena = wsb + off;

  static const int ces[6] = {8000, 4000, 2000, 1000, 500, 250};
  static const int cas[6] = {800, 800, 800, 400, 200, 100};
  int ce = 250, ca = 100;
  for (int i = 0; i < 6; ++i) {
    long long ne = (long long)ces[i] * 76544 + 64LL * 50688;
    long long na = (long long)cas[i] * 87808 + 64LL * 512;
    long long need = (long long)fixedB + (ne > na ? ne : na);
    if (need <= (long long)ws_size) { ce = ces[i]; ca = cas[i]; break; }
  }

  // edge-phase arena (padded A-sources)
  char* ap = arena;
  ushort_t* xrot_s = (ushort_t*)ap;  ap += (long long)(ce + 64) * 12544;
  ushort_t* xrot_t = (ushort_t*)ap;  ap += (long long)(ce + 64) * 12544;
  ushort_t* tb0    = (ushort_t*)ap;  ap += (long long)(ce + 64) * 1024;
  ushort_t* tbm    = (ushort_t*)ap;  ap += (long long)(ce + 64) * 24576;
  ushort_t* msgp   = (ushort_t*)ap;  ap += (long long)ce * 12544;
  ushort_t* gate   = (ushort_t*)ap;
  ushort_t* msg3   = (ushort_t*)arena;   // overlays xrot after stage1
  // atom-phase arena
  char* bp = arena;
  ushort_t* hb = (ushort_t*)bp;  bp += (long long)ca * 49 * 256;
  ushort_t* g1 = (ushort_t*)bp;  bp += ((long long)ca * 98 + 64) * 256;
  ushort_t* g2 = (ushort_t*)bp;  bp += ((long long)ca * 98 + 64) * 256;
  ushort_t* g3 = (ushort_t*)bp;

  long long ofs2[7][2], s1ofs[7][2];
  { long long cur = 0, cur1 = 0;
    for (int m = 1; m <= 6; ++m) {
      int k = (7 - m) * 128;
      ofs2[m][0] = cur; cur += (long long)k * 1024;
      ofs2[m][1] = cur; cur += (long long)k * 1024;
      s1ofs[m][0] = cur1; cur1 += 512LL * k;
      s1ofs[m][1] = cur1; cur1 += 512LL * k;
    } }

  auto D0 = []() { GemmP p; memset(&p, 0, sizeof(p)); p.asplit = 1 << 30; return p; };
  auto finalize = [&](Grouped& G) {
    int base = 0;
    for (int i = 0; i < G.nd; ++i) {
      GemmP& p = G.d[i];
      p.ngx = (p.M + 127) >> 7;
      int ngy = (p.N + 127) >> 7;
      p.wg_base = base;
      base += p.ngx * ngy;
    }
    gemm_g<<<base, 256, 0, stream>>>(G);
  };
  auto run1 = [&](GemmP p) { Grouped G; G.d[0] = p; G.nd = 1; finalize(G); };
  auto rungrid = [&](const float* A, int M, int K, int permA,
                     const ushort_t* B, int b_ib, void* C, int c_ib,
                     const float* bias, int act, int c_bf16, int nb) {
    GridP p;
    p.A = A; p.B = B; p.C = C; p.bias = bias;
    p.b_ib = b_ib; p.c_ib = c_ib;
    p.M = M; p.K = K; p.permA = permA; p.act = act; p.c_bf16 = c_bf16;
    gridmm<<<nb, 256, 0, stream>>>(p);
  };
  auto cvt = [&](const float* s, ushort_t* d, int n) {
    k_cvt<<<(n + 255) / 256, 256, 0, stream>>>(s, d, n);
  };

  // 0) builds
  k_build_b2b<<<(5505024 + 255) / 256, 256, 0, stream>>>(sw[7], sw[9], tw[7], tw[9], b2ab);
  k_build_bgcat<<<(858624 + 255) / 256, 256, 0, stream>>>(
      sw[0], tw[0], sw[4], tw[4], sw[1], tw[1], sw[5], tw[5], bgcw, bgcb);
  k_build_b20b<<<(458752 + 255) / 256, 256, 0, stream>>>(sw[3], tw[3], b20b);
  k_build_s1m<<<(2752512 + 255) / 256, 256, 0, stream>>>(sw[6], sw[8], tw[6], tw[8], s1mb);
  cvt(sw[2], s1m0b, 229376);
  cvt(tw[2], s1m0b + 229376, 229376);
  cvt(w_dist1, wd1b, 65536);
  cvt(w_edge1, we1b, 16384);
  cvt(ws1, ws1b, 32768);
  cvt(ws2, ws2b, 16384);
  cvt(ws3, ws3b, 16384);
  cvt(from_grid, fgb, 4802);
  k_build_tg<<<(4802 + 255) / 256, 256, 0, stream>>>(to_grid, tgb);
  cvt(x, xb, 5017600);
  k_xT<<<AN, 256, 0, stream>>>(x, xbT);

  // scatter lists
  k_zeroi<<<4, 256, 0, stream>>>(deg, 800);
  k_deg<<<(EN + 255) / 256, 256, 0, stream>>>(eidx + EN, deg);
  k_prefix<<<1, 1024, 0, stream>>>(deg, sbase);
  k_fill<<<AN, 256, 0, stream>>>(eidx + EN, sbase, elist);

  // 1) edge features
  k_basis<<<(EN * 512 + 255) / 256, 256, 0, stream>>>(edist, basis);
  { GemmP p = D0();
    p.A = basis; p.a_se = 512; p.B = wd1b; p.ldb = 512; p.bias = b_dist1;
    p.C = x_dist; p.c_se = 128; p.M = EN; p.N = 128; p.K = 512;
    run1(p); }
  k_emb<<<(EN * 128 + 255) / 256, 256, 0, stream>>>(src_emb, tgt_emb, anum, eidx,
                                                    x_dist, x_distb);
  { GemmP p = D0();
    p.A = x_distb; p.a_se = 128; p.B = we1b; p.ldb = 128; p.bias = b_edge1;
    p.act = 1; p.C = x_edge; p.c_se = 128; p.c_bf16 = 1;
    p.M = EN; p.N = 128; p.K = 128;
    run1(p); }

  static const int offq[7] = {0, 7, 19, 29, 37, 43, 47};

  // 2) edge chunks
  for (int e0 = 0; e0 < EN; e0 += ce) {
    const int c = ce;
    k_rot2<<<c, 256, 0, stream>>>(wigner + (long long)e0 * 2401, xbT,
                                  eidx + e0, eidx + EN + e0, xrot_s, xrot_t);
    // gates
    { GemmP p = D0();
      p.A = x_edge + (long long)e0 * 128; p.a_se = 128;
      p.B = bgcw; p.ldb = 128; p.bias = bgcb; p.act = 1;
      p.C = gate; p.c_se = 6656; p.c_bf16 = 1;
      p.M = c; p.N = 6656; p.K = 128;
      run1(p); }
    // stage 1 grouped
    { Grouped G; G.nd = 14;
      for (int s = 0; s < 2; ++s) {
        GemmP p = D0();
        p.A = s ? xrot_t : xrot_s; p.a_se = 6272;
        p.B = s1m0b + (long long)s * 229376; p.ldb = 896;
        p.gate = gate; p.gate_ofs = s * 256;
        p.C = tb0; p.c_se = 512; p.c_ofs = s * 256; p.c_bf16 = 1;
        p.M = c; p.N = 256; p.K = 896;
        G.d[s] = p;
      }
      int di = 2;
      for (int m = 1; m <= 6; ++m) {
        const int k = (7 - m) * 128, off2 = offq[m];
        for (int s = 0; s < 2; ++s) {
          GemmP p = D0();
          p.A = (s ? xrot_t : xrot_s) + off2 * 128;
          p.a_se = 6272; p.a_si = k; p.pair = 1;
          p.B = s1mb + s1ofs[m][s]; p.ldb = k;
          p.gate = gate; p.gate_ofs = 512 + (m - 1) * 1024 + s * 512;
          p.C = tbm; p.c_se = 12288; p.c_si = 1024;
          p.c_ofs = (m - 1) * 2048 + s * 512;
          p.ihalf = 1; p.c_bf16 = 1;
          p.M = 2 * c; p.N = 512; p.K = k;
          G.d[di++] = p;
        }
      }
      finalize(G); }
    // stage 2 grouped
    { Grouped G; G.nd = 13;
      { GemmP p = D0();
        p.A = tb0; p.a_se = 512;
        p.B = b20b; p.ldb = 512;
        p.C = msgp; p.c_se = 6272; p.c_bf16 = 1;
        p.M = c; p.N = 896; p.K = 512;
        G.d[0] = p; }
      int di = 1;
      for (int m = 1; m <= 6; ++m) {
        const int n = 7 - m, k = n * 128, off2 = offq[m];
        for (int pp = 0; pp < 2; ++pp) {
          GemmP p = D0();
          p.A = tbm + (m - 1) * 2048 + pp * 1024; p.a_se = 12288;
          p.B = b2ab + ofs2[m][pp]; p.ldb = 1024;
          p.C = msgp; p.c_se = 6272; p.c_ofs = (off2 + (pp ? n : 0)) * 128; p.c_bf16 = 1;
          p.M = c; p.N = k; p.K = 1024;
          G.d[di++] = p;
        }
      }
      finalize(G); }
    // fused grid pipeline + gather
    k_grid<<<c, 256, 0, stream>>>(tgb, fgb, wiginv + (long long)e0 * 2401, msgp, msg3);
    k_gather<<<dim3(AN, 8), 256, 0, stream>>>(msg3, sbase, elist, xmsg, e0, c, e0 > 0);
  }

  // xmsg -> bf16 for atom GEMM
  cvt(xmsg, xmsgb, 5017600);

  // 3) atom phase
  for (int a0 = 0; a0 < AN; a0 += ca) {
    { GemmP p = D0();
      p.A = xb + (long long)a0 * 6272; p.A2 = xmsgb + (long long)a0 * 6272;
      p.a_se = 128; p.asplit = 128;
      p.B = ws1b; p.ldb = 256;
      p.C = hb; p.c_se = 128; p.c_bf16 = 1;
      p.M = ca * 49; p.N = 128; p.K = 256;
      run1(p); }
    rungrid(to_grid, 98, 49, 0, hb, 6272, g1, 12544, bs1, 1, 1, ca);
    { GemmP p = D0();
      p.A = g1; p.a_se = 128;
      p.B = ws2b; p.ldb = 128; p.bias = bs2; p.act = 1;
      p.C = g2; p.c_se = 128; p.c_bf16 = 1;
      p.M = ca * 98; p.N = 128; p.K = 128;
      run1(p); }
    { GemmP p = D0();
      p.A = g2; p.a_se = 128;
      p.B = ws3b; p.ldb = 128; p.bias = bs3;
      p.C = g3; p.c_se = 128; p.c_bf16 = 1;
      p.M = ca * 98; p.N = 128; p.K = 128;
      run1(p); }
    rungrid(from_grid, 49, 98, 0, g3, 12544, outp + (long long)a0 * 6272, 6272,
            nullptr, 0, 0, ca);
  }
}

// Round 7
// 1759.851 us; speedup vs baseline: 12.3003x; 1.0254x over previous
//
#include <hip/hip_runtime.h>
#include <string.h>

#define EN 8000
#define AN 800

typedef __attribute__((ext_vector_type(8))) short bf16x8;
typedef __attribute__((ext_vector_type(4))) float f32x4;
typedef unsigned short ushort_t;
typedef unsigned int uint32;

__constant__ int c_perm[49] = {
  0,2,6,12,20,30,42,
  1,5,11,19,29,41,
  3,7,13,21,31,43,
  4,10,18,28,40,
  8,14,22,32,44,
  9,17,27,39,
  15,23,33,45,
  16,26,38,
  24,34,46,
  25,37,
  35,47,
  36,
  48
};

__device__ __forceinline__ float siluf(float x) { return x / (1.0f + __expf(-x)); }
__device__ __forceinline__ ushort_t f2bf(float f) {
  uint32 u = __float_as_uint(f);
  u += 0x7fff + ((u >> 16) & 1);
  return (ushort_t)(u >> 16);
}
__device__ __forceinline__ float bf2f(ushort_t h) {
  return __uint_as_float(((uint32)h) << 16);
}
__device__ __forceinline__ void gld16(const void* g, void* l) {
  __builtin_amdgcn_global_load_lds(
      (const __attribute__((address_space(1))) void*)g,
      (__attribute__((address_space(3))) void*)l, 16, 0, 0);
}

// ---------------------------------------------------------------------------
// Weight builders (bf16 outputs)
// ---------------------------------------------------------------------------
__global__ __launch_bounds__(256) void k_build_b2b(
    const float* __restrict__ sw2r, const float* __restrict__ sw2i,
    const float* __restrict__ tw2r, const float* __restrict__ tw2i,
    ushort_t* __restrict__ dst)
{
  long long id = (long long)blockIdx.x * 256 + threadIdx.x;
  if (id >= 5505024LL) return;
  long long base = 0; int m = 1, k = 768;
  for (; m <= 6; ++m) {
    k = (7 - m) * 128;
    long long sz = 2LL * k * 1024;
    if (id < base + sz) break;
    base += sz;
  }
  long long rem = id - base;
  int p = (int)(rem / ((long long)k * 1024));
  int cj = (int)(rem - (long long)p * k * 1024);
  int c = cj >> 10, j = cj & 1023;
  int q = j >> 8, jj = j & 255;
  const float sgn = (q & 1) ? (p ? 1.f : -1.f) : 1.f;
  const float* src = (q < 2) ? (q == 0 ? sw2r : sw2i) : (q == 2 ? tw2r : tw2i);
  dst[id] = f2bf(sgn * src[(long long)(m - 1) * 196608 + c * 256 + jj]);
}

__global__ __launch_bounds__(256) void k_build_bgcat(
    const float* __restrict__ sw0, const float* __restrict__ tw0,
    const float* __restrict__ sw4, const float* __restrict__ tw4,
    const float* __restrict__ sb0, const float* __restrict__ tb0b,
    const float* __restrict__ sbd, const float* __restrict__ tbd,
    ushort_t* __restrict__ w, float* __restrict__ b)
{
  int id = blockIdx.x * 256 + threadIdx.x;
  if (id < 851968) {
    int r = id >> 7, c = id & 127;
    float v;
    if (r < 256) v = sw0[r * 128 + c];
    else if (r < 512) v = tw0[(r - 256) * 128 + c];
    else {
      int rr = r - 512, m = rr >> 10, q = rr & 1023;
      v = (q < 512) ? sw4[m * 65536 + q * 128 + c] : tw4[m * 65536 + (q - 512) * 128 + c];
    }
    w[id] = f2bf(v);
    return;
  }
  id -= 851968;
  if (id < 6656) {
    float v;
    if (id < 256) v = sb0[id];
    else if (id < 512) v = tb0b[id - 256];
    else {
      int rr = id - 512, m = rr >> 10, q = rr & 1023;
      v = (q < 512) ? sbd[m * 512 + q] : tbd[m * 512 + (q - 512)];
    }
    b[id] = v;
  }
}

__global__ __launch_bounds__(256) void k_build_b20b(
    const float* __restrict__ sw3, const float* __restrict__ tw3,
    ushort_t* __restrict__ b20)
{
  int id = blockIdx.x * 256 + threadIdx.x;
  if (id >= 458752) return;
  int cc = id >> 9, j = id & 511;
  b20[id] = f2bf((j < 256) ? sw3[cc * 256 + j] : tw3[cc * 256 + (j - 256)]);
}

__global__ __launch_bounds__(256) void k_build_s1m(
    const float* __restrict__ sw6, const float* __restrict__ sw8,
    const float* __restrict__ tw6, const float* __restrict__ tw8,
    ushort_t* __restrict__ dst)
{
  long long id = (long long)blockIdx.x * 256 + threadIdx.x;
  if (id >= 2752512LL) return;
  long long base = 0; int m = 1, k = 768;
  for (; m <= 6; ++m) {
    k = (7 - m) * 128;
    long long sz = 1024LL * k;
    if (id < base + sz) break;
    base += sz;
  }
  long long rem = id - base;
  int s = (int)(rem / (512LL * k));
  int rr = (int)(rem - (long long)s * 512 * k);
  int r = rr / k, c = rr - r * k;
  const float* src = (r < 256) ? (s ? tw6 : sw6) : (s ? tw8 : sw8);
  int r0 = (r < 256) ? r : r - 256;
  dst[id] = f2bf(src[(long long)(m - 1) * 196608 + r0 * 768 + c]);
}

__global__ __launch_bounds__(256) void k_cvt(
    const float* __restrict__ src, ushort_t* __restrict__ dst, int n)
{
  int id = blockIdx.x * 256 + threadIdx.x;
  if (id < n) dst[id] = f2bf(src[id]);
}

__global__ __launch_bounds__(256) void k_build_tg(
    const float* __restrict__ tg, ushort_t* __restrict__ dst)
{
  int id = blockIdx.x * 256 + threadIdx.x;
  if (id >= 98 * 49) return;
  int r = id / 49, s = id - r * 49;
  dst[id] = f2bf(tg[r * 49 + c_perm[s]]);
}

// transpose x (f32 [49][128]) -> xbT (bf16 [128][64], j-padded)
__global__ __launch_bounds__(256) void k_xT(
    const float* __restrict__ x, ushort_t* __restrict__ xbT)
{
  __shared__ __align__(16) float xs[49 * 128];
  const int a = blockIdx.x, t = threadIdx.x;
  const float4* src = (const float4*)(x + (long long)a * 6272);
  float4* d = (float4*)xs;
  for (int i = t; i < 1568; i += 256) d[i] = src[i];
  __syncthreads();
  ushort_t* o = xbT + (long long)a * 8192;
  int c = t >> 1;
  int jg = (t & 1) << 2;
  #pragma unroll
  for (int u = 0; u < 4; ++u) {
    int g = jg + u;
    bf16x8 v = (bf16x8)0;
    #pragma unroll
    for (int j = 0; j < 8; ++j) {
      int jj = (g << 3) + j;
      if (jj < 49) v[j] = (short)f2bf(xs[jj * 128 + c]);
    }
    *(bf16x8*)&o[(c << 6) + (g << 3)] = v;
  }
}

// ---------------------------------------------------------------------------
// Edge features
// ---------------------------------------------------------------------------
__global__ __launch_bounds__(256) void k_basis(
    const float* __restrict__ dist, ushort_t* __restrict__ basis)
{
  int id = blockIdx.x * 256 + threadIdx.x;
  if (id >= EN * 512) return;
  int e = id >> 9, g = id & 511;
  const float step = 8.0f / 511.0f;
  const float coeff = -2040.0078125f;
  float df = dist[e] - (float)g * step;
  basis[id] = f2bf(expf(coeff * df * df));
}

__global__ __launch_bounds__(256) void k_emb(
    const float* __restrict__ src_emb, const float* __restrict__ tgt_emb,
    const int* __restrict__ anum, const int* __restrict__ eidx,
    const float* __restrict__ xd, ushort_t* __restrict__ out)
{
  int id = blockIdx.x * 256 + threadIdx.x;
  if (id >= EN * 128) return;
  int e = id >> 7, c = id & 127;
  int a0 = anum[eidx[e]], a1 = anum[eidx[EN + e]];
  out[id] = f2bf(siluf(src_emb[a0 * 128 + c] + tgt_emb[a1 * 128 + c] + xd[id]));
}

// ---------------------------------------------------------------------------
// MFMA Wigner rotation: out[q][c] = sum_j W[perm[q]][j] * x[j][c] (s and t)
// ---------------------------------------------------------------------------
__global__ __launch_bounds__(256) void k_rot2(
    const float* __restrict__ wig, const ushort_t* __restrict__ xbT,
    const int* __restrict__ srcl, const int* __restrict__ tgtl,
    ushort_t* __restrict__ osrc, ushort_t* __restrict__ otgt)
{
  __shared__ short Ws[4096];   // [64][64] bf16, 8-slot swz
  __shared__ short Xs[8192];   // [128][64]
  __shared__ short Xt[8192];
  const int e = blockIdx.x, tid = threadIdx.x;
  const int lane = tid & 63, wave = tid >> 6;
  const float* wge = wig + (long long)e * 2401;
  #pragma unroll
  for (int t = 0; t < 2; ++t) {
    int ci = (t << 8) + tid;
    int row = ci >> 3, g = ci & 7;
    bf16x8 v = (bf16x8)0;
    if (row < 49) {
      const float* wr = wge + c_perm[row] * 49;
      #pragma unroll
      for (int j = 0; j < 8; ++j) {
        int col = (g << 3) + j;
        if (col < 49) v[j] = (short)f2bf(wr[col]);
      }
    }
    *(bf16x8*)&Ws[(row << 6) + ((g ^ (row & 7)) << 3)] = v;
  }
  const int as = srcl[e], at = tgtl[e];
  const ushort_t* xsg = xbT + (long long)as * 8192;
  const ushort_t* xtg = xbT + (long long)at * 8192;
  #pragma unroll
  for (int t = 0; t < 4; ++t) {
    int ci = (t << 8) + tid;
    int row = ci >> 3, g = ci & 7;
    int ofs = (row << 6) + ((g ^ (row & 7)) << 3);
    *(bf16x8*)&Xs[ofs] = *(const bf16x8*)&xsg[ci << 3];
    *(bf16x8*)&Xt[ofs] = *(const bf16x8*)&xtg[ci << 3];
  }
  __syncthreads();
  const short* Xb = (wave >> 1) ? Xt : Xs;
  ushort_t* ob = ((wave >> 1) ? otgt : osrc) + (long long)e * 6272;
  const int ch = (wave & 1) << 6;
  const int fr = lane & 15, g = lane >> 4;
  f32x4 acc[4][4];
  #pragma unroll
  for (int i = 0; i < 4; ++i)
    #pragma unroll
    for (int j = 0; j < 4; ++j) acc[i][j] = (f32x4){0.f, 0.f, 0.f, 0.f};
  #pragma unroll
  for (int ks = 0; ks < 2; ++ks) {
    bf16x8 af[4], bfv[4];
    int lc = (ks << 2) + g;
    #pragma unroll
    for (int i = 0; i < 4; ++i) {
      int ra = (i << 4) + fr;
      af[i] = *(const bf16x8*)&Ws[(ra << 6) + ((lc ^ (ra & 7)) << 3)];
      int rb = ch + (i << 4) + fr;
      bfv[i] = *(const bf16x8*)&Xb[(rb << 6) + ((lc ^ (rb & 7)) << 3)];
    }
    #pragma unroll
    for (int i = 0; i < 4; ++i)
      #pragma unroll
      for (int j = 0; j < 4; ++j)
        acc[i][j] = __builtin_amdgcn_mfma_f32_16x16x32_bf16(af[i], bfv[j], acc[i][j], 0, 0, 0);
  }
  const int crl = (lane >> 4) << 2, ccl = lane & 15;
  #pragma unroll
  for (int i = 0; i < 4; ++i)
    #pragma unroll
    for (int r = 0; r < 4; ++r) {
      int q = (i << 4) + crl + r;
      if (q < 49) {
        #pragma unroll
        for (int j = 0; j < 4; ++j) {
          int col = ch + (j << 4) + ccl;
          ob[q * 128 + col] = f2bf(acc[i][j][r]);
        }
      }
    }
}

// ---------------------------------------------------------------------------
// Grouped MFMA GEMM, all-bf16, global_load_lds + XOR swizzle,
// DOUBLE-BUFFERED K-loop with counted vmcnt (T3/T4): loads stay in flight
// across barriers; vmcnt(4) waits only for the previous stage's 4 loads.
// ---------------------------------------------------------------------------
struct GemmP {
  const ushort_t* A; const ushort_t* A2; const ushort_t* B;
  const float* bias; const ushort_t* gate; void* C;
  int a_se, a_si, pair, asplit;
  int ldb;
  int gate_ofs;
  int c_se, c_si, c_ofs;
  int ihalf, act, c_bf16;
  int M, N, K;
  int ngx, wg_base;
};
struct Grouped { GemmP d[14]; int nd; };

__global__ __launch_bounds__(256) void gemm_g(Grouped G) {
  __shared__ short As[8192];   // 2 x [128 rows][32 k] 4-slot swz
  __shared__ short Bs[8192];
  const int bid = blockIdx.x;
  int di = G.nd - 1;
  for (int i = 1; i < G.nd; ++i) if (bid < G.d[i].wg_base) { di = i - 1; break; }
  const GemmP p = G.d[di];
  const int local = bid - p.wg_base;
  const int bx = local % p.ngx, by = local / p.ngx;
  const int m0 = bx << 7, n0 = by << 7;

  const int tid = threadIdx.x;
  const int lane = tid & 63, wave = tid >> 6;
  const int gl = ((lane & 3) ^ ((lane >> 3) & 3)) << 3;  // pre-swizzled k-offset
  const int grow = (wave << 4) + (lane >> 2);
  const int fr = lane & 15, fkg = lane >> 4;
  const int sxor = (fr >> 1) & 3;
  const int wm = (wave >> 1) << 6, wn = (wave & 1) << 6;

  f32x4 acc[4][4];
  #pragma unroll
  for (int i = 0; i < 4; ++i)
    #pragma unroll
    for (int j = 0; j < 4; ++j) acc[i][j] = (f32x4){0.f, 0.f, 0.f, 0.f};

  // per-thread global row addressing (constant across K-steps)
  long long abase;
  {
    int r0 = m0 + grow;
    abase = p.pair
        ? (long long)(r0 >> 1) * p.a_se + (long long)(r0 & 1) * p.a_si
        : (long long)r0 * p.a_se;
  }
  long long abase2;
  {
    int r1 = m0 + 64 + grow;
    abase2 = p.pair
        ? (long long)(r1 >> 1) * p.a_se + (long long)(r1 & 1) * p.a_si
        : (long long)r1 * p.a_se;
  }
  const long long bbase  = (long long)(n0 + grow) * p.ldb;
  const long long bbase2 = (long long)(n0 + 64 + grow) * p.ldb;

  const int nt = p.K >> 5;

  // stage one K-tile into buffer `buf`
  auto STAGE = [&](int buf, int k0) {
    const ushort_t* Ap = p.A;
    int kk = k0;
    if (p.A2 && k0 >= p.asplit) { Ap = p.A2; kk = k0 - p.asplit; }
    const int lofs = (buf << 12) + (wave << 9);
    gld16(Ap + abase + kk + gl,        &As[lofs]);
    gld16(p.B + bbase + k0 + gl,       &Bs[lofs]);
    gld16(Ap + abase2 + kk + gl,       &As[lofs + 2048]);
    gld16(p.B + bbase2 + k0 + gl,      &Bs[lofs + 2048]);
  };

  STAGE(0, 0);
  int cur = 0;
  for (int t = 0; t < nt; ++t) {
    if (t + 1 < nt) {
      STAGE(cur ^ 1, (t + 1) << 5);
      asm volatile("s_waitcnt vmcnt(4)" ::: "memory");
    } else {
      asm volatile("s_waitcnt vmcnt(0)" ::: "memory");
    }
    __builtin_amdgcn_sched_barrier(0);
    __builtin_amdgcn_s_barrier();
    {
      const int bofs = cur << 12;
      bf16x8 af[4], bfv[4];
      #pragma unroll
      for (int i = 0; i < 4; ++i) {
        int ra = wm + (i << 4) + fr;
        int rb = wn + (i << 4) + fr;
        af[i]  = *(const bf16x8*)&As[bofs + (ra << 5) + ((fkg ^ sxor) << 3)];
        bfv[i] = *(const bf16x8*)&Bs[bofs + (rb << 5) + ((fkg ^ sxor) << 3)];
      }
      #pragma unroll
      for (int i = 0; i < 4; ++i)
        #pragma unroll
        for (int j = 0; j < 4; ++j)
          acc[i][j] = __builtin_amdgcn_mfma_f32_16x16x32_bf16(af[i], bfv[j], acc[i][j], 0, 0, 0);
    }
    __builtin_amdgcn_s_barrier();
    cur ^= 1;
  }

  const int crl = (lane >> 4) << 2, ccl = lane & 15;
  #pragma unroll
  for (int mi = 0; mi < 4; ++mi) {
    #pragma unroll
    for (int r = 0; r < 4; ++r) {
      int gr = m0 + wm + mi * 16 + crl + r;
      if (gr >= p.M) continue;
      long long e; int ii;
      if (p.pair) { e = gr >> 1; ii = gr & 1; } else { e = gr; ii = 0; }
      const ushort_t* grw = p.gate ? p.gate + e * 6656 + p.gate_ofs : nullptr;
      #pragma unroll
      for (int ni = 0; ni < 4; ++ni) {
        int gc = n0 + wn + ni * 16 + ccl;
        if (gc >= p.N) continue;
        float v = acc[mi][ni][r];
        if (p.bias) v += p.bias[gc];
        if (p.act)  v = siluf(v);
        if (grw)    v *= bf2f(grw[gc]);
        int par = (p.ihalf && gc >= 256) ? (1 - ii) : ii;
        long long co = e * (long long)p.c_se + (long long)par * p.c_si + p.c_ofs + gc;
        if (p.c_bf16) ((ushort_t*)p.C)[co] = f2bf(v);
        else          ((float*)p.C)[co] = v;
      }
    }
  }
}

// ---------------------------------------------------------------------------
// gridmm (atom phase)
// ---------------------------------------------------------------------------
struct GridP {
  const float* A; const ushort_t* B; void* C; const float* bias;
  int b_ib, c_ib;
  int M, K, permA, act, c_bf16;
};

#define LDW 40

__global__ __launch_bounds__(256) void gridmm(GridP p) {
  __shared__ short As[128 * LDW];
  __shared__ short Bs[128 * LDW];
  const int e = blockIdx.x;
  const int tid = threadIdx.x;
  const int srow = tid >> 1, sk = (tid & 1) << 4;
  const int lane = tid & 63, wave = tid >> 6;
  const int wm = (wave >> 1) << 6, wn = (wave & 1) << 6;
  const int fr = lane & 15, fk = (lane >> 4) << 3;

  f32x4 acc[4][4];
  #pragma unroll
  for (int i = 0; i < 4; ++i)
    #pragma unroll
    for (int j = 0; j < 4; ++j) acc[i][j] = (f32x4){0.f, 0.f, 0.f, 0.f};

  const ushort_t* bp0 = p.B + (long long)e * p.b_ib;

  for (int k0 = 0; k0 < p.K; k0 += 32) {
    {
      bf16x8 lo = (bf16x8)0, hi = (bf16x8)0;
      if (srow < p.M) {
        const float* ar = p.A + srow * p.K;
        #pragma unroll
        for (int j = 0; j < 8; ++j) {
          int col = k0 + sk + j;
          float v = 0.f;
          if (col < p.K) v = ar[p.permA ? c_perm[col] : col];
          lo[j] = (short)f2bf(v);
        }
        #pragma unroll
        for (int j = 0; j < 8; ++j) {
          int col = k0 + sk + 8 + j;
          float v = 0.f;
          if (col < p.K) v = ar[p.permA ? c_perm[col] : col];
          hi[j] = (short)f2bf(v);
        }
      }
      *(bf16x8*)&As[srow * LDW + sk] = lo;
      *(bf16x8*)&As[srow * LDW + sk + 8] = hi;
    }
    {
      const int c = tid & 127, kq = tid >> 7;
      #pragma unroll
      for (int i = 0; i < 8; ++i) {
        int kk = kq * 16 + i * 2;
        int k1 = k0 + kk, k2 = k1 + 1;
        uint32 v0 = (k1 < p.K) ? (uint32)bp0[(long long)k1 * 128 + c] : 0u;
        uint32 v1 = (k2 < p.K) ? (uint32)bp0[(long long)k2 * 128 + c] : 0u;
        *(uint32*)&Bs[c * LDW + kk] = v0 | (v1 << 16);
      }
    }
    __syncthreads();
    bf16x8 af[4], bfv[4];
    #pragma unroll
    for (int i = 0; i < 4; ++i) {
      af[i]  = *(const bf16x8*)(&As[(wm + i * 16 + fr) * LDW + fk]);
      bfv[i] = *(const bf16x8*)(&Bs[(wn + i * 16 + fr) * LDW + fk]);
    }
    #pragma unroll
    for (int i = 0; i < 4; ++i)
      #pragma unroll
      for (int j = 0; j < 4; ++j)
        acc[i][j] = __builtin_amdgcn_mfma_f32_16x16x32_bf16(af[i], bfv[j], acc[i][j], 0, 0, 0);
    __syncthreads();
  }

  const int crl = (lane >> 4) << 2, ccl = lane & 15;
  #pragma unroll
  for (int mi = 0; mi < 4; ++mi) {
    #pragma unroll
    for (int r = 0; r < 4; ++r) {
      int gr = wm + mi * 16 + crl + r;
      if (gr >= p.M) continue;
      #pragma unroll
      for (int ni = 0; ni < 4; ++ni) {
        int c = wn + ni * 16 + ccl;
        float v = acc[mi][ni][r];
        if (p.bias) v += p.bias[c];
        if (p.act)  v = siluf(v);
        long long co = (long long)e * p.c_ib + gr * 128 + c;
        if (p.c_bf16) ((ushort_t*)p.C)[co] = f2bf(v);
        else          ((float*)p.C)[co] = v;
      }
    }
  }
}

// ---------------------------------------------------------------------------
// Fused grid pipeline per edge: msg3 = WI @ (FG @ silu(TGp @ msgp))
// ---------------------------------------------------------------------------
#define SWZ8(cg, r) (((cg) ^ ((r) & 7)) & 7)
#define SWZ16(cg, r) (((cg) & 8) | (((cg) ^ (r)) & 7))

__global__ __launch_bounds__(256, 2) void k_grid(
    const ushort_t* __restrict__ tgb, const ushort_t* __restrict__ fgb,
    const float* __restrict__ wigv, const ushort_t* __restrict__ msgp,
    ushort_t* __restrict__ msg3)
{
  __shared__ short Abuf[8192];
  __shared__ short Bsh[8192];
  __shared__ short Ps[16384];
  const int e = blockIdx.x, tid = threadIdx.x;
  const int lane = tid & 63, wv = tid >> 6;
  const int fr = lane & 15, fk = (lane >> 4) << 3;
  const int crl = (lane >> 4) << 2, ccl = lane & 15;
  const ushort_t* me = msgp + (long long)e * 6272;

  for (int gid = tid; gid < 896; gid += 256) {
    int r = gid >> 3, cg = gid & 7;
    bf16x8 v = (bf16x8)0;
    if (r < 98) {
      #pragma unroll
      for (int j = 0; j < 8; ++j) {
        int col = (cg << 3) + j;
        if (col < 49) v[j] = (short)tgb[r * 49 + col];
      }
    }
    *(bf16x8*)&Abuf[(r << 6) + (SWZ8(cg, r) << 3)] = v;
  }
  for (int gid = tid; gid < 1024; gid += 256) {
    int kg = gid >> 7, c = gid & 127;
    bf16x8 v = (bf16x8)0;
    #pragma unroll
    for (int j = 0; j < 8; ++j) {
      int k = (kg << 3) + j;
      if (k < 49) v[j] = (short)me[k * 128 + c];
    }
    *(bf16x8*)&Bsh[(c << 6) + (SWZ8(kg, c) << 3)] = v;
  }
  {
    int c = tid >> 1, gg = 14 + (tid & 1);
    *(bf16x8*)&Ps[(c << 7) + (SWZ16(gg, c) << 3)] = (bf16x8)0;
  }
  __syncthreads();

  {
    f32x4 acc[7][2];
    #pragma unroll
    for (int i = 0; i < 7; ++i) { acc[i][0] = (f32x4){0,0,0,0}; acc[i][1] = (f32x4){0,0,0,0}; }
    #pragma unroll
    for (int k0 = 0; k0 < 64; k0 += 32) {
      int cg = (k0 + fk) >> 3;
      int br0 = ((2 * wv) << 4) + fr, br1 = ((2 * wv + 1) << 4) + fr;
      bf16x8 bf0 = *(const bf16x8*)&Bsh[(br0 << 6) + (SWZ8(cg, br0) << 3)];
      bf16x8 bf1 = *(const bf16x8*)&Bsh[(br1 << 6) + (SWZ8(cg, br1) << 3)];
      #pragma unroll
      for (int rt = 0; rt < 7; ++rt) {
        int ar = (rt << 4) + fr;
        bf16x8 af = *(const bf16x8*)&Abuf[(ar << 6) + (SWZ8(cg, ar) << 3)];
        acc[rt][0] = __builtin_amdgcn_mfma_f32_16x16x32_bf16(af, bf0, acc[rt][0], 0, 0, 0);
        acc[rt][1] = __builtin_amdgcn_mfma_f32_16x16x32_bf16(af, bf1, acc[rt][1], 0, 0, 0);
      }
    }
    #pragma unroll
    for (int rt = 0; rt < 7; ++rt)
      #pragma unroll
      for (int cj = 0; cj < 2; ++cj) {
        int c = ((2 * wv + cj) << 4) + ccl;
        #pragma unroll
        for (int r = 0; r < 4; ++r) {
          int g = (rt << 4) + crl + r;
          Ps[(c << 7) + (SWZ16(g >> 3, c) << 3) + (g & 7)] =
              (short)f2bf(siluf(acc[rt][cj][r]));
        }
      }
  }
  __syncthreads();
  for (int gid = tid; gid < 1024; gid += 256) {
    int r = gid >> 4, cg = gid & 15;
    bf16x8 v = (bf16x8)0;
    if (r < 49) {
      #pragma unroll
      for (int j = 0; j < 8; ++j) {
        int col = (cg << 3) + j;
        if (col < 98) v[j] = (short)fgb[r * 98 + col];
      }
    }
    *(bf16x8*)&Abuf[(r << 7) + (SWZ16(cg, r) << 3)] = v;
  }
  __syncthreads();

  {
    f32x4 acc[4][2];
    #pragma unroll
    for (int i = 0; i < 4; ++i) { acc[i][0] = (f32x4){0,0,0,0}; acc[i][1] = (f32x4){0,0,0,0}; }
    #pragma unroll
    for (int k0 = 0; k0 < 128; k0 += 32) {
      int cg = (k0 + fk) >> 3;
      int br0 = ((2 * wv) << 4) + fr, br1 = ((2 * wv + 1) << 4) + fr;
      bf16x8 bf0 = *(const bf16x8*)&Ps[(br0 << 7) + (SWZ16(cg, br0) << 3)];
      bf16x8 bf1 = *(const bf16x8*)&Ps[(br1 << 7) + (SWZ16(cg, br1) << 3)];
      #pragma unroll
      for (int rt = 0; rt < 4; ++rt) {
        int ar = (rt << 4) + fr;
        bf16x8 af = *(const bf16x8*)&Abuf[(ar << 7) + (SWZ16(cg, ar) << 3)];
        acc[rt][0] = __builtin_amdgcn_mfma_f32_16x16x32_bf16(af, bf0, acc[rt][0], 0, 0, 0);
        acc[rt][1] = __builtin_amdgcn_mfma_f32_16x16x32_bf16(af, bf1, acc[rt][1], 0, 0, 0);
      }
    }
    #pragma unroll
    for (int rt = 0; rt < 4; ++rt)
      #pragma unroll
      for (int cj = 0; cj < 2; ++cj) {
        int c = ((2 * wv + cj) << 4) + ccl;
        #pragma unroll
        for (int r = 0; r < 4; ++r) {
          int q = (rt << 4) + crl + r;
          Bsh[(c << 6) + (SWZ8(q >> 3, c) << 3) + (q & 7)] = (short)f2bf(acc[rt][cj][r]);
        }
      }
  }
  __syncthreads();
  {
    const float* we = wigv + (long long)e * 2401;
    for (int gid = tid; gid < 512; gid += 256) {
      int r = gid >> 3, cg = gid & 7;
      bf16x8 v = (bf16x8)0;
      if (r < 49) {
        #pragma unroll
        for (int j = 0; j < 8; ++j) {
          int col = (cg << 3) + j;
          if (col < 49) v[j] = (short)f2bf(we[r * 49 + col]);
        }
      }
      *(bf16x8*)&Abuf[(r << 6) + (SWZ8(cg, r) << 3)] = v;
    }
  }
  __syncthreads();

  {
    f32x4 acc[4][2];
    #pragma unroll
    for (int i = 0; i < 4; ++i) { acc[i][0] = (f32x4){0,0,0,0}; acc[i][1] = (f32x4){0,0,0,0}; }
    #pragma unroll
    for (int k0 = 0; k0 < 64; k0 += 32) {
      int cg = (k0 + fk) >> 3;
      int br0 = ((2 * wv) << 4) + fr, br1 = ((2 * wv + 1) << 4) + fr;
      bf16x8 bf0 = *(const bf16x8*)&Bsh[(br0 << 6) + (SWZ8(cg, br0) << 3)];
      bf16x8 bf1 = *(const bf16x8*)&Bsh[(br1 << 6) + (SWZ8(cg, br1) << 3)];
      #pragma unroll
      for (int rt = 0; rt < 4; ++rt) {
        int ar = (rt << 4) + fr;
        bf16x8 af = *(const bf16x8*)&Abuf[(ar << 6) + (SWZ8(cg, ar) << 3)];
        acc[rt][0] = __builtin_amdgcn_mfma_f32_16x16x32_bf16(af, bf0, acc[rt][0], 0, 0, 0);
        acc[rt][1] = __builtin_amdgcn_mfma_f32_16x16x32_bf16(af, bf1, acc[rt][1], 0, 0, 0);
      }
    }
    ushort_t* oe = msg3 + (long long)e * 6272;
    #pragma unroll
    for (int rt = 0; rt < 4; ++rt)
      #pragma unroll
      for (int r = 0; r < 4; ++r) {
        int gi = (rt << 4) + crl + r;
        if (gi < 49) {
          #pragma unroll
          for (int cj = 0; cj < 2; ++cj) {
            int c = ((2 * wv + cj) << 4) + ccl;
            oe[gi * 128 + c] = f2bf(acc[rt][cj][r]);
          }
        }
      }
  }
}

// ---------------------------------------------------------------------------
// Segment-sum via per-atom edge lists
// ---------------------------------------------------------------------------
__global__ __launch_bounds__(256) void k_zeroi(int* __restrict__ p, int n) {
  int id = blockIdx.x * 256 + threadIdx.x;
  if (id < n) p[id] = 0;
}

__global__ __launch_bounds__(256) void k_deg(
    const int* __restrict__ tgt, int* __restrict__ deg) {
  int e = blockIdx.x * 256 + threadIdx.x;
  if (e < EN) atomicAdd(&deg[tgt[e]], 1);
}

__global__ __launch_bounds__(1024) void k_prefix(
    const int* __restrict__ deg, int* __restrict__ base) {
  __shared__ int s[1024];
  int t = threadIdx.x;
  s[t] = (t < AN) ? deg[t] : 0;
  __syncthreads();
  for (int ofs = 1; ofs < 1024; ofs <<= 1) {
    int u = (t >= ofs) ? s[t - ofs] : 0;
    __syncthreads();
    s[t] += u;
    __syncthreads();
  }
  if (t < AN) base[t + 1] = s[t];
  if (t == 0) base[0] = 0;
}

__global__ __launch_bounds__(256) void k_fill(
    const int* __restrict__ tgt, const int* __restrict__ base,
    int* __restrict__ list) {
  const int a = blockIdx.x, t = threadIdx.x;
  const int lane = t & 63, w = t >> 6;
  __shared__ int wtot[4];
  __shared__ int runbase;
  if (t == 0) runbase = base[a];
  __syncthreads();
  for (int i0 = 0; i0 < EN; i0 += 256) {
    int e = i0 + t;
    bool m = (e < EN) && (tgt[e] == a);
    unsigned long long bal = __ballot(m);
    if (lane == 0) wtot[w] = __popcll(bal);
    __syncthreads();
    int wbase = 0;
    for (int j = 0; j < w; ++j) wbase += wtot[j];
    int tot = wtot[0] + wtot[1] + wtot[2] + wtot[3];
    if (m) {
      int off = __popcll(bal & ((1ull << lane) - 1ull));
      list[runbase + wbase + off] = e;
    }
    __syncthreads();
    if (t == 0) runbase += tot;
    __syncthreads();
  }
}

__global__ __launch_bounds__(256) void k_gather(
    const ushort_t* __restrict__ msg3, const int* __restrict__ base,
    const int* __restrict__ list, float* __restrict__ xmsg,
    int e0, int ce, int accum)
{
  const int a = blockIdx.x, part = blockIdx.y, t = threadIdx.x;
  const int b0 = base[a], b1 = base[a + 1];
  const int ofs = part * 784;
  float acc[4] = {0.f, 0.f, 0.f, 0.f};
  for (int i = b0; i < b1; ++i) {
    int e = list[i];
    if (e < e0 || e >= e0 + ce) continue;
    const ushort_t* m = msg3 + (long long)(e - e0) * 6272 + ofs;
    #pragma unroll
    for (int u = 0; u < 4; ++u) {
      int idx = t + (u << 8);
      if (idx < 784) acc[u] += bf2f(m[idx]);
    }
  }
  float* o = xmsg + (long long)a * 6272 + ofs;
  #pragma unroll
  for (int u = 0; u < 4; ++u) {
    int idx = t + (u << 8);
    if (idx < 784) {
      if (accum) o[idx] += acc[u]; else o[idx] = acc[u];
    }
  }
}

// ---------------------------------------------------------------------------
// Host orchestration
// ---------------------------------------------------------------------------
extern "C" void kernel_launch(void* const* d_in, const int* in_sizes, int n_in,
                              void* d_out, int out_size, void* d_ws, size_t ws_size,
                              hipStream_t stream) {
  const float* x         = (const float*)d_in[0];
  const float* edist     = (const float*)d_in[1];
  const float* wigner    = (const float*)d_in[2];
  const float* wiginv    = (const float*)d_in[3];
  const float* to_grid   = (const float*)d_in[4];
  const float* from_grid = (const float*)d_in[5];
  const float* w_dist1   = (const float*)d_in[6];
  const float* b_dist1   = (const float*)d_in[7];
  const float* src_emb   = (const float*)d_in[8];
  const float* tgt_emb   = (const float*)d_in[9];
  const float* w_edge1   = (const float*)d_in[10];
  const float* b_edge1   = (const float*)d_in[11];
  const float* ws1       = (const float*)d_in[12];
  const float* bs1       = (const float*)d_in[13];
  const float* ws2       = (const float*)d_in[14];
  const float* bs2       = (const float*)d_in[15];
  const float* ws3       = (const float*)d_in[16];
  const float* bs3       = (const float*)d_in[17];
  const int*   anum      = (const int*)d_in[18];
  const int*   eidx      = (const int*)d_in[19];
  const float* sw[10]; const float* tw[10];
  for (int i = 0; i < 10; ++i) {
    sw[i] = (const float*)d_in[20 + i];
    tw[i] = (const float*)d_in[30 + i];
  }
  float* outp = (float*)d_out;

  // ---- workspace ----
  char* wsb = (char*)d_ws;
  size_t off = 0;
  auto alloc = [&](long long nbytes) {
    char* p = wsb + off; off += (size_t)((nbytes + 63) & ~63LL); return p;
  };
  ushort_t* x_edge  = (ushort_t*)alloc((8000LL + 128) * 128 * 2);
  ushort_t* b2ab    = (ushort_t*)alloc(5505024LL * 2);
  ushort_t* bgcw    = (ushort_t*)alloc(851968LL * 2);
  float*    bgcb    = (float*)alloc(6656 * 4);
  ushort_t* b20b    = (ushort_t*)alloc(458752LL * 2);
  ushort_t* s1m0b   = (ushort_t*)alloc(458752LL * 2);
  ushort_t* s1mb    = (ushort_t*)alloc(2752512LL * 2);
  ushort_t* wd1b    = (ushort_t*)alloc(65536 * 2);
  ushort_t* we1b    = (ushort_t*)alloc(16384 * 2);
  ushort_t* ws1b    = (ushort_t*)alloc(32768 * 2);
  ushort_t* ws2b    = (ushort_t*)alloc(16384 * 2);
  ushort_t* ws3b    = (ushort_t*)alloc(16384 * 2);
  ushort_t* tgb     = (ushort_t*)alloc(4802 * 2);
  ushort_t* fgb     = (ushort_t*)alloc(4802 * 2);
  float*    xmsg    = (float*)alloc(5017600LL * 4);
  ushort_t* xmsgb   = (ushort_t*)alloc((5017600LL + 16384) * 2);
  ushort_t* xb      = (ushort_t*)alloc((5017600LL + 16384) * 2);
  ushort_t* xbT     = (ushort_t*)alloc(6553600LL * 2);
  ushort_t* basis   = (ushort_t*)alloc((8000LL + 128) * 512 * 2);
  float*    x_dist  = (float*)alloc(1024000LL * 4);
  ushort_t* x_distb = (ushort_t*)alloc((8000LL + 128) * 128 * 2);
  int*      deg     = (int*)alloc(800 * 4);
  int*      sbase   = (int*)alloc(801 * 4);
  int*      elist   = (int*)alloc(8000 * 4);
  const size_t fixedB = off;
  char* arena = wsb + off;

  static const int ces[6] = {8000, 4000, 2000, 1000, 500, 250};
  static const int cas[6] = {800, 800, 800, 400, 200, 100};
  int ce = 250, ca = 100;
  for (int i = 0; i < 6; ++i) {
    long long ne = (long long)ces[i] * 76544 + 64LL * 50688;
    long long na = (long long)cas[i] * 87808 + 64LL * 512;
    long long need = (long long)fixedB + (ne > na ? ne : na);
    if (need <= (long long)ws_size) { ce = ces[i]; ca = cas[i]; break; }
  }

  // edge-phase arena (padded A-sources)
  char* ap = arena;
  ushort_t* xrot_s = (ushort_t*)ap;  ap += (long long)(ce + 64) * 12544;
  ushort_t* xrot_t = (ushort_t*)ap;  ap += (long long)(ce + 64) * 12544;
  ushort_t* tb0    = (ushort_t*)ap;  ap += (long long)(ce + 64) * 1024;
  ushort_t* tbm    = (ushort_t*)ap;  ap += (long long)(ce + 64) * 24576;
  ushort_t* msgp   = (ushort_t*)ap;  ap += (long long)ce * 12544;
  ushort_t* gate   = (ushort_t*)ap;
  ushort_t* msg3   = (ushort_t*)arena;   // overlays xrot after stage1
  // atom-phase arena
  char* bp = arena;
  ushort_t* hb = (ushort_t*)bp;  bp += (long long)ca * 49 * 256;
  ushort_t* g1 = (ushort_t*)bp;  bp += ((long long)ca * 98 + 64) * 256;
  ushort_t* g2 = (ushort_t*)bp;  bp += ((long long)ca * 98 + 64) * 256;
  ushort_t* g3 = (ushort_t*)bp;

  long long ofs2[7][2], s1ofs[7][2];
  { long long cur = 0, cur1 = 0;
    for (int m = 1; m <= 6; ++m) {
      int k = (7 - m) * 128;
      ofs2[m][0] = cur; cur += (long long)k * 1024;
      ofs2[m][1] = cur; cur += (long long)k * 1024;
      s1ofs[m][0] = cur1; cur1 += 512LL * k;
      s1ofs[m][1] = cur1; cur1 += 512LL * k;
    } }

  auto D0 = []() { GemmP p; memset(&p, 0, sizeof(p)); p.asplit = 1 << 30; return p; };
  auto finalize = [&](Grouped& G) {
    int base = 0;
    for (int i = 0; i < G.nd; ++i) {
      GemmP& p = G.d[i];
      p.ngx = (p.M + 127) >> 7;
      int ngy = (p.N + 127) >> 7;
      p.wg_base = base;
      base += p.ngx * ngy;
    }
    gemm_g<<<base, 256, 0, stream>>>(G);
  };
  auto run1 = [&](GemmP p) { Grouped G; G.d[0] = p; G.nd = 1; finalize(G); };
  auto rungrid = [&](const float* A, int M, int K, int permA,
                     const ushort_t* B, int b_ib, void* C, int c_ib,
                     const float* bias, int act, int c_bf16, int nb) {
    GridP p;
    p.A = A; p.B = B; p.C = C; p.bias = bias;
    p.b_ib = b_ib; p.c_ib = c_ib;
    p.M = M; p.K = K; p.permA = permA; p.act = act; p.c_bf16 = c_bf16;
    gridmm<<<nb, 256, 0, stream>>>(p);
  };
  auto cvt = [&](const float* s, ushort_t* d, int n) {
    k_cvt<<<(n + 255) / 256, 256, 0, stream>>>(s, d, n);
  };

  // 0) builds
  k_build_b2b<<<(5505024 + 255) / 256, 256, 0, stream>>>(sw[7], sw[9], tw[7], tw[9], b2ab);
  k_build_bgcat<<<(858624 + 255) / 256, 256, 0, stream>>>(
      sw[0], tw[0], sw[4], tw[4], sw[1], tw[1], sw[5], tw[5], bgcw, bgcb);
  k_build_b20b<<<(458752 + 255) / 256, 256, 0, stream>>>(sw[3], tw[3], b20b);
  k_build_s1m<<<(2752512 + 255) / 256, 256, 0, stream>>>(sw[6], sw[8], tw[6], tw[8], s1mb);
  cvt(sw[2], s1m0b, 229376);
  cvt(tw[2], s1m0b + 229376, 229376);
  cvt(w_dist1, wd1b, 65536);
  cvt(w_edge1, we1b, 16384);
  cvt(ws1, ws1b, 32768);
  cvt(ws2, ws2b, 16384);
  cvt(ws3, ws3b, 16384);
  cvt(from_grid, fgb, 4802);
  k_build_tg<<<(4802 + 255) / 256, 256, 0, stream>>>(to_grid, tgb);
  cvt(x, xb, 5017600);
  k_xT<<<AN, 256, 0, stream>>>(x, xbT);

  // scatter lists
  k_zeroi<<<4, 256, 0, stream>>>(deg, 800);
  k_deg<<<(EN + 255) / 256, 256, 0, stream>>>(eidx + EN, deg);
  k_prefix<<<1, 1024, 0, stream>>>(deg, sbase);
  k_fill<<<AN, 256, 0, stream>>>(eidx + EN, sbase, elist);

  // 1) edge features
  k_basis<<<(EN * 512 + 255) / 256, 256, 0, stream>>>(edist, basis);
  { GemmP p = D0();
    p.A = basis; p.a_se = 512; p.B = wd1b; p.ldb = 512; p.bias = b_dist1;
    p.C = x_dist; p.c_se = 128; p.M = EN; p.N = 128; p.K = 512;
    run1(p); }
  k_emb<<<(EN * 128 + 255) / 256, 256, 0, stream>>>(src_emb, tgt_emb, anum, eidx,
                                                    x_dist, x_distb);
  { GemmP p = D0();
    p.A = x_distb; p.a_se = 128; p.B = we1b; p.ldb = 128; p.bias = b_edge1;
    p.act = 1; p.C = x_edge; p.c_se = 128; p.c_bf16 = 1;
    p.M = EN; p.N = 128; p.K = 128;
    run1(p); }

  static const int offq[7] = {0, 7, 19, 29, 37, 43, 47};

  // 2) edge chunks
  for (int e0 = 0; e0 < EN; e0 += ce) {
    const int c = ce;
    k_rot2<<<c, 256, 0, stream>>>(wigner + (long long)e0 * 2401, xbT,
                                  eidx + e0, eidx + EN + e0, xrot_s, xrot_t);
    // gates
    { GemmP p = D0();
      p.A = x_edge + (long long)e0 * 128; p.a_se = 128;
      p.B = bgcw; p.ldb = 128; p.bias = bgcb; p.act = 1;
      p.C = gate; p.c_se = 6656; p.c_bf16 = 1;
      p.M = c; p.N = 6656; p.K = 128;
      run1(p); }
    // stage 1 grouped
    { Grouped G; G.nd = 14;
      for (int s = 0; s < 2; ++s) {
        GemmP p = D0();
        p.A = s ? xrot_t : xrot_s; p.a_se = 6272;
        p.B = s1m0b + (long long)s * 229376; p.ldb = 896;
        p.gate = gate; p.gate_ofs = s * 256;
        p.C = tb0; p.c_se = 512; p.c_ofs = s * 256; p.c_bf16 = 1;
        p.M = c; p.N = 256; p.K = 896;
        G.d[s] = p;
      }
      int di = 2;
      for (int m = 1; m <= 6; ++m) {
        const int k = (7 - m) * 128, off2 = offq[m];
        for (int s = 0; s < 2; ++s) {
          GemmP p = D0();
          p.A = (s ? xrot_t : xrot_s) + off2 * 128;
          p.a_se = 6272; p.a_si = k; p.pair = 1;
          p.B = s1mb + s1ofs[m][s]; p.ldb = k;
          p.gate = gate; p.gate_ofs = 512 + (m - 1) * 1024 + s * 512;
          p.C = tbm; p.c_se = 12288; p.c_si = 1024;
          p.c_ofs = (m - 1) * 2048 + s * 512;
          p.ihalf = 1; p.c_bf16 = 1;
          p.M = 2 * c; p.N = 512; p.K = k;
          G.d[di++] = p;
        }
      }
      finalize(G); }
    // stage 2 grouped
    { Grouped G; G.nd = 13;
      { GemmP p = D0();
        p.A = tb0; p.a_se = 512;
        p.B = b20b; p.ldb = 512;
        p.C = msgp; p.c_se = 6272; p.c_bf16 = 1;
        p.M = c; p.N = 896; p.K = 512;
        G.d[0] = p; }
      int di = 1;
      for (int m = 1; m <= 6; ++m) {
        const int n = 7 - m, k = n * 128, off2 = offq[m];
        for (int pp = 0; pp < 2; ++pp) {
          GemmP p = D0();
          p.A = tbm + (m - 1) * 2048 + pp * 1024; p.a_se = 12288;
          p.B = b2ab + ofs2[m][pp]; p.ldb = 1024;
          p.C = msgp; p.c_se = 6272; p.c_ofs = (off2 + (pp ? n : 0)) * 128; p.c_bf16 = 1;
          p.M = c; p.N = k; p.K = 1024;
          G.d[di++] = p;
        }
      }
      finalize(G); }
    // fused grid pipeline + gather
    k_grid<<<c, 256, 0, stream>>>(tgb, fgb, wiginv + (long long)e0 * 2401, msgp, msg3);
    k_gather<<<dim3(AN, 8), 256, 0, stream>>>(msg3, sbase, elist, xmsg, e0, c, e0 > 0);
  }

  // xmsg -> bf16 for atom GEMM
  cvt(xmsg, xmsgb, 5017600);

  // 3) atom phase
  for (int a0 = 0; a0 < AN; a0 += ca) {
    { GemmP p = D0();
      p.A = xb + (long long)a0 * 6272; p.A2 = xmsgb + (long long)a0 * 6272;
      p.a_se = 128; p.asplit = 128;
      p.B = ws1b; p.ldb = 256;
      p.C = hb; p.c_se = 128; p.c_bf16 = 1;
      p.M = ca * 49; p.N = 128; p.K = 256;
      run1(p); }
    rungrid(to_grid, 98, 49, 0, hb, 6272, g1, 12544, bs1, 1, 1, ca);
    { GemmP p = D0();
      p.A = g1; p.a_se = 128;
      p.B = ws2b; p.ldb = 128; p.bias = bs2; p.act = 1;
      p.C = g2; p.c_se = 128; p.c_bf16 = 1;
      p.M = ca * 98; p.N = 128; p.K = 128;
      run1(p); }
    { GemmP p = D0();
      p.A = g2; p.a_se = 128;
      p.B = ws3b; p.ldb = 128; p.bias = bs3;
      p.C = g3; p.c_se = 128; p.c_bf16 = 1;
      p.M = ca * 98; p.N = 128; p.K = 128;
      run1(p); }
    rungrid(from_grid, 49, 98, 0, g3, 12544, outp + (long long)a0 * 6272, 6272,
            nullptr, 0, 0, ca);
  }
}

// Round 8
// 1636.347 us; speedup vs baseline: 13.2286x; 1.0755x over previous
//
#include <hip/hip_runtime.h>
#include <string.h>

#define EN 8000
#define AN 800

typedef __attribute__((ext_vector_type(8))) short bf16x8;
typedef __attribute__((ext_vector_type(4))) float f32x4;
typedef unsigned short ushort_t;
typedef unsigned int uint32;

__constant__ int c_perm[49] = {
  0,2,6,12,20,30,42,
  1,5,11,19,29,41,
  3,7,13,21,31,43,
  4,10,18,28,40,
  8,14,22,32,44,
  9,17,27,39,
  15,23,33,45,
  16,26,38,
  24,34,46,
  25,37,
  35,47,
  36,
  48
};

__device__ __forceinline__ float siluf(float x) { return x / (1.0f + __expf(-x)); }
__device__ __forceinline__ ushort_t f2bf(float f) {
  uint32 u = __float_as_uint(f);
  u += 0x7fff + ((u >> 16) & 1);
  return (ushort_t)(u >> 16);
}
__device__ __forceinline__ float bf2f(ushort_t h) {
  return __uint_as_float(((uint32)h) << 16);
}
__device__ __forceinline__ void gld16(const void* g, void* l) {
  __builtin_amdgcn_global_load_lds(
      (const __attribute__((address_space(1))) void*)g,
      (__attribute__((address_space(3))) void*)l, 16, 0, 0);
}

// ---------------------------------------------------------------------------
// Weight builders (bf16 outputs)
// ---------------------------------------------------------------------------
__global__ __launch_bounds__(256) void k_build_b2b(
    const float* __restrict__ sw2r, const float* __restrict__ sw2i,
    const float* __restrict__ tw2r, const float* __restrict__ tw2i,
    ushort_t* __restrict__ dst)
{
  long long id = (long long)blockIdx.x * 256 + threadIdx.x;
  if (id >= 5505024LL) return;
  long long base = 0; int m = 1, k = 768;
  for (; m <= 6; ++m) {
    k = (7 - m) * 128;
    long long sz = 2LL * k * 1024;
    if (id < base + sz) break;
    base += sz;
  }
  long long rem = id - base;
  int p = (int)(rem / ((long long)k * 1024));
  int cj = (int)(rem - (long long)p * k * 1024);
  int c = cj >> 10, j = cj & 1023;
  int q = j >> 8, jj = j & 255;
  const float sgn = (q & 1) ? (p ? 1.f : -1.f) : 1.f;
  const float* src = (q < 2) ? (q == 0 ? sw2r : sw2i) : (q == 2 ? tw2r : tw2i);
  dst[id] = f2bf(sgn * src[(long long)(m - 1) * 196608 + c * 256 + jj]);
}

__global__ __launch_bounds__(256) void k_build_bgcat(
    const float* __restrict__ sw0, const float* __restrict__ tw0,
    const float* __restrict__ sw4, const float* __restrict__ tw4,
    const float* __restrict__ sb0, const float* __restrict__ tb0b,
    const float* __restrict__ sbd, const float* __restrict__ tbd,
    ushort_t* __restrict__ w, float* __restrict__ b)
{
  int id = blockIdx.x * 256 + threadIdx.x;
  if (id < 851968) {
    int r = id >> 7, c = id & 127;
    float v;
    if (r < 256) v = sw0[r * 128 + c];
    else if (r < 512) v = tw0[(r - 256) * 128 + c];
    else {
      int rr = r - 512, m = rr >> 10, q = rr & 1023;
      v = (q < 512) ? sw4[m * 65536 + q * 128 + c] : tw4[m * 65536 + (q - 512) * 128 + c];
    }
    w[id] = f2bf(v);
    return;
  }
  id -= 851968;
  if (id < 6656) {
    float v;
    if (id < 256) v = sb0[id];
    else if (id < 512) v = tb0b[id - 256];
    else {
      int rr = id - 512, m = rr >> 10, q = rr & 1023;
      v = (q < 512) ? sbd[m * 512 + q] : tbd[m * 512 + (q - 512)];
    }
    b[id] = v;
  }
}

__global__ __launch_bounds__(256) void k_build_b20b(
    const float* __restrict__ sw3, const float* __restrict__ tw3,
    ushort_t* __restrict__ b20)
{
  int id = blockIdx.x * 256 + threadIdx.x;
  if (id >= 458752) return;
  int cc = id >> 9, j = id & 511;
  b20[id] = f2bf((j < 256) ? sw3[cc * 256 + j] : tw3[cc * 256 + (j - 256)]);
}

__global__ __launch_bounds__(256) void k_build_s1m(
    const float* __restrict__ sw6, const float* __restrict__ sw8,
    const float* __restrict__ tw6, const float* __restrict__ tw8,
    ushort_t* __restrict__ dst)
{
  long long id = (long long)blockIdx.x * 256 + threadIdx.x;
  if (id >= 2752512LL) return;
  long long base = 0; int m = 1, k = 768;
  for (; m <= 6; ++m) {
    k = (7 - m) * 128;
    long long sz = 1024LL * k;
    if (id < base + sz) break;
    base += sz;
  }
  long long rem = id - base;
  int s = (int)(rem / (512LL * k));
  int rr = (int)(rem - (long long)s * 512 * k);
  int r = rr / k, c = rr - r * k;
  const float* src = (r < 256) ? (s ? tw6 : sw6) : (s ? tw8 : sw8);
  int r0 = (r < 256) ? r : r - 256;
  dst[id] = f2bf(src[(long long)(m - 1) * 196608 + r0 * 768 + c]);
}

__global__ __launch_bounds__(256) void k_cvt(
    const float* __restrict__ src, ushort_t* __restrict__ dst, int n)
{
  int id = blockIdx.x * 256 + threadIdx.x;
  if (id < n) dst[id] = f2bf(src[id]);
}

__global__ __launch_bounds__(256) void k_build_tg(
    const float* __restrict__ tg, ushort_t* __restrict__ dst)
{
  int id = blockIdx.x * 256 + threadIdx.x;
  if (id >= 98 * 49) return;
  int r = id / 49, s = id - r * 49;
  dst[id] = f2bf(tg[r * 49 + c_perm[s]]);
}

// transpose x (f32 [49][128]) -> xbT (bf16 [128][64], j-padded)
__global__ __launch_bounds__(256) void k_xT(
    const float* __restrict__ x, ushort_t* __restrict__ xbT)
{
  __shared__ __align__(16) float xs[49 * 128];
  const int a = blockIdx.x, t = threadIdx.x;
  const float4* src = (const float4*)(x + (long long)a * 6272);
  float4* d = (float4*)xs;
  for (int i = t; i < 1568; i += 256) d[i] = src[i];
  __syncthreads();
  ushort_t* o = xbT + (long long)a * 8192;
  int c = t >> 1;
  int jg = (t & 1) << 2;
  #pragma unroll
  for (int u = 0; u < 4; ++u) {
    int g = jg + u;
    bf16x8 v = (bf16x8)0;
    #pragma unroll
    for (int j = 0; j < 8; ++j) {
      int jj = (g << 3) + j;
      if (jj < 49) v[j] = (short)f2bf(xs[jj * 128 + c]);
    }
    *(bf16x8*)&o[(c << 6) + (g << 3)] = v;
  }
}

// ---------------------------------------------------------------------------
// Edge features
// ---------------------------------------------------------------------------
__global__ __launch_bounds__(256) void k_basis(
    const float* __restrict__ dist, ushort_t* __restrict__ basis)
{
  int id = blockIdx.x * 256 + threadIdx.x;
  if (id >= EN * 512) return;
  int e = id >> 9, g = id & 511;
  const float step = 8.0f / 511.0f;
  const float coeff = -2040.0078125f;
  float df = dist[e] - (float)g * step;
  basis[id] = f2bf(expf(coeff * df * df));
}

__global__ __launch_bounds__(256) void k_emb(
    const float* __restrict__ src_emb, const float* __restrict__ tgt_emb,
    const int* __restrict__ anum, const int* __restrict__ eidx,
    const float* __restrict__ xd, ushort_t* __restrict__ out)
{
  int id = blockIdx.x * 256 + threadIdx.x;
  if (id >= EN * 128) return;
  int e = id >> 7, c = id & 127;
  int a0 = anum[eidx[e]], a1 = anum[eidx[EN + e]];
  out[id] = f2bf(siluf(src_emb[a0 * 128 + c] + tgt_emb[a1 * 128 + c] + xd[id]));
}

// ---------------------------------------------------------------------------
// MFMA Wigner rotation with coalesced (repacked) output
// ---------------------------------------------------------------------------
__global__ __launch_bounds__(256) void k_rot2(
    const float* __restrict__ wig, const ushort_t* __restrict__ xbT,
    const int* __restrict__ srcl, const int* __restrict__ tgtl,
    ushort_t* __restrict__ osrc, ushort_t* __restrict__ otgt)
{
  __shared__ short Ws[4096];   // [64][64] bf16, 8-slot swz
  __shared__ short Xs[8192];   // in: [128][64]; out-stage: [49][128] swz
  __shared__ short Xt[8192];
  const int e = blockIdx.x, tid = threadIdx.x;
  const int lane = tid & 63, wave = tid >> 6;
  const float* wge = wig + (long long)e * 2401;
  #pragma unroll
  for (int t = 0; t < 2; ++t) {
    int ci = (t << 8) + tid;
    int row = ci >> 3, g = ci & 7;
    bf16x8 v = (bf16x8)0;
    if (row < 49) {
      const float* wr = wge + c_perm[row] * 49;
      #pragma unroll
      for (int j = 0; j < 8; ++j) {
        int col = (g << 3) + j;
        if (col < 49) v[j] = (short)f2bf(wr[col]);
      }
    }
    *(bf16x8*)&Ws[(row << 6) + ((g ^ (row & 7)) << 3)] = v;
  }
  const int as = srcl[e], at = tgtl[e];
  const ushort_t* xsg = xbT + (long long)as * 8192;
  const ushort_t* xtg = xbT + (long long)at * 8192;
  #pragma unroll
  for (int t = 0; t < 4; ++t) {
    int ci = (t << 8) + tid;
    int row = ci >> 3, g = ci & 7;
    int ofs = (row << 6) + ((g ^ (row & 7)) << 3);
    *(bf16x8*)&Xs[ofs] = *(const bf16x8*)&xsg[ci << 3];
    *(bf16x8*)&Xt[ofs] = *(const bf16x8*)&xtg[ci << 3];
  }
  __syncthreads();
  const short* Xb = (wave >> 1) ? Xt : Xs;
  const int ch = (wave & 1) << 6;
  const int fr = lane & 15, g = lane >> 4;
  f32x4 acc[4][4];
  #pragma unroll
  for (int i = 0; i < 4; ++i)
    #pragma unroll
    for (int j = 0; j < 4; ++j) acc[i][j] = (f32x4){0.f, 0.f, 0.f, 0.f};
  #pragma unroll
  for (int ks = 0; ks < 2; ++ks) {
    bf16x8 af[4], bfv[4];
    int lc = (ks << 2) + g;
    #pragma unroll
    for (int i = 0; i < 4; ++i) {
      int ra = (i << 4) + fr;
      af[i] = *(const bf16x8*)&Ws[(ra << 6) + ((lc ^ (ra & 7)) << 3)];
      int rb = ch + (i << 4) + fr;
      bfv[i] = *(const bf16x8*)&Xb[(rb << 6) + ((lc ^ (rb & 7)) << 3)];
    }
    #pragma unroll
    for (int i = 0; i < 4; ++i)
      #pragma unroll
      for (int j = 0; j < 4; ++j)
        acc[i][j] = __builtin_amdgcn_mfma_f32_16x16x32_bf16(af[i], bfv[j], acc[i][j], 0, 0, 0);
  }
  const int crl = (lane >> 4) << 2, ccl = lane & 15;
  __syncthreads();   // everyone done reading Xs/Xt
  short* Ob = (wave >> 1) ? Xt : Xs;
  #pragma unroll
  for (int i = 0; i < 4; ++i)
    #pragma unroll
    for (int r = 0; r < 4; ++r) {
      int q = (i << 4) + crl + r;
      if (q < 49) {
        #pragma unroll
        for (int j = 0; j < 4; ++j) {
          int col = ch + (j << 4) + ccl;
          Ob[(q << 7) + (((col >> 3) ^ (q & 15)) << 3) + (col & 7)] =
              (short)f2bf(acc[i][j][r]);
        }
      }
    }
  __syncthreads();
  for (int gid = tid; gid < 1568; gid += 256) {
    int half = gid >= 784;
    int c784 = half ? gid - 784 : gid;
    int row = c784 >> 4, cc = c784 & 15;
    const short* Sb = half ? Xt : Xs;
    bf16x8 v = *(const bf16x8*)&Sb[(row << 7) + ((cc ^ (row & 15)) << 3)];
    ushort_t* dst = (half ? otgt : osrc) + (long long)e * 6272 + (row << 7) + (cc << 3);
    *(bf16x8*)dst = v;
  }
}

// ---------------------------------------------------------------------------
// Grouped MFMA GEMM, bf16, global_load_lds + swizzle, dbuf + counted vmcnt,
// XCD-swizzled blockIdx, LDS-repacked coalesced epilogue (16B C-stores,
// 16B gate loads).
// ---------------------------------------------------------------------------
struct GemmP {
  const ushort_t* A; const ushort_t* A2; const ushort_t* B;
  const float* bias; const ushort_t* gate; void* C;
  int a_se, a_si, pair, asplit;
  int ldb;
  int gate_ofs;
  int c_se, c_si, c_ofs;
  int ihalf, act, c_bf16;
  int M, N, K;
  int ngx, wg_base;
};
struct Grouped { GemmP d[14]; int nd; int nwg; };

__global__ __launch_bounds__(256) void gemm_g(Grouped G) {
  __shared__ short SH[16384];       // staging (2x dbuf A|B) and epilogue repack
  short* As = SH;
  short* Bs = SH + 8192;
  int bid;
  { // bijective XCD chunk swizzle (m204)
    int n = G.nwg, orig = blockIdx.x;
    int q = n >> 3, r = n & 7;
    int xcd = orig & 7, pos = orig >> 3;
    bid = (xcd < r ? xcd * (q + 1) : r * (q + 1) + (xcd - r) * q) + pos;
  }
  int di = G.nd - 1;
  for (int i = 1; i < G.nd; ++i) if (bid < G.d[i].wg_base) { di = i - 1; break; }
  const GemmP p = G.d[di];
  const int local = bid - p.wg_base;
  const int bx = local % p.ngx, by = local / p.ngx;
  const int m0 = bx << 7, n0 = by << 7;

  const int tid = threadIdx.x;
  const int lane = tid & 63, wave = tid >> 6;
  const int gl = ((lane & 3) ^ ((lane >> 3) & 3)) << 3;
  const int grow = (wave << 4) + (lane >> 2);
  const int fr = lane & 15, fkg = lane >> 4;
  const int sxor = (fr >> 1) & 3;
  const int wm = (wave >> 1) << 6, wn = (wave & 1) << 6;

  f32x4 acc[4][4];
  #pragma unroll
  for (int i = 0; i < 4; ++i)
    #pragma unroll
    for (int j = 0; j < 4; ++j) acc[i][j] = (f32x4){0.f, 0.f, 0.f, 0.f};

  long long abase;
  {
    int r0 = m0 + grow;
    abase = p.pair
        ? (long long)(r0 >> 1) * p.a_se + (long long)(r0 & 1) * p.a_si
        : (long long)r0 * p.a_se;
  }
  long long abase2;
  {
    int r1 = m0 + 64 + grow;
    abase2 = p.pair
        ? (long long)(r1 >> 1) * p.a_se + (long long)(r1 & 1) * p.a_si
        : (long long)r1 * p.a_se;
  }
  const long long bbase  = (long long)(n0 + grow) * p.ldb;
  const long long bbase2 = (long long)(n0 + 64 + grow) * p.ldb;

  const int nt = p.K >> 5;

  auto STAGE = [&](int buf, int k0) {
    const ushort_t* Ap = p.A;
    int kk = k0;
    if (p.A2 && k0 >= p.asplit) { Ap = p.A2; kk = k0 - p.asplit; }
    const int lofs = (buf << 12) + (wave << 9);
    gld16(Ap + abase + kk + gl,   &As[lofs]);
    gld16(p.B + bbase + k0 + gl,  &Bs[lofs]);
    gld16(Ap + abase2 + kk + gl,  &As[lofs + 2048]);
    gld16(p.B + bbase2 + k0 + gl, &Bs[lofs + 2048]);
  };

  STAGE(0, 0);
  int cur = 0;
  for (int t = 0; t < nt; ++t) {
    if (t + 1 < nt) {
      STAGE(cur ^ 1, (t + 1) << 5);
      asm volatile("s_waitcnt vmcnt(4)" ::: "memory");
    } else {
      asm volatile("s_waitcnt vmcnt(0)" ::: "memory");
    }
    __builtin_amdgcn_sched_barrier(0);
    __builtin_amdgcn_s_barrier();
    {
      const int bofs = cur << 12;
      bf16x8 af[4], bfv[4];
      #pragma unroll
      for (int i = 0; i < 4; ++i) {
        int ra = wm + (i << 4) + fr;
        int rb = wn + (i << 4) + fr;
        af[i]  = *(const bf16x8*)&As[bofs + (ra << 5) + ((fkg ^ sxor) << 3)];
        bfv[i] = *(const bf16x8*)&Bs[bofs + (rb << 5) + ((fkg ^ sxor) << 3)];
      }
      #pragma unroll
      for (int i = 0; i < 4; ++i)
        #pragma unroll
        for (int j = 0; j < 4; ++j)
          acc[i][j] = __builtin_amdgcn_mfma_f32_16x16x32_bf16(af[i], bfv[j], acc[i][j], 0, 0, 0);
    }
    __builtin_amdgcn_s_barrier();
    cur ^= 1;
  }

  const int crl = (lane >> 4) << 2, ccl = lane & 15;
  if (p.c_bf16) {
    // 1) acc (+bias/act) -> SH[128][128] bf16 with chunk^row swizzle
    #pragma unroll
    for (int mi = 0; mi < 4; ++mi)
      #pragma unroll
      for (int r = 0; r < 4; ++r) {
        int lrow = wm + mi * 16 + crl + r;
        #pragma unroll
        for (int ni = 0; ni < 4; ++ni) {
          int lcol = wn + ni * 16 + ccl;
          float v = acc[mi][ni][r];
          int gc = n0 + lcol;
          if (p.bias) v += p.bias[gc];
          if (p.act)  v = siluf(v);
          SH[(lrow << 7) + (((lcol >> 3) ^ (lrow & 15)) << 3) + (lcol & 7)] =
              (short)f2bf(v);
        }
      }
    __syncthreads();
    // 2) coalesced output: 1 row, 64 cols per thread (8 x 16B)
    const int lr = tid >> 1, chalf = (tid & 1) << 6;
    int gr = m0 + lr;
    if (gr < p.M) {
      long long e; int ii;
      if (p.pair) { e = gr >> 1; ii = gr & 1; } else { e = gr; ii = 0; }
      const ushort_t* grw = p.gate ? p.gate + e * 6656 + p.gate_ofs : nullptr;
      #pragma unroll
      for (int j = 0; j < 8; ++j) {
        int lcol = chalf + (j << 3);
        bf16x8 v = *(const bf16x8*)&SH[(lr << 7) + (((lcol >> 3) ^ (lr & 15)) << 3)];
        int gc = n0 + lcol;
        if (grw) {
          bf16x8 g8 = *(const bf16x8*)&grw[gc];
          #pragma unroll
          for (int q2 = 0; q2 < 8; ++q2)
            v[q2] = (short)f2bf(bf2f((ushort_t)v[q2]) * bf2f((ushort_t)g8[q2]));
        }
        int par = (p.ihalf && gc >= 256) ? (1 - ii) : ii;
        long long co = e * (long long)p.c_se + (long long)par * p.c_si + p.c_ofs + gc;
        *(bf16x8*)&((ushort_t*)p.C)[co] = v;
      }
    }
  } else {
    // f32-C scalar path (x_dist only)
    #pragma unroll
    for (int mi = 0; mi < 4; ++mi) {
      #pragma unroll
      for (int r = 0; r < 4; ++r) {
        int gr = m0 + wm + mi * 16 + crl + r;
        if (gr >= p.M) continue;
        long long e = gr;
        float* crow = (float*)p.C + e * (long long)p.c_se + p.c_ofs;
        #pragma unroll
        for (int ni = 0; ni < 4; ++ni) {
          int gc = n0 + wn + ni * 16 + ccl;
          if (gc >= p.N) continue;
          float v = acc[mi][ni][r];
          if (p.bias) v += p.bias[gc];
          if (p.act)  v = siluf(v);
          crow[gc] = v;
        }
      }
    }
  }
}

// ---------------------------------------------------------------------------
// gridmm (atom phase)
// ---------------------------------------------------------------------------
struct GridP {
  const float* A; const ushort_t* B; void* C; const float* bias;
  int b_ib, c_ib;
  int M, K, permA, act, c_bf16;
};

#define LDW 40

__global__ __launch_bounds__(256) void gridmm(GridP p) {
  __shared__ short As[128 * LDW];
  __shared__ short Bs[128 * LDW];
  const int e = blockIdx.x;
  const int tid = threadIdx.x;
  const int srow = tid >> 1, sk = (tid & 1) << 4;
  const int lane = tid & 63, wave = tid >> 6;
  const int wm = (wave >> 1) << 6, wn = (wave & 1) << 6;
  const int fr = lane & 15, fk = (lane >> 4) << 3;

  f32x4 acc[4][4];
  #pragma unroll
  for (int i = 0; i < 4; ++i)
    #pragma unroll
    for (int j = 0; j < 4; ++j) acc[i][j] = (f32x4){0.f, 0.f, 0.f, 0.f};

  const ushort_t* bp0 = p.B + (long long)e * p.b_ib;

  for (int k0 = 0; k0 < p.K; k0 += 32) {
    {
      bf16x8 lo = (bf16x8)0, hi = (bf16x8)0;
      if (srow < p.M) {
        const float* ar = p.A + srow * p.K;
        #pragma unroll
        for (int j = 0; j < 8; ++j) {
          int col = k0 + sk + j;
          float v = 0.f;
          if (col < p.K) v = ar[p.permA ? c_perm[col] : col];
          lo[j] = (short)f2bf(v);
        }
        #pragma unroll
        for (int j = 0; j < 8; ++j) {
          int col = k0 + sk + 8 + j;
          float v = 0.f;
          if (col < p.K) v = ar[p.permA ? c_perm[col] : col];
          hi[j] = (short)f2bf(v);
        }
      }
      *(bf16x8*)&As[srow * LDW + sk] = lo;
      *(bf16x8*)&As[srow * LDW + sk + 8] = hi;
    }
    {
      const int c = tid & 127, kq = tid >> 7;
      #pragma unroll
      for (int i = 0; i < 8; ++i) {
        int kk = kq * 16 + i * 2;
        int k1 = k0 + kk, k2 = k1 + 1;
        uint32 v0 = (k1 < p.K) ? (uint32)bp0[(long long)k1 * 128 + c] : 0u;
        uint32 v1 = (k2 < p.K) ? (uint32)bp0[(long long)k2 * 128 + c] : 0u;
        *(uint32*)&Bs[c * LDW + kk] = v0 | (v1 << 16);
      }
    }
    __syncthreads();
    bf16x8 af[4], bfv[4];
    #pragma unroll
    for (int i = 0; i < 4; ++i) {
      af[i]  = *(const bf16x8*)(&As[(wm + i * 16 + fr) * LDW + fk]);
      bfv[i] = *(const bf16x8*)(&Bs[(wn + i * 16 + fr) * LDW + fk]);
    }
    #pragma unroll
    for (int i = 0; i < 4; ++i)
      #pragma unroll
      for (int j = 0; j < 4; ++j)
        acc[i][j] = __builtin_amdgcn_mfma_f32_16x16x32_bf16(af[i], bfv[j], acc[i][j], 0, 0, 0);
    __syncthreads();
  }

  const int crl = (lane >> 4) << 2, ccl = lane & 15;
  #pragma unroll
  for (int mi = 0; mi < 4; ++mi) {
    #pragma unroll
    for (int r = 0; r < 4; ++r) {
      int gr = wm + mi * 16 + crl + r;
      if (gr >= p.M) continue;
      #pragma unroll
      for (int ni = 0; ni < 4; ++ni) {
        int c = wn + ni * 16 + ccl;
        float v = acc[mi][ni][r];
        if (p.bias) v += p.bias[c];
        if (p.act)  v = siluf(v);
        long long co = (long long)e * p.c_ib + gr * 128 + c;
        if (p.c_bf16) ((ushort_t*)p.C)[co] = f2bf(v);
        else          ((float*)p.C)[co] = v;
      }
    }
  }
}

// ---------------------------------------------------------------------------
// Fused grid pipeline per edge: msg3 = WI @ (FG @ silu(TGp @ msgp))
// ---------------------------------------------------------------------------
#define SWZ8(cg, r) (((cg) ^ ((r) & 7)) & 7)
#define SWZ16(cg, r) (((cg) & 8) | (((cg) ^ (r)) & 7))

__global__ __launch_bounds__(256, 2) void k_grid(
    const ushort_t* __restrict__ tgb, const ushort_t* __restrict__ fgb,
    const float* __restrict__ wigv, const ushort_t* __restrict__ msgp,
    ushort_t* __restrict__ msg3)
{
  __shared__ short Abuf[8192];
  __shared__ short Bsh[8192];
  __shared__ short Ps[16384];
  const int e = blockIdx.x, tid = threadIdx.x;
  const int lane = tid & 63, wv = tid >> 6;
  const int fr = lane & 15, fk = (lane >> 4) << 3;
  const int crl = (lane >> 4) << 2, ccl = lane & 15;
  const ushort_t* me = msgp + (long long)e * 6272;

  for (int gid = tid; gid < 896; gid += 256) {
    int r = gid >> 3, cg = gid & 7;
    bf16x8 v = (bf16x8)0;
    if (r < 98) {
      #pragma unroll
      for (int j = 0; j < 8; ++j) {
        int col = (cg << 3) + j;
        if (col < 49) v[j] = (short)tgb[r * 49 + col];
      }
    }
    *(bf16x8*)&Abuf[(r << 6) + (SWZ8(cg, r) << 3)] = v;
  }
  for (int gid = tid; gid < 1024; gid += 256) {
    int kg = gid >> 7, c = gid & 127;
    bf16x8 v = (bf16x8)0;
    #pragma unroll
    for (int j = 0; j < 8; ++j) {
      int k = (kg << 3) + j;
      if (k < 49) v[j] = (short)me[k * 128 + c];
    }
    *(bf16x8*)&Bsh[(c << 6) + (SWZ8(kg, c) << 3)] = v;
  }
  {
    int c = tid >> 1, gg = 14 + (tid & 1);
    *(bf16x8*)&Ps[(c << 7) + (SWZ16(gg, c) << 3)] = (bf16x8)0;
  }
  __syncthreads();

  {
    f32x4 acc[7][2];
    #pragma unroll
    for (int i = 0; i < 7; ++i) { acc[i][0] = (f32x4){0,0,0,0}; acc[i][1] = (f32x4){0,0,0,0}; }
    #pragma unroll
    for (int k0 = 0; k0 < 64; k0 += 32) {
      int cg = (k0 + fk) >> 3;
      int br0 = ((2 * wv) << 4) + fr, br1 = ((2 * wv + 1) << 4) + fr;
      bf16x8 bf0 = *(const bf16x8*)&Bsh[(br0 << 6) + (SWZ8(cg, br0) << 3)];
      bf16x8 bf1 = *(const bf16x8*)&Bsh[(br1 << 6) + (SWZ8(cg, br1) << 3)];
      #pragma unroll
      for (int rt = 0; rt < 7; ++rt) {
        int ar = (rt << 4) + fr;
        bf16x8 af = *(const bf16x8*)&Abuf[(ar << 6) + (SWZ8(cg, ar) << 3)];
        acc[rt][0] = __builtin_amdgcn_mfma_f32_16x16x32_bf16(af, bf0, acc[rt][0], 0, 0, 0);
        acc[rt][1] = __builtin_amdgcn_mfma_f32_16x16x32_bf16(af, bf1, acc[rt][1], 0, 0, 0);
      }
    }
    #pragma unroll
    for (int rt = 0; rt < 7; ++rt)
      #pragma unroll
      for (int cj = 0; cj < 2; ++cj) {
        int c = ((2 * wv + cj) << 4) + ccl;
        #pragma unroll
        for (int r = 0; r < 4; ++r) {
          int g = (rt << 4) + crl + r;
          Ps[(c << 7) + (SWZ16(g >> 3, c) << 3) + (g & 7)] =
              (short)f2bf(siluf(acc[rt][cj][r]));
        }
      }
  }
  __syncthreads();
  for (int gid = tid; gid < 1024; gid += 256) {
    int r = gid >> 4, cg = gid & 15;
    bf16x8 v = (bf16x8)0;
    if (r < 49) {
      #pragma unroll
      for (int j = 0; j < 8; ++j) {
        int col = (cg << 3) + j;
        if (col < 98) v[j] = (short)fgb[r * 98 + col];
      }
    }
    *(bf16x8*)&Abuf[(r << 7) + (SWZ16(cg, r) << 3)] = v;
  }
  __syncthreads();

  {
    f32x4 acc[4][2];
    #pragma unroll
    for (int i = 0; i < 4; ++i) { acc[i][0] = (f32x4){0,0,0,0}; acc[i][1] = (f32x4){0,0,0,0}; }
    #pragma unroll
    for (int k0 = 0; k0 < 128; k0 += 32) {
      int cg = (k0 + fk) >> 3;
      int br0 = ((2 * wv) << 4) + fr, br1 = ((2 * wv + 1) << 4) + fr;
      bf16x8 bf0 = *(const bf16x8*)&Ps[(br0 << 7) + (SWZ16(cg, br0) << 3)];
      bf16x8 bf1 = *(const bf16x8*)&Ps[(br1 << 7) + (SWZ16(cg, br1) << 3)];
      #pragma unroll
      for (int rt = 0; rt < 4; ++rt) {
        int ar = (rt << 4) + fr;
        bf16x8 af = *(const bf16x8*)&Abuf[(ar << 7) + (SWZ16(cg, ar) << 3)];
        acc[rt][0] = __builtin_amdgcn_mfma_f32_16x16x32_bf16(af, bf0, acc[rt][0], 0, 0, 0);
        acc[rt][1] = __builtin_amdgcn_mfma_f32_16x16x32_bf16(af, bf1, acc[rt][1], 0, 0, 0);
      }
    }
    #pragma unroll
    for (int rt = 0; rt < 4; ++rt)
      #pragma unroll
      for (int cj = 0; cj < 2; ++cj) {
        int c = ((2 * wv + cj) << 4) + ccl;
        #pragma unroll
        for (int r = 0; r < 4; ++r) {
          int q = (rt << 4) + crl + r;
          Bsh[(c << 6) + (SWZ8(q >> 3, c) << 3) + (q & 7)] = (short)f2bf(acc[rt][cj][r]);
        }
      }
  }
  __syncthreads();
  {
    const float* we = wigv + (long long)e * 2401;
    for (int gid = tid; gid < 512; gid += 256) {
      int r = gid >> 3, cg = gid & 7;
      bf16x8 v = (bf16x8)0;
      if (r < 49) {
        #pragma unroll
        for (int j = 0; j < 8; ++j) {
          int col = (cg << 3) + j;
          if (col < 49) v[j] = (short)f2bf(we[r * 49 + col]);
        }
      }
      *(bf16x8*)&Abuf[(r << 6) + (SWZ8(cg, r) << 3)] = v;
    }
  }
  __syncthreads();

  {
    f32x4 acc[4][2];
    #pragma unroll
    for (int i = 0; i < 4; ++i) { acc[i][0] = (f32x4){0,0,0,0}; acc[i][1] = (f32x4){0,0,0,0}; }
    #pragma unroll
    for (int k0 = 0; k0 < 64; k0 += 32) {
      int cg = (k0 + fk) >> 3;
      int br0 = ((2 * wv) << 4) + fr, br1 = ((2 * wv + 1) << 4) + fr;
      bf16x8 bf0 = *(const bf16x8*)&Bsh[(br0 << 6) + (SWZ8(cg, br0) << 3)];
      bf16x8 bf1 = *(const bf16x8*)&Bsh[(br1 << 6) + (SWZ8(cg, br1) << 3)];
      #pragma unroll
      for (int rt = 0; rt < 4; ++rt) {
        int ar = (rt << 4) + fr;
        bf16x8 af = *(const bf16x8*)&Abuf[(ar << 6) + (SWZ8(cg, ar) << 3)];
        acc[rt][0] = __builtin_amdgcn_mfma_f32_16x16x32_bf16(af, bf0, acc[rt][0], 0, 0, 0);
        acc[rt][1] = __builtin_amdgcn_mfma_f32_16x16x32_bf16(af, bf1, acc[rt][1], 0, 0, 0);
      }
    }
    // repack -> coalesced 16B stores
    #pragma unroll
    for (int rt = 0; rt < 4; ++rt)
      #pragma unroll
      for (int r = 0; r < 4; ++r) {
        int gi = (rt << 4) + crl + r;
        if (gi < 49) {
          #pragma unroll
          for (int cj = 0; cj < 2; ++cj) {
            int c = ((2 * wv + cj) << 4) + ccl;
            Ps[(gi << 7) + (((c >> 3) ^ (gi & 15)) << 3) + (c & 7)] =
                (short)f2bf(acc[rt][cj][r]);
          }
        }
      }
    __syncthreads();
    ushort_t* oe = msg3 + (long long)e * 6272;
    for (int gid = tid; gid < 784; gid += 256) {
      int row = gid >> 4, cc = gid & 15;
      bf16x8 v = *(const bf16x8*)&Ps[(row << 7) + ((cc ^ (row & 15)) << 3)];
      *(bf16x8*)&oe[(row << 7) + (cc << 3)] = v;
    }
  }
}

// ---------------------------------------------------------------------------
// Segment-sum via per-atom edge lists (vectorized bf16x8 gather)
// ---------------------------------------------------------------------------
__global__ __launch_bounds__(256) void k_zeroi(int* __restrict__ p, int n) {
  int id = blockIdx.x * 256 + threadIdx.x;
  if (id < n) p[id] = 0;
}

__global__ __launch_bounds__(256) void k_deg(
    const int* __restrict__ tgt, int* __restrict__ deg) {
  int e = blockIdx.x * 256 + threadIdx.x;
  if (e < EN) atomicAdd(&deg[tgt[e]], 1);
}

__global__ __launch_bounds__(1024) void k_prefix(
    const int* __restrict__ deg, int* __restrict__ base) {
  __shared__ int s[1024];
  int t = threadIdx.x;
  s[t] = (t < AN) ? deg[t] : 0;
  __syncthreads();
  for (int ofs = 1; ofs < 1024; ofs <<= 1) {
    int u = (t >= ofs) ? s[t - ofs] : 0;
    __syncthreads();
    s[t] += u;
    __syncthreads();
  }
  if (t < AN) base[t + 1] = s[t];
  if (t == 0) base[0] = 0;
}

__global__ __launch_bounds__(256) void k_fill(
    const int* __restrict__ tgt, const int* __restrict__ base,
    int* __restrict__ list) {
  const int a = blockIdx.x, t = threadIdx.x;
  const int lane = t & 63, w = t >> 6;
  __shared__ int wtot[4];
  __shared__ int runbase;
  if (t == 0) runbase = base[a];
  __syncthreads();
  for (int i0 = 0; i0 < EN; i0 += 256) {
    int e = i0 + t;
    bool m = (e < EN) && (tgt[e] == a);
    unsigned long long bal = __ballot(m);
    if (lane == 0) wtot[w] = __popcll(bal);
    __syncthreads();
    int wbase = 0;
    for (int j = 0; j < w; ++j) wbase += wtot[j];
    int tot = wtot[0] + wtot[1] + wtot[2] + wtot[3];
    if (m) {
      int off = __popcll(bal & ((1ull << lane) - 1ull));
      list[runbase + wbase + off] = e;
    }
    __syncthreads();
    if (t == 0) runbase += tot;
    __syncthreads();
  }
}

__global__ __launch_bounds__(256) void k_gather4(
    const ushort_t* __restrict__ msg3, const int* __restrict__ base,
    const int* __restrict__ list, float* __restrict__ xmsg,
    int e0, int ce, int accum)
{
  const int a = blockIdx.x, part = blockIdx.y, t = threadIdx.x;
  if (t >= 196) return;
  const int b0 = base[a], b1 = base[a + 1];
  const int co = part * 1568 + t * 8;
  float a8[8];
  #pragma unroll
  for (int u = 0; u < 8; ++u) a8[u] = 0.f;
  for (int i = b0; i < b1; ++i) {
    int e = list[i];
    if (e < e0 || e >= e0 + ce) continue;
    bf16x8 v = *(const bf16x8*)&msg3[(long long)(e - e0) * 6272 + co];
    #pragma unroll
    for (int u = 0; u < 8; ++u) a8[u] += bf2f((ushort_t)v[u]);
  }
  float* o = xmsg + (long long)a * 6272 + co;
  if (accum) {
    #pragma unroll
    for (int u = 0; u < 8; ++u) o[u] += a8[u];
  } else {
    float4 lo = make_float4(a8[0], a8[1], a8[2], a8[3]);
    float4 hi = make_float4(a8[4], a8[5], a8[6], a8[7]);
    *(float4*)o = lo;
    *(float4*)(o + 4) = hi;
  }
}

// ---------------------------------------------------------------------------
// Host orchestration
// ---------------------------------------------------------------------------
extern "C" void kernel_launch(void* const* d_in, const int* in_sizes, int n_in,
                              void* d_out, int out_size, void* d_ws, size_t ws_size,
                              hipStream_t stream) {
  const float* x         = (const float*)d_in[0];
  const float* edist     = (const float*)d_in[1];
  const float* wigner    = (const float*)d_in[2];
  const float* wiginv    = (const float*)d_in[3];
  const float* to_grid   = (const float*)d_in[4];
  const float* from_grid = (const float*)d_in[5];
  const float* w_dist1   = (const float*)d_in[6];
  const float* b_dist1   = (const float*)d_in[7];
  const float* src_emb   = (const float*)d_in[8];
  const float* tgt_emb   = (const float*)d_in[9];
  const float* w_edge1   = (const float*)d_in[10];
  const float* b_edge1   = (const float*)d_in[11];
  const float* ws1       = (const float*)d_in[12];
  const float* bs1       = (const float*)d_in[13];
  const float* ws2       = (const float*)d_in[14];
  const float* bs2       = (const float*)d_in[15];
  const float* ws3       = (const float*)d_in[16];
  const float* bs3       = (const float*)d_in[17];
  const int*   anum      = (const int*)d_in[18];
  const int*   eidx      = (const int*)d_in[19];
  const float* sw[10]; const float* tw[10];
  for (int i = 0; i < 10; ++i) {
    sw[i] = (const float*)d_in[20 + i];
    tw[i] = (const float*)d_in[30 + i];
  }
  float* outp = (float*)d_out;

  // ---- workspace ----
  char* wsb = (char*)d_ws;
  size_t off = 0;
  auto alloc = [&](long long nbytes) {
    char* p = wsb + off; off += (size_t)((nbytes + 63) & ~63LL); return p;
  };
  ushort_t* x_edge  = (ushort_t*)alloc((8000LL + 128) * 128 * 2);
  ushort_t* b2ab    = (ushort_t*)alloc(5505024LL * 2);
  ushort_t* bgcw    = (ushort_t*)alloc(851968LL * 2);
  float*    bgcb    = (float*)alloc(6656 * 4);
  ushort_t* b20b    = (ushort_t*)alloc(458752LL * 2);
  ushort_t* s1m0b   = (ushort_t*)alloc(458752LL * 2);
  ushort_t* s1mb    = (ushort_t*)alloc(2752512LL * 2);
  ushort_t* wd1b    = (ushort_t*)alloc(65536 * 2);
  ushort_t* we1b    = (ushort_t*)alloc(16384 * 2);
  ushort_t* ws1b    = (ushort_t*)alloc(32768 * 2);
  ushort_t* ws2b    = (ushort_t*)alloc(16384 * 2);
  ushort_t* ws3b    = (ushort_t*)alloc(16384 * 2);
  ushort_t* tgb     = (ushort_t*)alloc(4802 * 2);
  ushort_t* fgb     = (ushort_t*)alloc(4802 * 2);
  float*    xmsg    = (float*)alloc(5017600LL * 4);
  ushort_t* xmsgb   = (ushort_t*)alloc((5017600LL + 16384) * 2);
  ushort_t* xb      = (ushort_t*)alloc((5017600LL + 16384) * 2);
  ushort_t* xbT     = (ushort_t*)alloc(6553600LL * 2);
  ushort_t* basis   = (ushort_t*)alloc((8000LL + 128) * 512 * 2);
  float*    x_dist  = (float*)alloc(1024000LL * 4);
  ushort_t* x_distb = (ushort_t*)alloc((8000LL + 128) * 128 * 2);
  int*      deg     = (int*)alloc(800 * 4);
  int*      sbase   = (int*)alloc(801 * 4);
  int*      elist   = (int*)alloc(8000 * 4);
  const size_t fixedB = off;
  char* arena = wsb + off;

  static const int ces[6] = {8000, 4000, 2000, 1000, 500, 250};
  static const int cas[6] = {800, 800, 800, 400, 200, 100};
  int ce = 250, ca = 100;
  for (int i = 0; i < 6; ++i) {
    long long ne = (long long)ces[i] * 76544 + 64LL * 50688;
    long long na = (long long)cas[i] * 87808 + 64LL * 512;
    long long need = (long long)fixedB + (ne > na ? ne : na);
    if (need <= (long long)ws_size) { ce = ces[i]; ca = cas[i]; break; }
  }

  // edge-phase arena (padded A-sources)
  char* ap = arena;
  ushort_t* xrot_s = (ushort_t*)ap;  ap += (long long)(ce + 64) * 12544;
  ushort_t* xrot_t = (ushort_t*)ap;  ap += (long long)(ce + 64) * 12544;
  ushort_t* tb0    = (ushort_t*)ap;  ap += (long long)(ce + 64) * 1024;
  ushort_t* tbm    = (ushort_t*)ap;  ap += (long long)(ce + 64) * 24576;
  ushort_t* msgp   = (ushort_t*)ap;  ap += (long long)ce * 12544;
  ushort_t* gate   = (ushort_t*)ap;
  ushort_t* msg3   = (ushort_t*)arena;   // overlays xrot after stage1
  // atom-phase arena
  char* bp = arena;
  ushort_t* hb = (ushort_t*)bp;  bp += (long long)ca * 49 * 256;
  ushort_t* g1 = (ushort_t*)bp;  bp += ((long long)ca * 98 + 64) * 256;
  ushort_t* g2 = (ushort_t*)bp;  bp += ((long long)ca * 98 + 64) * 256;
  ushort_t* g3 = (ushort_t*)bp;

  long long ofs2[7][2], s1ofs[7][2];
  { long long cur = 0, cur1 = 0;
    for (int m = 1; m <= 6; ++m) {
      int k = (7 - m) * 128;
      ofs2[m][0] = cur; cur += (long long)k * 1024;
      ofs2[m][1] = cur; cur += (long long)k * 1024;
      s1ofs[m][0] = cur1; cur1 += 512LL * k;
      s1ofs[m][1] = cur1; cur1 += 512LL * k;
    } }

  auto D0 = []() { GemmP p; memset(&p, 0, sizeof(p)); p.asplit = 1 << 30; return p; };
  auto finalize = [&](Grouped& G) {
    int base = 0;
    for (int i = 0; i < G.nd; ++i) {
      GemmP& p = G.d[i];
      p.ngx = (p.M + 127) >> 7;
      int ngy = (p.N + 127) >> 7;
      p.wg_base = base;
      base += p.ngx * ngy;
    }
    G.nwg = base;
    gemm_g<<<base, 256, 0, stream>>>(G);
  };
  auto run1 = [&](GemmP p) { Grouped G; G.d[0] = p; G.nd = 1; finalize(G); };
  auto rungrid = [&](const float* A, int M, int K, int permA,
                     const ushort_t* B, int b_ib, void* C, int c_ib,
                     const float* bias, int act, int c_bf16, int nb) {
    GridP p;
    p.A = A; p.B = B; p.C = C; p.bias = bias;
    p.b_ib = b_ib; p.c_ib = c_ib;
    p.M = M; p.K = K; p.permA = permA; p.act = act; p.c_bf16 = c_bf16;
    gridmm<<<nb, 256, 0, stream>>>(p);
  };
  auto cvt = [&](const float* s, ushort_t* d, int n) {
    k_cvt<<<(n + 255) / 256, 256, 0, stream>>>(s, d, n);
  };

  // 0) builds
  k_build_b2b<<<(5505024 + 255) / 256, 256, 0, stream>>>(sw[7], sw[9], tw[7], tw[9], b2ab);
  k_build_bgcat<<<(858624 + 255) / 256, 256, 0, stream>>>(
      sw[0], tw[0], sw[4], tw[4], sw[1], tw[1], sw[5], tw[5], bgcw, bgcb);
  k_build_b20b<<<(458752 + 255) / 256, 256, 0, stream>>>(sw[3], tw[3], b20b);
  k_build_s1m<<<(2752512 + 255) / 256, 256, 0, stream>>>(sw[6], sw[8], tw[6], tw[8], s1mb);
  cvt(sw[2], s1m0b, 229376);
  cvt(tw[2], s1m0b + 229376, 229376);
  cvt(w_dist1, wd1b, 65536);
  cvt(w_edge1, we1b, 16384);
  cvt(ws1, ws1b, 32768);
  cvt(ws2, ws2b, 16384);
  cvt(ws3, ws3b, 16384);
  cvt(from_grid, fgb, 4802);
  k_build_tg<<<(4802 + 255) / 256, 256, 0, stream>>>(to_grid, tgb);
  cvt(x, xb, 5017600);
  k_xT<<<AN, 256, 0, stream>>>(x, xbT);

  // scatter lists
  k_zeroi<<<4, 256, 0, stream>>>(deg, 800);
  k_deg<<<(EN + 255) / 256, 256, 0, stream>>>(eidx + EN, deg);
  k_prefix<<<1, 1024, 0, stream>>>(deg, sbase);
  k_fill<<<AN, 256, 0, stream>>>(eidx + EN, sbase, elist);

  // 1) edge features
  k_basis<<<(EN * 512 + 255) / 256, 256, 0, stream>>>(edist, basis);
  { GemmP p = D0();
    p.A = basis; p.a_se = 512; p.B = wd1b; p.ldb = 512; p.bias = b_dist1;
    p.C = x_dist; p.c_se = 128; p.M = EN; p.N = 128; p.K = 512;
    run1(p); }
  k_emb<<<(EN * 128 + 255) / 256, 256, 0, stream>>>(src_emb, tgt_emb, anum, eidx,
                                                    x_dist, x_distb);
  { GemmP p = D0();
    p.A = x_distb; p.a_se = 128; p.B = we1b; p.ldb = 128; p.bias = b_edge1;
    p.act = 1; p.C = x_edge; p.c_se = 128; p.c_bf16 = 1;
    p.M = EN; p.N = 128; p.K = 128;
    run1(p); }

  static const int offq[7] = {0, 7, 19, 29, 37, 43, 47};

  // 2) edge chunks
  for (int e0 = 0; e0 < EN; e0 += ce) {
    const int c = ce;
    k_rot2<<<c, 256, 0, stream>>>(wigner + (long long)e0 * 2401, xbT,
                                  eidx + e0, eidx + EN + e0, xrot_s, xrot_t);
    // gates
    { GemmP p = D0();
      p.A = x_edge + (long long)e0 * 128; p.a_se = 128;
      p.B = bgcw; p.ldb = 128; p.bias = bgcb; p.act = 1;
      p.C = gate; p.c_se = 6656; p.c_bf16 = 1;
      p.M = c; p.N = 6656; p.K = 128;
      run1(p); }
    // stage 1 grouped
    { Grouped G; G.nd = 14;
      for (int s = 0; s < 2; ++s) {
        GemmP p = D0();
        p.A = s ? xrot_t : xrot_s; p.a_se = 6272;
        p.B = s1m0b + (long long)s * 229376; p.ldb = 896;
        p.gate = gate; p.gate_ofs = s * 256;
        p.C = tb0; p.c_se = 512; p.c_ofs = s * 256; p.c_bf16 = 1;
        p.M = c; p.N = 256; p.K = 896;
        G.d[s] = p;
      }
      int di = 2;
      for (int m = 1; m <= 6; ++m) {
        const int k = (7 - m) * 128, off2 = offq[m];
        for (int s = 0; s < 2; ++s) {
          GemmP p = D0();
          p.A = (s ? xrot_t : xrot_s) + off2 * 128;
          p.a_se = 6272; p.a_si = k; p.pair = 1;
          p.B = s1mb + s1ofs[m][s]; p.ldb = k;
          p.gate = gate; p.gate_ofs = 512 + (m - 1) * 1024 + s * 512;
          p.C = tbm; p.c_se = 12288; p.c_si = 1024;
          p.c_ofs = (m - 1) * 2048 + s * 512;
          p.ihalf = 1; p.c_bf16 = 1;
          p.M = 2 * c; p.N = 512; p.K = k;
          G.d[di++] = p;
        }
      }
      finalize(G); }
    // stage 2 grouped
    { Grouped G; G.nd = 13;
      { GemmP p = D0();
        p.A = tb0; p.a_se = 512;
        p.B = b20b; p.ldb = 512;
        p.C = msgp; p.c_se = 6272; p.c_bf16 = 1;
        p.M = c; p.N = 896; p.K = 512;
        G.d[0] = p; }
      int di = 1;
      for (int m = 1; m <= 6; ++m) {
        const int n = 7 - m, k = n * 128, off2 = offq[m];
        for (int pp = 0; pp < 2; ++pp) {
          GemmP p = D0();
          p.A = tbm + (m - 1) * 2048 + pp * 1024; p.a_se = 12288;
          p.B = b2ab + ofs2[m][pp]; p.ldb = 1024;
          p.C = msgp; p.c_se = 6272; p.c_ofs = (off2 + (pp ? n : 0)) * 128; p.c_bf16 = 1;
          p.M = c; p.N = k; p.K = 1024;
          G.d[di++] = p;
        }
      }
      finalize(G); }
    // fused grid pipeline + gather
    k_grid<<<c, 256, 0, stream>>>(tgb, fgb, wiginv + (long long)e0 * 2401, msgp, msg3);
    k_gather4<<<dim3(AN, 4), 256, 0, stream>>>(msg3, sbase, elist, xmsg, e0, c, e0 > 0);
  }

  // xmsg -> bf16 for atom GEMM
  cvt(xmsg, xmsgb, 5017600);

  // 3) atom phase
  for (int a0 = 0; a0 < AN; a0 += ca) {
    { GemmP p = D0();
      p.A = xb + (long long)a0 * 6272; p.A2 = xmsgb + (long long)a0 * 6272;
      p.a_se = 128; p.asplit = 128;
      p.B = ws1b; p.ldb = 256;
      p.C = hb; p.c_se = 128; p.c_bf16 = 1;
      p.M = ca * 49; p.N = 128; p.K = 256;
      run1(p); }
    rungrid(to_grid, 98, 49, 0, hb, 6272, g1, 12544, bs1, 1, 1, ca);
    { GemmP p = D0();
      p.A = g1; p.a_se = 128;
      p.B = ws2b; p.ldb = 128; p.bias = bs2; p.act = 1;
      p.C = g2; p.c_se = 128; p.c_bf16 = 1;
      p.M = ca * 98; p.N = 128; p.K = 128;
      run1(p); }
    { GemmP p = D0();
      p.A = g2; p.a_se = 128;
      p.B = ws3b; p.ldb = 128; p.bias = bs3;
      p.C = g3; p.c_se = 128; p.c_bf16 = 1;
      p.M = ca * 98; p.N = 128; p.K = 128;
      run1(p); }
    rungrid(from_grid, 49, 98, 0, g3, 12544, outp + (long long)a0 * 6272, 6272,
            nullptr, 0, 0, ca);
  }
}